// Round 4
// baseline (935.579 us; speedup 1.0000x reference)
//
#include <hip/hip_runtime.h>
#include <math.h>

// GNN_2_Model: fused-embed -> GAT1 -> GAT2(+res) -> gid head & edge head.
// Round 3: (1) edge head decomposed: UV = h2 @ [We1_top|We1_bot] (per-node, 26 GF)
//   + per-pair combine kernel (replaces 68.7 GF gather-GEMM over P rows);
// (2) weights pre-packed into MFMA fragment order -> B staging is a linear
//   conflict-free ds_write_b128; (3) aggregate gathers widened to uint4.
// ws: X0 [N,832] | featB/UV [N,512] | h1 [N,512] | h2 [N,512] | W1p | W2p | Wg1p | Wuvp
//   | sa_ext[512] sb[256] | el,er f32 [N,4] | offsets [N+1] | counts [N] | csr_src [E]
//   g_tmp bf16 [N,256] reuses X0.

typedef __attribute__((ext_vector_type(8))) short short8;   // 8 x bf16 (4 VGPR)
typedef __attribute__((ext_vector_type(4))) float f32x4;    // MFMA accum
typedef unsigned short ushort;

__device__ __forceinline__ float b2f(ushort h) {
  union { unsigned u; float f; } v; v.u = ((unsigned)h) << 16; return v.f;
}
__device__ __forceinline__ ushort f2b(float f) {
  union { float f; unsigned u; } v; v.f = f;
  unsigned r = v.u + 0x7fffu + ((v.u >> 16) & 1u);  // round-to-nearest-even
  return (ushort)(r >> 16);
}
__device__ __forceinline__ void up4(uint2 q, float* o) {
  o[0] = b2f((ushort)(q.x & 0xffffu)); o[1] = b2f((ushort)(q.x >> 16));
  o[2] = b2f((ushort)(q.y & 0xffffu)); o[3] = b2f((ushort)(q.y >> 16));
}
__device__ __forceinline__ uint2 pk4(const float* o) {
  uint2 q;
  q.x = (unsigned)f2b(o[0]) | ((unsigned)f2b(o[1]) << 16);
  q.y = (unsigned)f2b(o[2]) | ((unsigned)f2b(o[3]) << 16);
  return q;
}
__device__ __forceinline__ void up8(uint4 q, float* o) {
  o[0] = b2f((ushort)(q.x & 0xffffu)); o[1] = b2f((ushort)(q.x >> 16));
  o[2] = b2f((ushort)(q.y & 0xffffu)); o[3] = b2f((ushort)(q.y >> 16));
  o[4] = b2f((ushort)(q.z & 0xffffu)); o[5] = b2f((ushort)(q.z >> 16));
  o[6] = b2f((ushort)(q.w & 0xffffu)); o[7] = b2f((ushort)(q.w >> 16));
}
__device__ __forceinline__ uint4 pk8(const float* o) {
  uint4 q;
  q.x = (unsigned)f2b(o[0]) | ((unsigned)f2b(o[1]) << 16);
  q.y = (unsigned)f2b(o[2]) | ((unsigned)f2b(o[3]) << 16);
  q.z = (unsigned)f2b(o[4]) | ((unsigned)f2b(o[5]) << 16);
  q.w = (unsigned)f2b(o[6]) | ((unsigned)f2b(o[7]) << 16);
  return q;
}
__device__ __forceinline__ float warp_sum(float v) {
#pragma unroll
  for (int o = 32; o > 0; o >>= 1) v += __shfl_xor(v, o);
  return v;
}

// ---------------- fused embedding -> X0 bf16 [N,832] ----------------
__global__ __launch_bounds__(256) void embed_kernel(
    const float* __restrict__ cell_h, const float* __restrict__ pos_emb,
    const float* __restrict__ mf_emb,
    const int* __restrict__ row_pos, const int* __restrict__ col_pos,
    const int* __restrict__ row_mf, const int* __restrict__ col_mf,
    ushort* __restrict__ X0, int N)
{
  const int idx = blockIdx.x * 256 + threadIdx.x;
  const int total = N * 104;  // 832/8 chunks per node
  if (idx >= total) return;
  const int n = idx / 104;
  const int c8 = (idx - n * 104) * 8;
  float o[8];
  if (c8 < 768) {
    const int rp = row_pos[n], cp = col_pos[n];
    const float4* pc = (const float4*)(cell_h + (size_t)n * 768 + c8);
    const float4* pr = (const float4*)(pos_emb + (size_t)rp * 768 + c8);
    const float4* pq = (const float4*)(pos_emb + (size_t)cp * 768 + c8);
    float4 c0 = pc[0], c1 = pc[1], r0 = pr[0], r1 = pr[1], q0 = pq[0], q1 = pq[1];
    o[0] = c0.x + r0.x + q0.x; o[1] = c0.y + r0.y + q0.y;
    o[2] = c0.z + r0.z + q0.z; o[3] = c0.w + r0.w + q0.w;
    o[4] = c1.x + r1.x + q1.x; o[5] = c1.y + r1.y + q1.y;
    o[6] = c1.z + r1.z + q1.z; o[7] = c1.w + r1.w + q1.w;
  } else {
    const int rm = min(row_mf[n], 5), cm = min(col_mf[n], 5);
    const int j0 = c8 - 768;
    const float4* pr = (const float4*)(mf_emb + (size_t)rm * 64 + j0);
    const float4* pq = (const float4*)(mf_emb + (size_t)cm * 64 + j0);
    float4 r0 = pr[0], r1 = pr[1], q0 = pq[0], q1 = pq[1];
    o[0] = r0.x + q0.x; o[1] = r0.y + q0.y; o[2] = r0.z + q0.z; o[3] = r0.w + q0.w;
    o[4] = r1.x + q1.x; o[5] = r1.y + q1.y; o[6] = r1.z + q1.z; o[7] = r1.w + q1.w;
  }
  *(uint4*)(X0 + (size_t)n * 832 + c8) = pk8(o);
}

// ------- weight pack: W[K][Ncols] f32 -> Wp bf16 in MFMA fragment-tile order -------
// Tile (tn: 128 cols of output, tk: 64 k). Within tile: 16 subtiles of 512 shorts,
// subidx = rb*2+ks (rb = colrow>>4, ks = (k>>5)&1), element at lane*8+j with
// lane = mm + 16*g, per round-2 staging mapping (verified passing).
// SPLIT: W is We1 [2K][256]; col n<256 -> We1[k][n], n>=256 -> We1[K+k][n-256].
template <bool SPLIT>
__global__ __launch_bounds__(256) void wpack_kernel(
    const float* __restrict__ W, ushort* __restrict__ Wp, int K, int Ncols)
{
  const int idx = blockIdx.x * 256 + threadIdx.x;
  if (idx >= K * Ncols) return;
  const int n = idx / K, k = idx - n * K;
  float v;
  if (SPLIT) {
    v = W[(size_t)(k + (n >= 256 ? K : 0)) * 256 + (n & 255)];
  } else {
    v = W[(size_t)k * Ncols + n];
  }
  const int tn = n >> 7, rb = (n >> 4) & 7, mm = n & 15;
  const int tk = k >> 6;
  const int kl = k & 63;
  const int kc = kl >> 3, i = kl & 7;
  const int g = (kc & 1) * 2 + (i >> 2);
  const int j = ((kc >> 1) & 1) * 4 + (i & 3);
  const int ks = kc >> 2;
  const int nTK = K >> 6;
  const size_t off = (((size_t)(tn * nTK + tk) * 16) + (rb * 2 + ks)) * 512
                     + ((mm + 16 * g) * 8) + j;
  Wp[off] = f2b(v);
}

// ---- fold edge-head BN into per-channel scale/shift: sa (applied in GEMM), sb ----
__global__ void eprep_kernel(const float* __restrict__ be1,
                             const float* __restrict__ eg, const float* __restrict__ eb,
                             const float* __restrict__ em, const float* __restrict__ ev,
                             float* __restrict__ sa_ext, float* __restrict__ sb)
{
  const int c = threadIdx.x;  // 256
  const float sa = eg[c] * rsqrtf(ev[c] + 1e-5f);
  sa_ext[c] = sa;
  sa_ext[c + 256] = sa;
  sb[c] = eb[c] + (be1[c] - em[c]) * sa;
}

// ---------------- bf16 MFMA GEMM: C[M,Ncols] = A[M,K] @ Bp (packed) ----------------
// 128x128 tile, BK=64, 4 waves. B staging = linear copy from packed tiles
// (conflict-free ds_write_b128); A staging = reg-staged fragment scatter.
// EPI: 0 none, 1 BN+ReLU (bias/gamma/beta/mean/var), 2 per-col scale (gamma).
template <int EPI>
__global__ __launch_bounds__(256) void mfma_gemm_kernel(
    const ushort* __restrict__ A, const ushort* __restrict__ Bp,
    ushort* __restrict__ C, int M, int K, int Ncols,
    const float* __restrict__ bias, const float* __restrict__ gamma,
    const float* __restrict__ beta, const float* __restrict__ mean,
    const float* __restrict__ var)
{
  __shared__ ushort As[8192];  // 128 x 64 bf16, fragment-major
  __shared__ ushort Bs[8192];
  const int tid = threadIdx.x;
  const int lane = tid & 63;
  const int wave = tid >> 6;
  const int wm = wave >> 1, wn = wave & 1;
  const int m0 = blockIdx.y * 128, n0 = blockIdx.x * 128;
  const int nTK = K >> 6;

  f32x4 acc[4][4];
#pragma unroll
  for (int i = 0; i < 4; ++i)
#pragma unroll
    for (int j = 0; j < 4; ++j) acc[i][j] = (f32x4){0.f, 0.f, 0.f, 0.f};

  for (int k0 = 0; k0 < K; k0 += 64) {
    uint4 aval[4], bval[4];
    const ushort* btile = Bp + (((size_t)blockIdx.x * nTK + (k0 >> 6)) << 13);
#pragma unroll
    for (int cc = 0; cc < 4; ++cc) {
      const int c = tid + cc * 256;          // chunk id 0..1023
      const int r = c >> 3, kc = c & 7;      // tile row, 16B chunk within BK
      const int gr = m0 + r;
      const ushort* ap = (gr < M) ? (A + (size_t)gr * K + k0 + kc * 8) : A;
      aval[cc] = *(const uint4*)ap;
      bval[cc] = *(const uint4*)(btile + ((size_t)c << 3));
    }
    __syncthreads();  // previous tile's frags consumed
#pragma unroll
    for (int cc = 0; cc < 4; ++cc) {
      const int c = tid + cc * 256;
      const int r = c >> 3, kc = c & 7;
      const int mb = r >> 4, mm = r & 15;
      const int ks = kc >> 2;
      const int g0 = (kc & 1) * 2;
      const int j0 = ((kc >> 1) & 1) * 4;
      const int sub = (mb * 2 + ks) << 9;
      uint2 w;
      w.x = aval[cc].x; w.y = aval[cc].y;
      *(uint2*)(As + sub + ((mm + 16 * g0) << 3) + j0) = w;
      w.x = aval[cc].z; w.y = aval[cc].w;
      *(uint2*)(As + sub + ((mm + 16 * (g0 + 1)) << 3) + j0) = w;
      *(uint4*)(Bs + ((size_t)c << 3)) = bval[cc];  // linear, conflict-free
    }
    __syncthreads();

    short8 af[4][2], bfr[4][2];
#pragma unroll
    for (int f = 0; f < 4; ++f)
#pragma unroll
      for (int ks = 0; ks < 2; ++ks) {
        af[f][ks]  = *(const short8*)(As + ((((wm * 4 + f) * 2) + ks) << 9) + (lane << 3));
        bfr[f][ks] = *(const short8*)(Bs + ((((wn * 4 + f) * 2) + ks) << 9) + (lane << 3));
      }
#pragma unroll
    for (int mf = 0; mf < 4; ++mf)
#pragma unroll
      for (int nf = 0; nf < 4; ++nf)
#pragma unroll
        for (int ks = 0; ks < 2; ++ks)
          acc[mf][nf] = __builtin_amdgcn_mfma_f32_16x16x32_bf16(
              af[mf][ks], bfr[nf][ks], acc[mf][nf], 0, 0, 0);
  }

  // epilogue: C layout col = lane&15, row = (lane>>4)*4 + j  [measured m89]
#pragma unroll
  for (int nf = 0; nf < 4; ++nf) {
    const int col = n0 + (wn * 4 + nf) * 16 + (lane & 15);
    float sa = 1.f, sb = 0.f;
    if (EPI == 1) {
      const float rs = rsqrtf(var[col] + 1e-5f);
      sa = rs * gamma[col];
      sb = beta[col] + (bias[col] - mean[col]) * sa;
    } else if (EPI == 2) {
      sa = gamma[col];
    }
#pragma unroll
    for (int mf = 0; mf < 4; ++mf) {
      const int rbase = m0 + (wm * 4 + mf) * 16 + (lane >> 4) * 4;
#pragma unroll
      for (int j = 0; j < 4; ++j) {
        const int row = rbase + j;
        if (row >= M) continue;
        float v = acc[mf][nf][j];
        if (EPI == 1) v = fmaxf(fmaf(v, sa, sb), 0.f);
        else if (EPI == 2) v = v * sa;
        C[(size_t)row * Ncols + col] = f2b(v);
      }
    }
  }
}

// el[n,h] = sum_d feat[n,h,d]*al[h,d]; er likewise. One wave per node. feat bf16.
__global__ __launch_bounds__(256) void elr_kernel(
    const ushort* __restrict__ feat, const float* __restrict__ al,
    const float* __restrict__ ar, float* __restrict__ el, float* __restrict__ er, int N)
{
  const int wv = (blockIdx.x * 256 + threadIdx.x) >> 6;
  const int lane = threadIdx.x & 63;
  if (wv >= N) return;
  const ushort* f = feat + (size_t)wv * 512;
#pragma unroll
  for (int h = 0; h < 4; h++) {
    const float x0 = b2f(f[h * 128 + lane]);
    const float x1 = b2f(f[h * 128 + 64 + lane]);
    float sl = x0 * al[h * 128 + lane] + x1 * al[h * 128 + 64 + lane];
    float sr = x0 * ar[h * 128 + lane] + x1 * ar[h * 128 + 64 + lane];
    sl = warp_sum(sl);
    sr = warp_sum(sr);
    if (lane == 0) { el[(size_t)wv * 4 + h] = sl; er[(size_t)wv * 4 + h] = sr; }
  }
}

// ---------------- CSR build (by dst), done once ----------------
__global__ __launch_bounds__(256) void hist_kernel(
    const int* __restrict__ dst, int* __restrict__ counts, int E)
{
  const int e = blockIdx.x * 256 + threadIdx.x;
  if (e < E) atomicAdd(counts + dst[e], 1);
}

__global__ __launch_bounds__(1024) void scan_kernel(
    const int* __restrict__ counts, int* __restrict__ offsets, int N)
{
  __shared__ int sums[1024];
  const int t = threadIdx.x;
  const int chunk = (N + 1023) >> 10;
  const int beg = t * chunk;
  const int end = min(beg + chunk, N);
  int s = 0;
  for (int i = beg; i < end; ++i) s += counts[i];
  sums[t] = s;
  __syncthreads();
  for (int o = 1; o < 1024; o <<= 1) {
    int u = (t >= o) ? sums[t - o] : 0;
    __syncthreads();
    sums[t] += u;
    __syncthreads();
  }
  int run = sums[t] - s;
  for (int i = beg; i < end; ++i) { offsets[i] = run; run += counts[i]; }
  if (t == 1023) offsets[N] = sums[1023];
}

__global__ __launch_bounds__(256) void scatter_kernel(
    const int* __restrict__ src, const int* __restrict__ dst,
    const int* __restrict__ offsets, int* __restrict__ cursor,
    int* __restrict__ csr_src, int E)
{
  const int e = blockIdx.x * 256 + threadIdx.x;
  if (e >= E) return;
  const int d = dst[e];
  const int pos = offsets[d] + atomicAdd(cursor + d, 1);
  csr_src[pos] = src[e];
}

// ---------------- GAT aggregate: one wave per dst node (uint4 gathers) ----------------
template <bool RES>
__global__ __launch_bounds__(256) void gat_aggregate_kernel(
    const int* __restrict__ csr_src, const int* __restrict__ offsets,
    const float* __restrict__ el, const float* __restrict__ er,
    const ushort* __restrict__ feat, const float* __restrict__ bias,
    const ushort* __restrict__ resid, ushort* __restrict__ out, int N)
{
  const int node = (blockIdx.x * 256 + threadIdx.x) >> 6;
  const int lane = threadIdx.x & 63;
  if (node >= N) return;
  const int beg = offsets[node], end = offsets[node + 1];
  const float4 erd = *(const float4*)(er + (size_t)node * 4);

  // pass 1: softmax denominators
  float d0 = 0.f, d1 = 0.f, d2 = 0.f, d3 = 0.f;
  for (int i = beg + lane; i < end; i += 64) {
    const int s = csr_src[i];
    const float4 l = *(const float4*)(el + (size_t)s * 4);
    float x0 = l.x + erd.x, x1 = l.y + erd.y, x2 = l.z + erd.z, x3 = l.w + erd.w;
    x0 = x0 > 0.f ? x0 : 0.2f * x0;
    x1 = x1 > 0.f ? x1 : 0.2f * x1;
    x2 = x2 > 0.f ? x2 : 0.2f * x2;
    x3 = x3 > 0.f ? x3 : 0.2f * x3;
    d0 += __expf(x0); d1 += __expf(x1); d2 += __expf(x2); d3 += __expf(x3);
  }
  d0 = warp_sum(d0); d1 = warp_sum(d1); d2 = warp_sum(d2); d3 = warp_sum(d3);
  const float r0 = 1.f / d0, r1 = 1.f / d1, r2 = 1.f / d2, r3 = 1.f / d3;

  // pass 2: lane owns feats [lane*8, +8) — single head h = lane>>4
  float a[8] = {0.f, 0.f, 0.f, 0.f, 0.f, 0.f, 0.f, 0.f};
  for (int i = beg; i < end; ++i) {
    const int s = csr_src[i];  // uniform across wave
    const float4 l = *(const float4*)(el + (size_t)s * 4);
    float x0 = l.x + erd.x, x1 = l.y + erd.y, x2 = l.z + erd.z, x3 = l.w + erd.w;
    x0 = x0 > 0.f ? x0 : 0.2f * x0;
    x1 = x1 > 0.f ? x1 : 0.2f * x1;
    x2 = x2 > 0.f ? x2 : 0.2f * x2;
    x3 = x3 > 0.f ? x3 : 0.2f * x3;
    const float al0 = __expf(x0) * r0, al1 = __expf(x1) * r1;
    const float al2 = __expf(x2) * r2, al3 = __expf(x3) * r3;
    const float aw = (lane & 32) ? ((lane & 16) ? al3 : al2)
                                 : ((lane & 16) ? al1 : al0);
    const uint4 q = *(const uint4*)(feat + (size_t)s * 512 + lane * 8);
    float v[8];
    up8(q, v);
#pragma unroll
    for (int j = 0; j < 8; ++j) a[j] = fmaf(v[j], aw, a[j]);
  }

  const float4 b0 = *(const float4*)(bias + lane * 8);
  const float4 b1 = *(const float4*)(bias + lane * 8 + 4);
  a[0] += b0.x; a[1] += b0.y; a[2] += b0.z; a[3] += b0.w;
  a[4] += b1.x; a[5] += b1.y; a[6] += b1.z; a[7] += b1.w;
  if (RES) {
    float q[8];
    up8(*(const uint4*)(resid + (size_t)node * 512 + lane * 8), q);
#pragma unroll
    for (int j = 0; j < 8; ++j) a[j] += q[j];
  }
  *(uint4*)(out + (size_t)node * 512 + lane * 8) = pk8(a);
}

// gid logits: one wave per node; g bf16 [N,256] @ Wg2[256,4] + bg2.
__global__ __launch_bounds__(256) void gid2_kernel(
    const ushort* __restrict__ g, const float* __restrict__ Wg2,
    const float* __restrict__ bg2, float* __restrict__ out, int N)
{
  const int wv = (blockIdx.x * 256 + threadIdx.x) >> 6;
  const int lane = threadIdx.x & 63;
  if (wv >= N) return;
  float ga[4];
  up4(*(const uint2*)(g + (size_t)wv * 256 + lane * 4), ga);
  float a0 = 0.f, a1 = 0.f, a2 = 0.f, a3 = 0.f;
  const float* wp = Wg2 + (size_t)lane * 16;
#pragma unroll
  for (int j = 0; j < 4; j++) {
    const float4 w = *(const float4*)(wp + j * 4);
    a0 += ga[j] * w.x; a1 += ga[j] * w.y; a2 += ga[j] * w.z; a3 += ga[j] * w.w;
  }
  a0 = warp_sum(a0); a1 = warp_sum(a1); a2 = warp_sum(a2); a3 = warp_sum(a3);
  if (lane == 0) {
    float4 o = {a0 + bg2[0], a1 + bg2[1], a2 + bg2[2], a3 + bg2[3]};
    *(float4*)(out + (size_t)wv * 4) = o;
  }
}

// edge logits: one wave per pair over UV (bf16, scale pre-applied):
// logit = sum_c relu(U'[p0][c] + V'[p1][c] + sb[c]) * We2[c] + be2
__global__ __launch_bounds__(256) void pair_combine_kernel(
    const ushort* __restrict__ UV, const int* __restrict__ pairs,
    const float* __restrict__ sb, const float* __restrict__ We2,
    const float* __restrict__ be2, float* __restrict__ out, int P)
{
  const int wv = (blockIdx.x * 256 + threadIdx.x) >> 6;
  const int lane = threadIdx.x & 63;
  if (wv >= P) return;
  const int p0 = pairs[2 * wv], p1 = pairs[2 * wv + 1];
  float u[4], v[4];
  up4(*(const uint2*)(UV + (size_t)p0 * 512 + lane * 4), u);
  up4(*(const uint2*)(UV + (size_t)p1 * 512 + 256 + lane * 4), v);
  const float4 sbv = *(const float4*)(sb + lane * 4);
  const float4 w2 = *(const float4*)(We2 + lane * 4);
  float s = fmaxf(u[0] + v[0] + sbv.x, 0.f) * w2.x
          + fmaxf(u[1] + v[1] + sbv.y, 0.f) * w2.y
          + fmaxf(u[2] + v[2] + sbv.z, 0.f) * w2.z
          + fmaxf(u[3] + v[3] + sbv.w, 0.f) * w2.w;
  s = warp_sum(s);
  if (lane == 0) out[wv] = s + be2[0];
}

extern "C" void kernel_launch(void* const* d_in, const int* in_sizes, int n_in,
                              void* d_out, int out_size, void* d_ws, size_t ws_size,
                              hipStream_t stream) {
  const float* cell_h  = (const float*)d_in[0];
  const float* pos_emb = (const float*)d_in[1];
  const float* mf_emb  = (const float*)d_in[2];
  const float* W1  = (const float*)d_in[3];
  const float* al1 = (const float*)d_in[4];
  const float* ar1 = (const float*)d_in[5];
  const float* b1  = (const float*)d_in[6];
  const float* W2  = (const float*)d_in[7];
  const float* al2 = (const float*)d_in[8];
  const float* ar2 = (const float*)d_in[9];
  const float* b2  = (const float*)d_in[10];
  const float* Wg1 = (const float*)d_in[11];
  const float* bg1 = (const float*)d_in[12];
  const float* g_gamma = (const float*)d_in[13];
  const float* g_beta  = (const float*)d_in[14];
  const float* g_mean  = (const float*)d_in[15];
  const float* g_var   = (const float*)d_in[16];
  const float* Wg2 = (const float*)d_in[17];
  const float* bg2 = (const float*)d_in[18];
  const float* We1 = (const float*)d_in[19];
  const float* be1 = (const float*)d_in[20];
  const float* e_gamma = (const float*)d_in[21];
  const float* e_beta  = (const float*)d_in[22];
  const float* e_mean  = (const float*)d_in[23];
  const float* e_var   = (const float*)d_in[24];
  const float* We2 = (const float*)d_in[25];
  const float* be2 = (const float*)d_in[26];
  const int* src = (const int*)d_in[27];
  const int* dst = (const int*)d_in[28];
  const int* row_pos = (const int*)d_in[29];
  const int* col_pos = (const int*)d_in[30];
  const int* row_mf  = (const int*)d_in[31];
  const int* col_mf  = (const int*)d_in[32];
  const int* pairs   = (const int*)d_in[33];

  const int N = in_sizes[0] / 768;
  const int E = in_sizes[27];
  const int P = in_sizes[33] / 2;

  ushort* X0    = (ushort*)d_ws;                 // [N,832]
  ushort* featB = X0 + (size_t)N * 832;          // [N,512] (later reused as UV)
  ushort* h1    = featB + (size_t)N * 512;       // [N,512]
  ushort* h2    = h1 + (size_t)N * 512;          // [N,512]
  ushort* W1p   = h2 + (size_t)N * 512;          // packed [512,832]
  ushort* W2p   = W1p + 512 * 832;               // packed [512,512]
  ushort* Wg1p  = W2p + 512 * 512;               // packed [256,512]
  ushort* Wuvp  = Wg1p + 256 * 512;              // packed [512,512] ([We1_top|We1_bot])
  float* sa_ext = (float*)(Wuvp + 512 * 512);    // [512]
  float* sbv    = sa_ext + 512;                  // [256]
  float* el     = sbv + 256;                     // [N,4]
  float* er     = el + (size_t)N * 4;            // [N,4]
  int* offsets  = (int*)(er + (size_t)N * 4);    // [N+1]
  int* counts   = offsets + (N + 1);             // [N]
  int* csr_src  = counts + N;                    // [E]
  ushort* g_tmp = X0;                            // [N,256] (X0 dead after GEMM1)
  ushort* UV    = featB;                         // [N,512] (featB dead after agg2)

  const int nodeWaves = (N + 3) / 4;
  const int mtiles = (N + 127) / 128;

  // ---- CSR build (once) ----
  hipMemsetAsync(counts, 0, (size_t)N * sizeof(int), stream);
  hist_kernel<<<(E + 255) / 256, 256, 0, stream>>>(dst, counts, E);
  scan_kernel<<<1, 1024, 0, stream>>>(counts, offsets, N);
  hipMemsetAsync(counts, 0, (size_t)N * sizeof(int), stream);
  scatter_kernel<<<(E + 255) / 256, 256, 0, stream>>>(src, dst, offsets, counts, csr_src, E);

  // ---- weights -> packed bf16 fragment tiles ----
  wpack_kernel<false><<<(512 * 832 + 255) / 256, 256, 0, stream>>>(W1, W1p, 832, 512);
  wpack_kernel<false><<<(512 * 512 + 255) / 256, 256, 0, stream>>>(W2, W2p, 512, 512);
  wpack_kernel<false><<<(256 * 512 + 255) / 256, 256, 0, stream>>>(Wg1, Wg1p, 512, 256);
  wpack_kernel<true><<<(512 * 512 + 255) / 256, 256, 0, stream>>>(We1, Wuvp, 512, 512);
  eprep_kernel<<<1, 256, 0, stream>>>(be1, e_gamma, e_beta, e_mean, e_var, sa_ext, sbv);

  // ---- fused embedding -> X0 bf16 ----
  embed_kernel<<<(N * 104 + 255) / 256, 256, 0, stream>>>(
      cell_h, pos_emb, mf_emb, row_pos, col_pos, row_mf, col_mf, X0, N);

  // ---- GAT layer 1 ----
  mfma_gemm_kernel<0><<<dim3(4, mtiles), 256, 0, stream>>>(
      X0, W1p, featB, N, 832, 512, nullptr, nullptr, nullptr, nullptr, nullptr);
  elr_kernel<<<nodeWaves, 256, 0, stream>>>(featB, al1, ar1, el, er, N);
  gat_aggregate_kernel<false><<<nodeWaves, 256, 0, stream>>>(
      csr_src, offsets, el, er, featB, b1, nullptr, h1, N);

  // ---- GAT layer 2 (identity residual) ----
  mfma_gemm_kernel<0><<<dim3(4, mtiles), 256, 0, stream>>>(
      h1, W2p, featB, N, 512, 512, nullptr, nullptr, nullptr, nullptr, nullptr);
  elr_kernel<<<nodeWaves, 256, 0, stream>>>(featB, al2, ar2, el, er, N);
  gat_aggregate_kernel<true><<<nodeWaves, 256, 0, stream>>>(
      csr_src, offsets, el, er, featB, b2, h1, h2, N);

  // ---- comp_and_gid head ----
  mfma_gemm_kernel<1><<<dim3(2, mtiles), 256, 0, stream>>>(
      h2, Wg1p, g_tmp, N, 512, 256, bg1, g_gamma, g_beta, g_mean, g_var);
  gid2_kernel<<<nodeWaves, 256, 0, stream>>>(g_tmp, Wg2, bg2, (float*)d_out, N);

  // ---- edge head: UV = h2 @ [We1_top|We1_bot] (scale folded), then pair combine ----
  mfma_gemm_kernel<2><<<dim3(4, mtiles), 256, 0, stream>>>(
      h2, Wuvp, UV, N, 512, 512, nullptr, sa_ext, nullptr, nullptr, nullptr);
  pair_combine_kernel<<<(P + 3) / 4, 256, 0, stream>>>(
      UV, pairs, sbv, We2, be2, (float*)d_out + (size_t)N * 4, P);
}

// Round 5
// 737.272 us; speedup vs baseline: 1.2690x; 1.2690x over previous
//
#include <hip/hip_runtime.h>
#include <math.h>

// GNN_2_Model: fused-embed -> GAT1 -> GAT2(+res) -> gid head & edge head.
// Round 5: GEMM rebuilt on global_load_lds (m97 structure):
//  - A and B staged via __builtin_amdgcn_global_load_lds width=16 (no reg round-trip,
//    no ds_write, no staging VGPRs). Fragment layout is lane-k-contiguous; the implied
//    k-permutation is applied identically to A (per-lane addresses) and B (wpack).
//  - C written via LDS [128][132] tile -> coalesced uint4 stores (kills 2B-store RMW amp).
//  - XCD-co-locating swizzle: all NT col-tiles of a row-band -> same XCD (A L2 reuse).
//  - gid GEMM fused into UV GEMM (same A=h2, Ncols=768, split epilogue).
// ws: X0 [N,832] | featB/UV [N,512] | h1 [N,512] | h2 [N,512] | W1p | W2p | Bh(768x512)
//   | sa_ext[512] sb[256] | el,er f32 [N,4] | offsets [N+1] | counts [N] | csr_src [E]
//   g_tmp bf16 [N,256] reuses X0.

typedef __attribute__((ext_vector_type(8))) short short8;   // 8 x bf16 (4 VGPR)
typedef __attribute__((ext_vector_type(4))) float f32x4;    // MFMA accum
typedef unsigned short ushort;

#define GLOAD16(g, l)                                                   \
  __builtin_amdgcn_global_load_lds(                                     \
      (const __attribute__((address_space(1))) unsigned int*)(g),       \
      (__attribute__((address_space(3))) unsigned int*)(l), 16, 0, 0)

__device__ __forceinline__ float b2f(ushort h) {
  union { unsigned u; float f; } v; v.u = ((unsigned)h) << 16; return v.f;
}
__device__ __forceinline__ ushort f2b(float f) {
  union { float f; unsigned u; } v; v.f = f;
  unsigned r = v.u + 0x7fffu + ((v.u >> 16) & 1u);  // round-to-nearest-even
  return (ushort)(r >> 16);
}
__device__ __forceinline__ void up4(uint2 q, float* o) {
  o[0] = b2f((ushort)(q.x & 0xffffu)); o[1] = b2f((ushort)(q.x >> 16));
  o[2] = b2f((ushort)(q.y & 0xffffu)); o[3] = b2f((ushort)(q.y >> 16));
}
__device__ __forceinline__ void up8(uint4 q, float* o) {
  o[0] = b2f((ushort)(q.x & 0xffffu)); o[1] = b2f((ushort)(q.x >> 16));
  o[2] = b2f((ushort)(q.y & 0xffffu)); o[3] = b2f((ushort)(q.y >> 16));
  o[4] = b2f((ushort)(q.z & 0xffffu)); o[5] = b2f((ushort)(q.z >> 16));
  o[6] = b2f((ushort)(q.w & 0xffffu)); o[7] = b2f((ushort)(q.w >> 16));
}
__device__ __forceinline__ uint4 pk8(const float* o) {
  uint4 q;
  q.x = (unsigned)f2b(o[0]) | ((unsigned)f2b(o[1]) << 16);
  q.y = (unsigned)f2b(o[2]) | ((unsigned)f2b(o[3]) << 16);
  q.z = (unsigned)f2b(o[4]) | ((unsigned)f2b(o[5]) << 16);
  q.w = (unsigned)f2b(o[6]) | ((unsigned)f2b(o[7]) << 16);
  return q;
}
__device__ __forceinline__ float warp_sum(float v) {
#pragma unroll
  for (int o = 32; o > 0; o >>= 1) v += __shfl_xor(v, o);
  return v;
}

// ---------------- fused embedding -> X0 bf16 [N,832] ----------------
__global__ __launch_bounds__(256) void embed_kernel(
    const float* __restrict__ cell_h, const float* __restrict__ pos_emb,
    const float* __restrict__ mf_emb,
    const int* __restrict__ row_pos, const int* __restrict__ col_pos,
    const int* __restrict__ row_mf, const int* __restrict__ col_mf,
    ushort* __restrict__ X0, int N)
{
  const int idx = blockIdx.x * 256 + threadIdx.x;
  const int total = N * 104;  // 832/8 chunks per node
  if (idx >= total) return;
  const int n = idx / 104;
  const int c8 = (idx - n * 104) * 8;
  float o[8];
  if (c8 < 768) {
    const int rp = row_pos[n], cp = col_pos[n];
    const float4* pc = (const float4*)(cell_h + (size_t)n * 768 + c8);
    const float4* pr = (const float4*)(pos_emb + (size_t)rp * 768 + c8);
    const float4* pq = (const float4*)(pos_emb + (size_t)cp * 768 + c8);
    float4 c0 = pc[0], c1 = pc[1], r0 = pr[0], r1 = pr[1], q0 = pq[0], q1 = pq[1];
    o[0] = c0.x + r0.x + q0.x; o[1] = c0.y + r0.y + q0.y;
    o[2] = c0.z + r0.z + q0.z; o[3] = c0.w + r0.w + q0.w;
    o[4] = c1.x + r1.x + q1.x; o[5] = c1.y + r1.y + q1.y;
    o[6] = c1.z + r1.z + q1.z; o[7] = c1.w + r1.w + q1.w;
  } else {
    const int rm = min(row_mf[n], 5), cm = min(col_mf[n], 5);
    const int j0 = c8 - 768;
    const float4* pr = (const float4*)(mf_emb + (size_t)rm * 64 + j0);
    const float4* pq = (const float4*)(mf_emb + (size_t)cm * 64 + j0);
    float4 r0 = pr[0], r1 = pr[1], q0 = pq[0], q1 = pq[1];
    o[0] = r0.x + q0.x; o[1] = r0.y + q0.y; o[2] = r0.z + q0.z; o[3] = r0.w + q0.w;
    o[4] = r1.x + q1.x; o[5] = r1.y + q1.y; o[6] = r1.z + q1.z; o[7] = r1.w + q1.w;
  }
  *(uint4*)(X0 + (size_t)n * 832 + c8) = pk8(o);
}

// ------- weight pack: source W[K][srcN] f32, element (k,c) -> virtual col n=colBase+c.
// Packed layout (lane-k-contiguous frags): tile (tn=n>>7, tk=k>>6); sub=((n>>4)&7)*2+((k>>5)&1);
// lane=(n&15)|(((k>>3)&3)<<4); j=k&7; off=((tn*nTK+tk)*16+sub)*512 + lane*8 + j.
__global__ __launch_bounds__(256) void wpack_kernel(
    const float* __restrict__ W, ushort* __restrict__ Wp,
    int K, int srcN, int colBase, int nTK)
{
  const int idx = blockIdx.x * 256 + threadIdx.x;
  if (idx >= K * srcN) return;
  const int c = idx / K, k = idx - c * K;
  const int n = colBase + c;
  const int tn = n >> 7, tk = k >> 6;
  const int sub = (((n >> 4) & 7) << 1) | ((k >> 5) & 1);
  const int lane = (n & 15) | (((k >> 3) & 3) << 4);
  const int j = k & 7;
  const size_t off = (((size_t)(tn * nTK + tk) << 4) + sub) * 512 + lane * 8 + j;
  Wp[off] = f2b(W[(size_t)k * srcN + c]);
}

// ---- fold edge-head BN into per-channel scale/shift: sa (applied in GEMM), sb ----
__global__ void eprep_kernel(const float* __restrict__ be1,
                             const float* __restrict__ eg, const float* __restrict__ eb,
                             const float* __restrict__ em, const float* __restrict__ ev,
                             float* __restrict__ sa_ext, float* __restrict__ sb)
{
  const int c = threadIdx.x;  // 256
  const float sa = eg[c] * rsqrtf(ev[c] + 1e-5f);
  sa_ext[c] = sa;
  sa_ext[c + 256] = sa;
  sb[c] = eb[c] + (be1[c] - em[c]) * sa;
}

// ---------------- bf16 MFMA GEMM (global_load_lds staging) ----------------
// 128x128 tile, BK=64, 4 waves (2x2 of 64x64). EPI 0: plain -> C0[M][Ncols].
// EPI 1 (HEADS): cols<256 BN+ReLU -> C0[M][256]; cols>=256 *sa_ext -> C1[M][512].
template <int EPI>
__global__ __launch_bounds__(256) void mfma_gemm_kernel(
    const ushort* __restrict__ A, const ushort* __restrict__ Bp,
    ushort* __restrict__ C0, ushort* __restrict__ C1,
    int M, int K, int Ncols, int NT, int mtiles,
    const float* __restrict__ bias, const float* __restrict__ gamma,
    const float* __restrict__ beta, const float* __restrict__ mean,
    const float* __restrict__ var, const float* __restrict__ sa_ext)
{
  __shared__ ushort LDS[16896];  // staging: As=[0,8192), Bs=[8192,16384); epi: [128][132]
  ushort* As = LDS;
  ushort* Bs = LDS + 8192;
  const int tid = threadIdx.x;
  const int lane = tid & 63;
  const int wave = tid >> 6;
  const int wm = wave >> 1, wn = wave & 1;

  // XCD-co-locating swizzle: supergroup = 8 row-bands x NT col-tiles; within a full
  // supergroup, position p = band + 8*colt -> XCD p%8 = band, so all NT column blocks
  // of a band share one XCD's L2. Tail supergroup decoded bijectively.
  const int per = NT << 3;
  const int f = blockIdx.x;
  const int sg = f / per;
  const int rem = f - sg * per;
  const int nb = min(8, mtiles - (sg << 3));
  const int band = rem % nb, colt = rem / nb;
  const int m0 = ((sg << 3) + band) << 7;
  const int n0 = colt << 7;
  const int nTK = K >> 6;

  // per-lane A source addresses for this wave's 4 subtiles (a = wave*4+q):
  // row = m0 + (a>>1)*16 + (lane&15); k = k0 + (a&1)*32 + (lane>>4)*8
  const int rA = lane & 15;
  const int kA = (lane >> 4) << 3;
  const ushort* Aaddr[4];
#pragma unroll
  for (int q = 0; q < 4; ++q) {
    const int a = (wave << 2) + q;
    int row = m0 + ((a >> 1) << 4) + rA;
    if (row >= M) row = 0;  // clamp: garbage rows never stored
    Aaddr[q] = A + (size_t)row * K + ((a & 1) << 5) + kA;
  }
  const ushort* Baddr = Bp + (((size_t)colt * nTK) << 13)
                        + ((size_t)(wave << 2) << 9) + (lane << 3);

  f32x4 acc[4][4];
#pragma unroll
  for (int i = 0; i < 4; ++i)
#pragma unroll
    for (int j = 0; j < 4; ++j) acc[i][j] = (f32x4){0.f, 0.f, 0.f, 0.f};

  for (int k0 = 0; k0 < K; k0 += 64) {
    __syncthreads();  // previous tile's frags consumed
#pragma unroll
    for (int q = 0; q < 4; ++q)
      GLOAD16(Aaddr[q] + k0, As + (((wave << 2) + q) << 9));
#pragma unroll
    for (int q = 0; q < 4; ++q)
      GLOAD16(Baddr + (((size_t)(k0 >> 6)) << 13) + (q << 9),
              Bs + (((wave << 2) + q) << 9));
    __syncthreads();  // compiler drains vmcnt before barrier -> LDS valid
#pragma unroll
    for (int ks = 0; ks < 2; ++ks) {
      short8 af[4], bf4[4];
#pragma unroll
      for (int x = 0; x < 4; ++x)
        af[x] = *(const short8*)(As + ((((wm << 2) + x) * 2 + ks) << 9) + (lane << 3));
#pragma unroll
      for (int x = 0; x < 4; ++x)
        bf4[x] = *(const short8*)(Bs + ((((wn << 2) + x) * 2 + ks) << 9) + (lane << 3));
#pragma unroll
      for (int mf = 0; mf < 4; ++mf)
#pragma unroll
        for (int nf = 0; nf < 4; ++nf)
          acc[mf][nf] = __builtin_amdgcn_mfma_f32_16x16x32_bf16(
              af[mf], bf4[nf], acc[mf][nf], 0, 0, 0);
    }
  }

  // ---- epilogue: acc -> LDS[128][132] bf16 (conflict-free), then coalesced stores ----
  __syncthreads();
#pragma unroll
  for (int nf = 0; nf < 4; ++nf) {
    const int cl = (((wn << 2) + nf) << 4) + (lane & 15);
    const int col = n0 + cl;
    float sa = 1.f, sb = 0.f;
    bool dorelu = false;
    if (EPI == 1) {
      if (col < 256) {
        const float rs = rsqrtf(var[col] + 1e-5f);
        sa = rs * gamma[col];
        sb = beta[col] + (bias[col] - mean[col]) * sa;
        dorelu = true;
      } else {
        sa = sa_ext[col - 256];
      }
    }
#pragma unroll
    for (int mf = 0; mf < 4; ++mf) {
      const int rl = (((wm << 2) + mf) << 4) + ((lane >> 4) << 2);
#pragma unroll
      for (int j = 0; j < 4; ++j) {
        float v = acc[mf][nf][j];
        if (EPI == 1) { v = fmaf(v, sa, sb); if (dorelu) v = fmaxf(v, 0.f); }
        LDS[(rl + j) * 132 + cl] = f2b(v);
      }
    }
  }
  __syncthreads();
#pragma unroll
  for (int i = 0; i < 8; ++i) {
    const int g = tid + (i << 8);          // 2048 granules of 16B
    const int r = g >> 4, c8 = g & 15;
    const int row = m0 + r;
    if (row >= M) continue;
    const uint4 v = *(const uint4*)(LDS + r * 132 + (c8 << 3));
    const int col = n0 + (c8 << 3);
    if (EPI == 0) {
      *(uint4*)(C0 + (size_t)row * Ncols + col) = v;
    } else {
      if (col < 256) *(uint4*)(C0 + (size_t)row * 256 + col) = v;
      else           *(uint4*)(C1 + (size_t)row * 512 + (col - 256)) = v;
    }
  }
}

// el[n,h] = sum_d feat[n,h,d]*al[h,d]; er likewise. One wave per node. feat bf16.
__global__ __launch_bounds__(256) void elr_kernel(
    const ushort* __restrict__ feat, const float* __restrict__ al,
    const float* __restrict__ ar, float* __restrict__ el, float* __restrict__ er, int N)
{
  const int wv = (blockIdx.x * 256 + threadIdx.x) >> 6;
  const int lane = threadIdx.x & 63;
  if (wv >= N) return;
  const ushort* f = feat + (size_t)wv * 512;
#pragma unroll
  for (int h = 0; h < 4; h++) {
    const float x0 = b2f(f[h * 128 + lane]);
    const float x1 = b2f(f[h * 128 + 64 + lane]);
    float sl = x0 * al[h * 128 + lane] + x1 * al[h * 128 + 64 + lane];
    float sr = x0 * ar[h * 128 + lane] + x1 * ar[h * 128 + 64 + lane];
    sl = warp_sum(sl);
    sr = warp_sum(sr);
    if (lane == 0) { el[(size_t)wv * 4 + h] = sl; er[(size_t)wv * 4 + h] = sr; }
  }
}

// ---------------- CSR build (by dst), done once ----------------
__global__ __launch_bounds__(256) void hist_kernel(
    const int* __restrict__ dst, int* __restrict__ counts, int E)
{
  const int e = blockIdx.x * 256 + threadIdx.x;
  if (e < E) atomicAdd(counts + dst[e], 1);
}

__global__ __launch_bounds__(1024) void scan_kernel(
    const int* __restrict__ counts, int* __restrict__ offsets, int N)
{
  __shared__ int sums[1024];
  const int t = threadIdx.x;
  const int chunk = (N + 1023) >> 10;
  const int beg = t * chunk;
  const int end = min(beg + chunk, N);
  int s = 0;
  for (int i = beg; i < end; ++i) s += counts[i];
  sums[t] = s;
  __syncthreads();
  for (int o = 1; o < 1024; o <<= 1) {
    int u = (t >= o) ? sums[t - o] : 0;
    __syncthreads();
    sums[t] += u;
    __syncthreads();
  }
  int run = sums[t] - s;
  for (int i = beg; i < end; ++i) { offsets[i] = run; run += counts[i]; }
  if (t == 1023) offsets[N] = sums[1023];
}

__global__ __launch_bounds__(256) void scatter_kernel(
    const int* __restrict__ src, const int* __restrict__ dst,
    const int* __restrict__ offsets, int* __restrict__ cursor,
    int* __restrict__ csr_src, int E)
{
  const int e = blockIdx.x * 256 + threadIdx.x;
  if (e >= E) return;
  const int d = dst[e];
  const int pos = offsets[d] + atomicAdd(cursor + d, 1);
  csr_src[pos] = src[e];
}

// ---------------- GAT aggregate: one wave per dst node (uint4 gathers) ----------------
template <bool RES>
__global__ __launch_bounds__(256) void gat_aggregate_kernel(
    const int* __restrict__ csr_src, const int* __restrict__ offsets,
    const float* __restrict__ el, const float* __restrict__ er,
    const ushort* __restrict__ feat, const float* __restrict__ bias,
    const ushort* __restrict__ resid, ushort* __restrict__ out, int N)
{
  const int node = (blockIdx.x * 256 + threadIdx.x) >> 6;
  const int lane = threadIdx.x & 63;
  if (node >= N) return;
  const int beg = offsets[node], end = offsets[node + 1];
  const float4 erd = *(const float4*)(er + (size_t)node * 4);

  // pass 1: softmax denominators
  float d0 = 0.f, d1 = 0.f, d2 = 0.f, d3 = 0.f;
  for (int i = beg + lane; i < end; i += 64) {
    const int s = csr_src[i];
    const float4 l = *(const float4*)(el + (size_t)s * 4);
    float x0 = l.x + erd.x, x1 = l.y + erd.y, x2 = l.z + erd.z, x3 = l.w + erd.w;
    x0 = x0 > 0.f ? x0 : 0.2f * x0;
    x1 = x1 > 0.f ? x1 : 0.2f * x1;
    x2 = x2 > 0.f ? x2 : 0.2f * x2;
    x3 = x3 > 0.f ? x3 : 0.2f * x3;
    d0 += __expf(x0); d1 += __expf(x1); d2 += __expf(x2); d3 += __expf(x3);
  }
  d0 = warp_sum(d0); d1 = warp_sum(d1); d2 = warp_sum(d2); d3 = warp_sum(d3);
  const float r0 = 1.f / d0, r1 = 1.f / d1, r2 = 1.f / d2, r3 = 1.f / d3;

  // pass 2: lane owns feats [lane*8, +8) — single head h = lane>>4
  float a[8] = {0.f, 0.f, 0.f, 0.f, 0.f, 0.f, 0.f, 0.f};
  for (int i = beg; i < end; ++i) {
    const int s = csr_src[i];  // uniform across wave
    const float4 l = *(const float4*)(el + (size_t)s * 4);
    float x0 = l.x + erd.x, x1 = l.y + erd.y, x2 = l.z + erd.z, x3 = l.w + erd.w;
    x0 = x0 > 0.f ? x0 : 0.2f * x0;
    x1 = x1 > 0.f ? x1 : 0.2f * x1;
    x2 = x2 > 0.f ? x2 : 0.2f * x2;
    x3 = x3 > 0.f ? x3 : 0.2f * x3;
    const float al0 = __expf(x0) * r0, al1 = __expf(x1) * r1;
    const float al2 = __expf(x2) * r2, al3 = __expf(x3) * r3;
    const float aw = (lane & 32) ? ((lane & 16) ? al3 : al2)
                                 : ((lane & 16) ? al1 : al0);
    const uint4 q = *(const uint4*)(feat + (size_t)s * 512 + lane * 8);
    float v[8];
    up8(q, v);
#pragma unroll
    for (int j = 0; j < 8; ++j) a[j] = fmaf(v[j], aw, a[j]);
  }

  const float4 b0 = *(const float4*)(bias + lane * 8);
  const float4 b1 = *(const float4*)(bias + lane * 8 + 4);
  a[0] += b0.x; a[1] += b0.y; a[2] += b0.z; a[3] += b0.w;
  a[4] += b1.x; a[5] += b1.y; a[6] += b1.z; a[7] += b1.w;
  if (RES) {
    float q[8];
    up8(*(const uint4*)(resid + (size_t)node * 512 + lane * 8), q);
#pragma unroll
    for (int j = 0; j < 8; ++j) a[j] += q[j];
  }
  *(uint4*)(out + (size_t)node * 512 + lane * 8) = pk8(a);
}

// gid logits: one wave per node; g bf16 [N,256] @ Wg2[256,4] + bg2.
__global__ __launch_bounds__(256) void gid2_kernel(
    const ushort* __restrict__ g, const float* __restrict__ Wg2,
    const float* __restrict__ bg2, float* __restrict__ out, int N)
{
  const int wv = (blockIdx.x * 256 + threadIdx.x) >> 6;
  const int lane = threadIdx.x & 63;
  if (wv >= N) return;
  float ga[4];
  up4(*(const uint2*)(g + (size_t)wv * 256 + lane * 4), ga);
  float a0 = 0.f, a1 = 0.f, a2 = 0.f, a3 = 0.f;
  const float* wp = Wg2 + (size_t)lane * 16;
#pragma unroll
  for (int j = 0; j < 4; j++) {
    const float4 w = *(const float4*)(wp + j * 4);
    a0 += ga[j] * w.x; a1 += ga[j] * w.y; a2 += ga[j] * w.z; a3 += ga[j] * w.w;
  }
  a0 = warp_sum(a0); a1 = warp_sum(a1); a2 = warp_sum(a2); a3 = warp_sum(a3);
  if (lane == 0) {
    float4 o = {a0 + bg2[0], a1 + bg2[1], a2 + bg2[2], a3 + bg2[3]};
    *(float4*)(out + (size_t)wv * 4) = o;
  }
}

// edge logits: one wave per pair over UV (bf16, scale pre-applied):
// logit = sum_c relu(U'[p0][c] + V'[p1][c] + sb[c]) * We2[c] + be2
__global__ __launch_bounds__(256) void pair_combine_kernel(
    const ushort* __restrict__ UV, const int* __restrict__ pairs,
    const float* __restrict__ sb, const float* __restrict__ We2,
    const float* __restrict__ be2, float* __restrict__ out, int P)
{
  const int wv = (blockIdx.x * 256 + threadIdx.x) >> 6;
  const int lane = threadIdx.x & 63;
  if (wv >= P) return;
  const int p0 = pairs[2 * wv], p1 = pairs[2 * wv + 1];
  float u[4], v[4];
  up4(*(const uint2*)(UV + (size_t)p0 * 512 + lane * 4), u);
  up4(*(const uint2*)(UV + (size_t)p1 * 512 + 256 + lane * 4), v);
  const float4 sbv = *(const float4*)(sb + lane * 4);
  const float4 w2 = *(const float4*)(We2 + lane * 4);
  float s = fmaxf(u[0] + v[0] + sbv.x, 0.f) * w2.x
          + fmaxf(u[1] + v[1] + sbv.y, 0.f) * w2.y
          + fmaxf(u[2] + v[2] + sbv.z, 0.f) * w2.z
          + fmaxf(u[3] + v[3] + sbv.w, 0.f) * w2.w;
  s = warp_sum(s);
  if (lane == 0) out[wv] = s + be2[0];
}

extern "C" void kernel_launch(void* const* d_in, const int* in_sizes, int n_in,
                              void* d_out, int out_size, void* d_ws, size_t ws_size,
                              hipStream_t stream) {
  const float* cell_h  = (const float*)d_in[0];
  const float* pos_emb = (const float*)d_in[1];
  const float* mf_emb  = (const float*)d_in[2];
  const float* W1  = (const float*)d_in[3];
  const float* al1 = (const float*)d_in[4];
  const float* ar1 = (const float*)d_in[5];
  const float* b1  = (const float*)d_in[6];
  const float* W2  = (const float*)d_in[7];
  const float* al2 = (const float*)d_in[8];
  const float* ar2 = (const float*)d_in[9];
  const float* b2  = (const float*)d_in[10];
  const float* Wg1 = (const float*)d_in[11];
  const float* bg1 = (const float*)d_in[12];
  const float* g_gamma = (const float*)d_in[13];
  const float* g_beta  = (const float*)d_in[14];
  const float* g_mean  = (const float*)d_in[15];
  const float* g_var   = (const float*)d_in[16];
  const float* Wg2 = (const float*)d_in[17];
  const float* bg2 = (const float*)d_in[18];
  const float* We1 = (const float*)d_in[19];
  const float* be1 = (const float*)d_in[20];
  const float* e_gamma = (const float*)d_in[21];
  const float* e_beta  = (const float*)d_in[22];
  const float* e_mean  = (const float*)d_in[23];
  const float* e_var   = (const float*)d_in[24];
  const float* We2 = (const float*)d_in[25];
  const float* be2 = (const float*)d_in[26];
  const int* src = (const int*)d_in[27];
  const int* dst = (const int*)d_in[28];
  const int* row_pos = (const int*)d_in[29];
  const int* col_pos = (const int*)d_in[30];
  const int* row_mf  = (const int*)d_in[31];
  const int* col_mf  = (const int*)d_in[32];
  const int* pairs   = (const int*)d_in[33];

  const int N = in_sizes[0] / 768;
  const int E = in_sizes[27];
  const int P = in_sizes[33] / 2;

  ushort* X0    = (ushort*)d_ws;                 // [N,832]
  ushort* featB = X0 + (size_t)N * 832;          // [N,512] (later reused as UV)
  ushort* h1    = featB + (size_t)N * 512;       // [N,512]
  ushort* h2    = h1 + (size_t)N * 512;          // [N,512]
  ushort* W1p   = h2 + (size_t)N * 512;          // packed [512 cols,832 k]
  ushort* W2p   = W1p + 512 * 832;               // packed [512,512]
  ushort* Bh    = W2p + 512 * 512;               // packed heads [768 cols,512 k]
  float* sa_ext = (float*)(Bh + 768 * 512);      // [512]
  float* sbv    = sa_ext + 512;                  // [256]
  float* el     = sbv + 256;                     // [N,4]
  float* er     = el + (size_t)N * 4;            // [N,4]
  int* offsets  = (int*)(er + (size_t)N * 4);    // [N+1]
  int* counts   = offsets + (N + 1);             // [N]
  int* csr_src  = counts + N;                    // [E]
  ushort* g_tmp = X0;                            // [N,256] (X0 dead after GEMM1)
  ushort* UV    = featB;                         // [N,512] (featB dead after agg2)

  const int nodeWaves = (N + 3) / 4;
  const int mtiles = (N + 127) / 128;

  // ---- CSR build (once) ----
  hipMemsetAsync(counts, 0, (size_t)N * sizeof(int), stream);
  hist_kernel<<<(E + 255) / 256, 256, 0, stream>>>(dst, counts, E);
  scan_kernel<<<1, 1024, 0, stream>>>(counts, offsets, N);
  hipMemsetAsync(counts, 0, (size_t)N * sizeof(int), stream);
  scatter_kernel<<<(E + 255) / 256, 256, 0, stream>>>(src, dst, offsets, counts, csr_src, E);

  // ---- weights -> packed bf16 fragment tiles ----
  wpack_kernel<<<(512 * 832 + 255) / 256, 256, 0, stream>>>(W1, W1p, 832, 512, 0, 13);
  wpack_kernel<<<(512 * 512 + 255) / 256, 256, 0, stream>>>(W2, W2p, 512, 512, 0, 8);
  wpack_kernel<<<(512 * 256 + 255) / 256, 256, 0, stream>>>(Wg1, Bh, 512, 256, 0, 8);
  wpack_kernel<<<(512 * 256 + 255) / 256, 256, 0, stream>>>(We1, Bh, 512, 256, 256, 8);
  wpack_kernel<<<(512 * 256 + 255) / 256, 256, 0, stream>>>(We1 + 512 * 256, Bh, 512, 256, 512, 8);
  eprep_kernel<<<1, 256, 0, stream>>>(be1, e_gamma, e_beta, e_mean, e_var, sa_ext, sbv);

  // ---- fused embedding -> X0 bf16 ----
  embed_kernel<<<(N * 104 + 255) / 256, 256, 0, stream>>>(
      cell_h, pos_emb, mf_emb, row_pos, col_pos, row_mf, col_mf, X0, N);

  // ---- GAT layer 1 ----
  mfma_gemm_kernel<0><<<mtiles * 4, 256, 0, stream>>>(
      X0, W1p, featB, nullptr, N, 832, 512, 4, mtiles,
      nullptr, nullptr, nullptr, nullptr, nullptr, nullptr);
  elr_kernel<<<nodeWaves, 256, 0, stream>>>(featB, al1, ar1, el, er, N);
  gat_aggregate_kernel<false><<<nodeWaves, 256, 0, stream>>>(
      csr_src, offsets, el, er, featB, b1, nullptr, h1, N);

  // ---- GAT layer 2 (identity residual) ----
  mfma_gemm_kernel<0><<<mtiles * 4, 256, 0, stream>>>(
      h1, W2p, featB, nullptr, N, 512, 512, 4, mtiles,
      nullptr, nullptr, nullptr, nullptr, nullptr, nullptr);
  elr_kernel<<<nodeWaves, 256, 0, stream>>>(featB, al2, ar2, el, er, N);
  gat_aggregate_kernel<true><<<nodeWaves, 256, 0, stream>>>(
      csr_src, offsets, el, er, featB, b2, h1, h2, N);

  // ---- fused heads GEMM: [g_tmp | UV] = h2 @ [Wg1 | We1_top | We1_bot] ----
  mfma_gemm_kernel<1><<<mtiles * 6, 256, 0, stream>>>(
      h2, Bh, g_tmp, UV, N, 512, 0, 6, mtiles,
      bg1, g_gamma, g_beta, g_mean, g_var, sa_ext);
  gid2_kernel<<<nodeWaves, 256, 0, stream>>>(g_tmp, Wg2, bg2, (float*)d_out, N);
  pair_combine_kernel<<<(P + 3) / 4, 256, 0, stream>>>(
      UV, pairs, sbv, We2, be2, (float*)d_out + (size_t)N * 4, P);
}

// Round 6
// 622.152 us; speedup vs baseline: 1.5038x; 1.1850x over previous
//
#include <hip/hip_runtime.h>
#include <math.h>

// GNN_2_Model: fused-embed -> GAT1 -> GAT2(+res) -> gid head & edge head.
// Round 6:
//  - gat_aggregate: lane-parallel edge-weight precompute into per-wave LDS
//    (phase A: 1 edge/lane, stash ee[4]+src for first 256 edges; phase B inner
//    loop = broadcast ds_read + gather + fma, no redundant exp).
//  - elr fused into layer-GEMM epilogue (each 128-col tile == one head, so
//    el/er computed completely from the LDS output tile; elr kernel deleted).
//  - pair_combine: half-wave (32 lanes) per pair.
// GEMM structure unchanged from round 5 (global_load_lds, LDS epilogue, XCD swizzle).

typedef __attribute__((ext_vector_type(8))) short short8;   // 8 x bf16 (4 VGPR)
typedef __attribute__((ext_vector_type(4))) float f32x4;    // MFMA accum
typedef unsigned short ushort;

#define GLOAD16(g, l)                                                   \
  __builtin_amdgcn_global_load_lds(                                     \
      (const __attribute__((address_space(1))) unsigned int*)(g),       \
      (__attribute__((address_space(3))) unsigned int*)(l), 16, 0, 0)

__device__ __forceinline__ float b2f(ushort h) {
  union { unsigned u; float f; } v; v.u = ((unsigned)h) << 16; return v.f;
}
__device__ __forceinline__ ushort f2b(float f) {
  union { float f; unsigned u; } v; v.f = f;
  unsigned r = v.u + 0x7fffu + ((v.u >> 16) & 1u);  // round-to-nearest-even
  return (ushort)(r >> 16);
}
__device__ __forceinline__ void up4(uint2 q, float* o) {
  o[0] = b2f((ushort)(q.x & 0xffffu)); o[1] = b2f((ushort)(q.x >> 16));
  o[2] = b2f((ushort)(q.y & 0xffffu)); o[3] = b2f((ushort)(q.y >> 16));
}
__device__ __forceinline__ void up8(uint4 q, float* o) {
  o[0] = b2f((ushort)(q.x & 0xffffu)); o[1] = b2f((ushort)(q.x >> 16));
  o[2] = b2f((ushort)(q.y & 0xffffu)); o[3] = b2f((ushort)(q.y >> 16));
  o[4] = b2f((ushort)(q.z & 0xffffu)); o[5] = b2f((ushort)(q.z >> 16));
  o[6] = b2f((ushort)(q.w & 0xffffu)); o[7] = b2f((ushort)(q.w >> 16));
}
__device__ __forceinline__ uint4 pk8(const float* o) {
  uint4 q;
  q.x = (unsigned)f2b(o[0]) | ((unsigned)f2b(o[1]) << 16);
  q.y = (unsigned)f2b(o[2]) | ((unsigned)f2b(o[3]) << 16);
  q.z = (unsigned)f2b(o[4]) | ((unsigned)f2b(o[5]) << 16);
  q.w = (unsigned)f2b(o[6]) | ((unsigned)f2b(o[7]) << 16);
  return q;
}
__device__ __forceinline__ float warp_sum(float v) {
#pragma unroll
  for (int o = 32; o > 0; o >>= 1) v += __shfl_xor(v, o);
  return v;
}

// ---------------- fused embedding -> X0 bf16 [N,832] ----------------
__global__ __launch_bounds__(256) void embed_kernel(
    const float* __restrict__ cell_h, const float* __restrict__ pos_emb,
    const float* __restrict__ mf_emb,
    const int* __restrict__ row_pos, const int* __restrict__ col_pos,
    const int* __restrict__ row_mf, const int* __restrict__ col_mf,
    ushort* __restrict__ X0, int N)
{
  const int idx = blockIdx.x * 256 + threadIdx.x;
  const int total = N * 104;  // 832/8 chunks per node
  if (idx >= total) return;
  const int n = idx / 104;
  const int c8 = (idx - n * 104) * 8;
  float o[8];
  if (c8 < 768) {
    const int rp = row_pos[n], cp = col_pos[n];
    const float4* pc = (const float4*)(cell_h + (size_t)n * 768 + c8);
    const float4* pr = (const float4*)(pos_emb + (size_t)rp * 768 + c8);
    const float4* pq = (const float4*)(pos_emb + (size_t)cp * 768 + c8);
    float4 c0 = pc[0], c1 = pc[1], r0 = pr[0], r1 = pr[1], q0 = pq[0], q1 = pq[1];
    o[0] = c0.x + r0.x + q0.x; o[1] = c0.y + r0.y + q0.y;
    o[2] = c0.z + r0.z + q0.z; o[3] = c0.w + r0.w + q0.w;
    o[4] = c1.x + r1.x + q1.x; o[5] = c1.y + r1.y + q1.y;
    o[6] = c1.z + r1.z + q1.z; o[7] = c1.w + r1.w + q1.w;
  } else {
    const int rm = min(row_mf[n], 5), cm = min(col_mf[n], 5);
    const int j0 = c8 - 768;
    const float4* pr = (const float4*)(mf_emb + (size_t)rm * 64 + j0);
    const float4* pq = (const float4*)(mf_emb + (size_t)cm * 64 + j0);
    float4 r0 = pr[0], r1 = pr[1], q0 = pq[0], q1 = pq[1];
    o[0] = r0.x + q0.x; o[1] = r0.y + q0.y; o[2] = r0.z + q0.z; o[3] = r0.w + q0.w;
    o[4] = r1.x + q1.x; o[5] = r1.y + q1.y; o[6] = r1.z + q1.z; o[7] = r1.w + q1.w;
  }
  *(uint4*)(X0 + (size_t)n * 832 + c8) = pk8(o);
}

// ------- weight pack: source W[K][srcN] f32, element (k,c) -> virtual col n=colBase+c.
// Packed layout (lane-k-contiguous frags): tile (tn=n>>7, tk=k>>6); sub=((n>>4)&7)*2+((k>>5)&1);
// lane=(n&15)|(((k>>3)&3)<<4); j=k&7; off=((tn*nTK+tk)*16+sub)*512 + lane*8 + j.
__global__ __launch_bounds__(256) void wpack_kernel(
    const float* __restrict__ W, ushort* __restrict__ Wp,
    int K, int srcN, int colBase, int nTK)
{
  const int idx = blockIdx.x * 256 + threadIdx.x;
  if (idx >= K * srcN) return;
  const int c = idx / K, k = idx - c * K;
  const int n = colBase + c;
  const int tn = n >> 7, tk = k >> 6;
  const int sub = (((n >> 4) & 7) << 1) | ((k >> 5) & 1);
  const int lane = (n & 15) | (((k >> 3) & 3) << 4);
  const int j = k & 7;
  const size_t off = (((size_t)(tn * nTK + tk) << 4) + sub) * 512 + lane * 8 + j;
  Wp[off] = f2b(W[(size_t)k * srcN + c]);
}

// ---- fold edge-head BN into per-channel scale/shift: sa (applied in GEMM), sb ----
__global__ void eprep_kernel(const float* __restrict__ be1,
                             const float* __restrict__ eg, const float* __restrict__ eb,
                             const float* __restrict__ em, const float* __restrict__ ev,
                             float* __restrict__ sa_ext, float* __restrict__ sb)
{
  const int c = threadIdx.x;  // 256
  const float sa = eg[c] * rsqrtf(ev[c] + 1e-5f);
  sa_ext[c] = sa;
  sa_ext[c + 256] = sa;
  sb[c] = eb[c] + (be1[c] - em[c]) * sa;
}

// ---------------- bf16 MFMA GEMM (global_load_lds staging) ----------------
// 128x128 tile, BK=64, 4 waves (2x2 of 64x64). EPI 0: plain -> C0[M][Ncols].
// EPI 1 (HEADS): cols<256 BN+ReLU -> C0[M][256]; cols>=256 *sa_ext -> C1[M][512].
// ELR: fused el/er (col tile == one head; complete per-block dot with al/ar).
template <int EPI, bool ELR>
__global__ __launch_bounds__(256) void mfma_gemm_kernel(
    const ushort* __restrict__ A, const ushort* __restrict__ Bp,
    ushort* __restrict__ C0, ushort* __restrict__ C1,
    int M, int K, int Ncols, int NT, int mtiles,
    const float* __restrict__ bias, const float* __restrict__ gamma,
    const float* __restrict__ beta, const float* __restrict__ mean,
    const float* __restrict__ var, const float* __restrict__ sa_ext,
    const float* __restrict__ al, const float* __restrict__ ar,
    float* __restrict__ elp, float* __restrict__ erp)
{
  __shared__ ushort LDS[16896];  // staging: As=[0,8192), Bs=[8192,16384); epi: [128][132]
  __shared__ float redS[256];    // ELR half-combine
  ushort* As = LDS;
  ushort* Bs = LDS + 8192;
  const int tid = threadIdx.x;
  const int lane = tid & 63;
  const int wave = tid >> 6;
  const int wm = wave >> 1, wn = wave & 1;

  // XCD-co-locating swizzle (bijective incl. tail supergroup).
  const int per = NT << 3;
  const int f = blockIdx.x;
  const int sg = f / per;
  const int rem = f - sg * per;
  const int nb = min(8, mtiles - (sg << 3));
  const int band = rem % nb, colt = rem / nb;
  const int m0 = ((sg << 3) + band) << 7;
  const int n0 = colt << 7;
  const int nTK = K >> 6;

  const int rA = lane & 15;
  const int kA = (lane >> 4) << 3;
  const ushort* Aaddr[4];
#pragma unroll
  for (int q = 0; q < 4; ++q) {
    const int a = (wave << 2) + q;
    int row = m0 + ((a >> 1) << 4) + rA;
    if (row >= M) row = 0;  // clamp: garbage rows never stored
    Aaddr[q] = A + (size_t)row * K + ((a & 1) << 5) + kA;
  }
  const ushort* Baddr = Bp + (((size_t)colt * nTK) << 13)
                        + ((size_t)(wave << 2) << 9) + (lane << 3);

  f32x4 acc[4][4];
#pragma unroll
  for (int i = 0; i < 4; ++i)
#pragma unroll
    for (int j = 0; j < 4; ++j) acc[i][j] = (f32x4){0.f, 0.f, 0.f, 0.f};

  for (int k0 = 0; k0 < K; k0 += 64) {
    __syncthreads();  // previous tile's frags consumed
#pragma unroll
    for (int q = 0; q < 4; ++q)
      GLOAD16(Aaddr[q] + k0, As + (((wave << 2) + q) << 9));
#pragma unroll
    for (int q = 0; q < 4; ++q)
      GLOAD16(Baddr + (((size_t)(k0 >> 6)) << 13) + (q << 9),
              Bs + (((wave << 2) + q) << 9));
    __syncthreads();  // compiler drains vmcnt before barrier -> LDS valid
#pragma unroll
    for (int ks = 0; ks < 2; ++ks) {
      short8 af[4], bf4[4];
#pragma unroll
      for (int x = 0; x < 4; ++x)
        af[x] = *(const short8*)(As + ((((wm << 2) + x) * 2 + ks) << 9) + (lane << 3));
#pragma unroll
      for (int x = 0; x < 4; ++x)
        bf4[x] = *(const short8*)(Bs + ((((wn << 2) + x) * 2 + ks) << 9) + (lane << 3));
#pragma unroll
      for (int mf = 0; mf < 4; ++mf)
#pragma unroll
        for (int nf = 0; nf < 4; ++nf)
          acc[mf][nf] = __builtin_amdgcn_mfma_f32_16x16x32_bf16(
              af[mf], bf4[nf], acc[mf][nf], 0, 0, 0);
    }
  }

  // ---- epilogue: acc -> LDS[128][132] bf16, then coalesced stores ----
  __syncthreads();
#pragma unroll
  for (int nf = 0; nf < 4; ++nf) {
    const int cl = (((wn << 2) + nf) << 4) + (lane & 15);
    const int col = n0 + cl;
    float sa = 1.f, sb = 0.f;
    bool dorelu = false;
    if (EPI == 1) {
      if (col < 256) {
        const float rs = rsqrtf(var[col] + 1e-5f);
        sa = rs * gamma[col];
        sb = beta[col] + (bias[col] - mean[col]) * sa;
        dorelu = true;
      } else {
        sa = sa_ext[col - 256];
      }
    }
#pragma unroll
    for (int mf = 0; mf < 4; ++mf) {
      const int rl = (((wm << 2) + mf) << 4) + ((lane >> 4) << 2);
#pragma unroll
      for (int j = 0; j < 4; ++j) {
        float v = acc[mf][nf][j];
        if (EPI == 1) { v = fmaf(v, sa, sb); if (dorelu) v = fmaxf(v, 0.f); }
        LDS[(rl + j) * 132 + cl] = f2b(v);
      }
    }
  }
  __syncthreads();
#pragma unroll
  for (int i = 0; i < 8; ++i) {
    const int g = tid + (i << 8);          // 2048 granules of 16B
    const int r = g >> 4, c8 = g & 15;
    const int row = m0 + r;
    if (row >= M) continue;
    const uint4 v = *(const uint4*)(LDS + r * 132 + (c8 << 3));
    const int col = n0 + (c8 << 3);
    if (EPI == 0) {
      *(uint4*)(C0 + (size_t)row * Ncols + col) = v;
    } else {
      if (col < 256) *(uint4*)(C0 + (size_t)row * 256 + col) = v;
      else           *(uint4*)(C1 + (size_t)row * 512 + (col - 256)) = v;
    }
  }

  // ---- fused elr: this col tile is head `colt`; complete dot over 128 cols ----
  if (ELR) {
    const int r = tid & 127;
    const int half = tid >> 7;
    const float* alh = al + colt * 128 + half * 64;
    const float* arh = ar + colt * 128 + half * 64;
    const ushort* rowp = LDS + r * 132 + half * 64;
    float sl = 0.f, sr = 0.f;
#pragma unroll
    for (int c = 0; c < 64; ++c) {
      const float v = b2f(rowp[c]);
      sl = fmaf(v, alh[c], sl);
      sr = fmaf(v, arh[c], sr);
    }
    if (half) { redS[r] = sl; redS[r + 128] = sr; }
    __syncthreads();
    if (!half) {
      const int row = m0 + r;
      if (row < M) {
        elp[(size_t)row * 4 + colt] = sl + redS[r];
        erp[(size_t)row * 4 + colt] = sr + redS[r + 128];
      }
    }
  }
}

// ---------------- CSR build (by dst), done once ----------------
__global__ __launch_bounds__(256) void hist_kernel(
    const int* __restrict__ dst, int* __restrict__ counts, int E)
{
  const int e = blockIdx.x * 256 + threadIdx.x;
  if (e < E) atomicAdd(counts + dst[e], 1);
}

__global__ __launch_bounds__(1024) void scan_kernel(
    const int* __restrict__ counts, int* __restrict__ offsets, int N)
{
  __shared__ int sums[1024];
  const int t = threadIdx.x;
  const int chunk = (N + 1023) >> 10;
  const int beg = t * chunk;
  const int end = min(beg + chunk, N);
  int s = 0;
  for (int i = beg; i < end; ++i) s += counts[i];
  sums[t] = s;
  __syncthreads();
  for (int o = 1; o < 1024; o <<= 1) {
    int u = (t >= o) ? sums[t - o] : 0;
    __syncthreads();
    sums[t] += u;
    __syncthreads();
  }
  int run = sums[t] - s;
  for (int i = beg; i < end; ++i) { offsets[i] = run; run += counts[i]; }
  if (t == 1023) offsets[N] = sums[1023];
}

__global__ __launch_bounds__(256) void scatter_kernel(
    const int* __restrict__ src, const int* __restrict__ dst,
    const int* __restrict__ offsets, int* __restrict__ cursor,
    int* __restrict__ csr_src, int E)
{
  const int e = blockIdx.x * 256 + threadIdx.x;
  if (e >= E) return;
  const int d = dst[e];
  const int pos = offsets[d] + atomicAdd(cursor + d, 1);
  csr_src[pos] = src[e];
}

// ---------------- GAT aggregate: one wave per dst node ----------------
// Phase A (lane-parallel, 1 edge/lane): ee=exp(leaky(el[s]+er[n])) for all 4 heads,
// stash ee+src in per-wave LDS (first 256 edges), accumulate denominators.
// Phase B (feature-parallel): per edge, weight = broadcast LDS read * rh; gather+fma.
template <bool RES>
__global__ __launch_bounds__(256) void gat_aggregate_kernel(
    const int* __restrict__ csr_src, const int* __restrict__ offsets,
    const float* __restrict__ el, const float* __restrict__ er,
    const ushort* __restrict__ feat, const float* __restrict__ bias,
    const ushort* __restrict__ resid, ushort* __restrict__ out, int N)
{
  __shared__ float eeS[4][1024];  // [wave][edge<256][head]
  __shared__ int sS[4][256];      // [wave][edge<256] src id
  const int w = threadIdx.x >> 6;
  const int node = (blockIdx.x * 256 + threadIdx.x) >> 6;
  const int lane = threadIdx.x & 63;
  if (node >= N) return;
  const int beg = offsets[node], end = offsets[node + 1];
  const int deg = end - beg;
  const float4 erd = *(const float4*)(er + (size_t)node * 4);
  float* eew = eeS[w];
  int* sw = sS[w];

  // phase A
  float d0 = 0.f, d1 = 0.f, d2 = 0.f, d3 = 0.f;
  for (int i = lane; i < deg; i += 64) {
    const int s = csr_src[beg + i];
    const float4 l = *(const float4*)(el + (size_t)s * 4);
    float x0 = l.x + erd.x, x1 = l.y + erd.y, x2 = l.z + erd.z, x3 = l.w + erd.w;
    x0 = x0 > 0.f ? x0 : 0.2f * x0;
    x1 = x1 > 0.f ? x1 : 0.2f * x1;
    x2 = x2 > 0.f ? x2 : 0.2f * x2;
    x3 = x3 > 0.f ? x3 : 0.2f * x3;
    const float e0 = __expf(x0), e1 = __expf(x1), e2 = __expf(x2), e3 = __expf(x3);
    if (i < 256) {
      float4 ev = {e0, e1, e2, e3};
      *(float4*)(eew + (i << 2)) = ev;
      sw[i] = s;
    }
    d0 += e0; d1 += e1; d2 += e2; d3 += e3;
  }
  d0 = warp_sum(d0); d1 = warp_sum(d1); d2 = warp_sum(d2); d3 = warp_sum(d3);
  const float r0 = 1.f / d0, r1 = 1.f / d1, r2 = 1.f / d2, r3 = 1.f / d3;
  const int h = lane >> 4;  // this lane's head (lane owns feats [lane*8,+8))
  const float rh = (lane & 32) ? ((lane & 16) ? r3 : r2) : ((lane & 16) ? r1 : r0);
  const float erh = (lane & 32) ? ((lane & 16) ? erd.w : erd.z)
                                : ((lane & 16) ? erd.y : erd.x);

  // phase B
  float a[8] = {0.f, 0.f, 0.f, 0.f, 0.f, 0.f, 0.f, 0.f};
  for (int i = 0; i < deg; ++i) {
    int s;
    float ew;
    if (i < 256) {
      s = sw[i];                       // broadcast LDS read
      ew = eew[(i << 2) | h];          // 4 addrs, 4 banks, broadcast
    } else {                           // rare overflow: recompute own head only
      s = csr_src[beg + i];
      float x = el[(size_t)s * 4 + h] + erh;
      x = x > 0.f ? x : 0.2f * x;
      ew = __expf(x);
    }
    const float aw = ew * rh;
    const uint4 q = *(const uint4*)(feat + (size_t)s * 512 + lane * 8);
    float v[8];
    up8(q, v);
#pragma unroll
    for (int j = 0; j < 8; ++j) a[j] = fmaf(v[j], aw, a[j]);
  }

  const float4 b0 = *(const float4*)(bias + lane * 8);
  const float4 b1 = *(const float4*)(bias + lane * 8 + 4);
  a[0] += b0.x; a[1] += b0.y; a[2] += b0.z; a[3] += b0.w;
  a[4] += b1.x; a[5] += b1.y; a[6] += b1.z; a[7] += b1.w;
  if (RES) {
    float q[8];
    up8(*(const uint4*)(resid + (size_t)node * 512 + lane * 8), q);
#pragma unroll
    for (int j = 0; j < 8; ++j) a[j] += q[j];
  }
  *(uint4*)(out + (size_t)node * 512 + lane * 8) = pk8(a);
}

// gid logits: one wave per node; g bf16 [N,256] @ Wg2[256,4] + bg2.
__global__ __launch_bounds__(256) void gid2_kernel(
    const ushort* __restrict__ g, const float* __restrict__ Wg2,
    const float* __restrict__ bg2, float* __restrict__ out, int N)
{
  const int wv = (blockIdx.x * 256 + threadIdx.x) >> 6;
  const int lane = threadIdx.x & 63;
  if (wv >= N) return;
  float ga[4];
  up4(*(const uint2*)(g + (size_t)wv * 256 + lane * 4), ga);
  float a0 = 0.f, a1 = 0.f, a2 = 0.f, a3 = 0.f;
  const float* wp = Wg2 + (size_t)lane * 16;
#pragma unroll
  for (int j = 0; j < 4; j++) {
    const float4 w = *(const float4*)(wp + j * 4);
    a0 += ga[j] * w.x; a1 += ga[j] * w.y; a2 += ga[j] * w.z; a3 += ga[j] * w.w;
  }
  a0 = warp_sum(a0); a1 = warp_sum(a1); a2 = warp_sum(a2); a3 = warp_sum(a3);
  if (lane == 0) {
    float4 o = {a0 + bg2[0], a1 + bg2[1], a2 + bg2[2], a3 + bg2[3]};
    *(float4*)(out + (size_t)wv * 4) = o;
  }
}

// edge logits: HALF-wave (32 lanes) per pair; 32 x uint4 = exactly one 256-col row.
// logit = sum_c relu(U'[p0][c] + V'[p1][c] + sb[c]) * We2[c] + be2
__global__ __launch_bounds__(256) void pair_combine_kernel(
    const ushort* __restrict__ UV, const int* __restrict__ pairs,
    const float* __restrict__ sb, const float* __restrict__ We2,
    const float* __restrict__ be2, float* __restrict__ out, int P)
{
  const int hw = (blockIdx.x * 256 + threadIdx.x) >> 5;
  const int l = threadIdx.x & 31;
  if (hw >= P) return;
  const int p0 = pairs[2 * hw], p1 = pairs[2 * hw + 1];
  float u[8], v[8];
  up8(*(const uint4*)(UV + (size_t)p0 * 512 + l * 8), u);
  up8(*(const uint4*)(UV + (size_t)p1 * 512 + 256 + l * 8), v);
  const float4 sb0 = *(const float4*)(sb + l * 8);
  const float4 sb1 = *(const float4*)(sb + l * 8 + 4);
  const float4 w0 = *(const float4*)(We2 + l * 8);
  const float4 w1 = *(const float4*)(We2 + l * 8 + 4);
  float s = fmaxf(u[0] + v[0] + sb0.x, 0.f) * w0.x
          + fmaxf(u[1] + v[1] + sb0.y, 0.f) * w0.y
          + fmaxf(u[2] + v[2] + sb0.z, 0.f) * w0.z
          + fmaxf(u[3] + v[3] + sb0.w, 0.f) * w0.w
          + fmaxf(u[4] + v[4] + sb1.x, 0.f) * w1.x
          + fmaxf(u[5] + v[5] + sb1.y, 0.f) * w1.y
          + fmaxf(u[6] + v[6] + sb1.z, 0.f) * w1.z
          + fmaxf(u[7] + v[7] + sb1.w, 0.f) * w1.w;
#pragma unroll
  for (int o = 16; o > 0; o >>= 1) s += __shfl_xor(s, o);
  if (l == 0) out[hw] = s + be2[0];
}

extern "C" void kernel_launch(void* const* d_in, const int* in_sizes, int n_in,
                              void* d_out, int out_size, void* d_ws, size_t ws_size,
                              hipStream_t stream) {
  const float* cell_h  = (const float*)d_in[0];
  const float* pos_emb = (const float*)d_in[1];
  const float* mf_emb  = (const float*)d_in[2];
  const float* W1  = (const float*)d_in[3];
  const float* al1 = (const float*)d_in[4];
  const float* ar1 = (const float*)d_in[5];
  const float* b1  = (const float*)d_in[6];
  const float* W2  = (const float*)d_in[7];
  const float* al2 = (const float*)d_in[8];
  const float* ar2 = (const float*)d_in[9];
  const float* b2  = (const float*)d_in[10];
  const float* Wg1 = (const float*)d_in[11];
  const float* bg1 = (const float*)d_in[12];
  const float* g_gamma = (const float*)d_in[13];
  const float* g_beta  = (const float*)d_in[14];
  const float* g_mean  = (const float*)d_in[15];
  const float* g_var   = (const float*)d_in[16];
  const float* Wg2 = (const float*)d_in[17];
  const float* bg2 = (const float*)d_in[18];
  const float* We1 = (const float*)d_in[19];
  const float* be1 = (const float*)d_in[20];
  const float* e_gamma = (const float*)d_in[21];
  const float* e_beta  = (const float*)d_in[22];
  const float* e_mean  = (const float*)d_in[23];
  const float* e_var   = (const float*)d_in[24];
  const float* We2 = (const float*)d_in[25];
  const float* be2 = (const float*)d_in[26];
  const int* src = (const int*)d_in[27];
  const int* dst = (const int*)d_in[28];
  const int* row_pos = (const int*)d_in[29];
  const int* col_pos = (const int*)d_in[30];
  const int* row_mf  = (const int*)d_in[31];
  const int* col_mf  = (const int*)d_in[32];
  const int* pairs   = (const int*)d_in[33];

  const int N = in_sizes[0] / 768;
  const int E = in_sizes[27];
  const int P = in_sizes[33] / 2;

  ushort* X0    = (ushort*)d_ws;                 // [N,832]
  ushort* featB = X0 + (size_t)N * 832;          // [N,512] (later reused as UV)
  ushort* h1    = featB + (size_t)N * 512;       // [N,512]
  ushort* h2    = h1 + (size_t)N * 512;          // [N,512]
  ushort* W1p   = h2 + (size_t)N * 512;          // packed [512 cols,832 k]
  ushort* W2p   = W1p + 512 * 832;               // packed [512,512]
  ushort* Bh    = W2p + 512 * 512;               // packed heads [768 cols,512 k]
  float* sa_ext = (float*)(Bh + 768 * 512);      // [512]
  float* sbv    = sa_ext + 512;                  // [256]
  float* el     = sbv + 256;                     // [N,4]
  float* er     = el + (size_t)N * 4;            // [N,4]
  int* offsets  = (int*)(er + (size_t)N * 4);    // [N+1]
  int* counts   = offsets + (N + 1);             // [N]
  int* csr_src  = counts + N;                    // [E]
  ushort* g_tmp = X0;                            // [N,256] (X0 dead after GEMM1)
  ushort* UV    = featB;                         // [N,512] (featB dead after agg2)

  const int nodeWaves = (N + 3) / 4;
  const int mtiles = (N + 127) / 128;

  // ---- CSR build (once) ----
  hipMemsetAsync(counts, 0, (size_t)N * sizeof(int), stream);
  hist_kernel<<<(E + 255) / 256, 256, 0, stream>>>(dst, counts, E);
  scan_kernel<<<1, 1024, 0, stream>>>(counts, offsets, N);
  hipMemsetAsync(counts, 0, (size_t)N * sizeof(int), stream);
  scatter_kernel<<<(E + 255) / 256, 256, 0, stream>>>(src, dst, offsets, counts, csr_src, E);

  // ---- weights -> packed bf16 fragment tiles ----
  wpack_kernel<<<(512 * 832 + 255) / 256, 256, 0, stream>>>(W1, W1p, 832, 512, 0, 13);
  wpack_kernel<<<(512 * 512 + 255) / 256, 256, 0, stream>>>(W2, W2p, 512, 512, 0, 8);
  wpack_kernel<<<(512 * 256 + 255) / 256, 256, 0, stream>>>(Wg1, Bh, 512, 256, 0, 8);
  wpack_kernel<<<(512 * 256 + 255) / 256, 256, 0, stream>>>(We1, Bh, 512, 256, 256, 8);
  wpack_kernel<<<(512 * 256 + 255) / 256, 256, 0, stream>>>(We1 + 512 * 256, Bh, 512, 256, 512, 8);
  eprep_kernel<<<1, 256, 0, stream>>>(be1, e_gamma, e_beta, e_mean, e_var, sa_ext, sbv);

  // ---- fused embedding -> X0 bf16 ----
  embed_kernel<<<(N * 104 + 255) / 256, 256, 0, stream>>>(
      cell_h, pos_emb, mf_emb, row_pos, col_pos, row_mf, col_mf, X0, N);

  // ---- GAT layer 1 (GEMM with fused elr) ----
  mfma_gemm_kernel<0, true><<<mtiles * 4, 256, 0, stream>>>(
      X0, W1p, featB, nullptr, N, 832, 512, 4, mtiles,
      nullptr, nullptr, nullptr, nullptr, nullptr, nullptr, al1, ar1, el, er);
  gat_aggregate_kernel<false><<<nodeWaves, 256, 0, stream>>>(
      csr_src, offsets, el, er, featB, b1, nullptr, h1, N);

  // ---- GAT layer 2 (identity residual) ----
  mfma_gemm_kernel<0, true><<<mtiles * 4, 256, 0, stream>>>(
      h1, W2p, featB, nullptr, N, 512, 512, 4, mtiles,
      nullptr, nullptr, nullptr, nullptr, nullptr, nullptr, al2, ar2, el, er);
  gat_aggregate_kernel<true><<<nodeWaves, 256, 0, stream>>>(
      csr_src, offsets, el, er, featB, b2, h1, h2, N);

  // ---- fused heads GEMM: [g_tmp | UV] = h2 @ [Wg1 | We1_top | We1_bot] ----
  mfma_gemm_kernel<1, false><<<mtiles * 6, 256, 0, stream>>>(
      h2, Bh, g_tmp, UV, N, 512, 0, 6, mtiles,
      bg1, g_gamma, g_beta, g_mean, g_var, sa_ext, nullptr, nullptr, nullptr, nullptr);
  gid2_kernel<<<nodeWaves, 256, 0, stream>>>(g_tmp, Wg2, bg2, (float*)d_out, N);
  pair_combine_kernel<<<(P + 7) / 8, 256, 0, stream>>>(
      UV, pairs, sbv, We2, be2, (float*)d_out + (size_t)N * 4, P);
}

// Round 7
// 610.673 us; speedup vs baseline: 1.5320x; 1.0188x over previous
//
#include <hip/hip_runtime.h>
#include <math.h>

// GNN_2_Model: fused-embed -> GAT1 -> GAT2(+res) -> gid head & edge head.
// Round 7:
//  - GEMM K-loop: 2-phase double-buffered LDS staging with counted drain
//    (STAGE next -> compute cur -> asm vmcnt(0) -> raw s_barrier; one barrier
//    per K-step, loads overlap compute). Epilogue tile aliases buffer 0.
//  - wpack x5 + eprep fused into one prep_kernel (fewer launch gaps).
// Everything else unchanged from round 6.

typedef __attribute__((ext_vector_type(8))) short short8;   // 8 x bf16 (4 VGPR)
typedef __attribute__((ext_vector_type(4))) float f32x4;    // MFMA accum
typedef unsigned short ushort;

#define GLOAD16(g, l)                                                   \
  __builtin_amdgcn_global_load_lds(                                     \
      (const __attribute__((address_space(1))) unsigned int*)(g),       \
      (__attribute__((address_space(3))) unsigned int*)(l), 16, 0, 0)

__device__ __forceinline__ float b2f(ushort h) {
  union { unsigned u; float f; } v; v.u = ((unsigned)h) << 16; return v.f;
}
__device__ __forceinline__ ushort f2b(float f) {
  union { float f; unsigned u; } v; v.f = f;
  unsigned r = v.u + 0x7fffu + ((v.u >> 16) & 1u);  // round-to-nearest-even
  return (ushort)(r >> 16);
}
__device__ __forceinline__ void up4(uint2 q, float* o) {
  o[0] = b2f((ushort)(q.x & 0xffffu)); o[1] = b2f((ushort)(q.x >> 16));
  o[2] = b2f((ushort)(q.y & 0xffffu)); o[3] = b2f((ushort)(q.y >> 16));
}
__device__ __forceinline__ void up8(uint4 q, float* o) {
  o[0] = b2f((ushort)(q.x & 0xffffu)); o[1] = b2f((ushort)(q.x >> 16));
  o[2] = b2f((ushort)(q.y & 0xffffu)); o[3] = b2f((ushort)(q.y >> 16));
  o[4] = b2f((ushort)(q.z & 0xffffu)); o[5] = b2f((ushort)(q.z >> 16));
  o[6] = b2f((ushort)(q.w & 0xffffu)); o[7] = b2f((ushort)(q.w >> 16));
}
__device__ __forceinline__ uint4 pk8(const float* o) {
  uint4 q;
  q.x = (unsigned)f2b(o[0]) | ((unsigned)f2b(o[1]) << 16);
  q.y = (unsigned)f2b(o[2]) | ((unsigned)f2b(o[3]) << 16);
  q.z = (unsigned)f2b(o[4]) | ((unsigned)f2b(o[5]) << 16);
  q.w = (unsigned)f2b(o[6]) | ((unsigned)f2b(o[7]) << 16);
  return q;
}
__device__ __forceinline__ float warp_sum(float v) {
#pragma unroll
  for (int o = 32; o > 0; o >>= 1) v += __shfl_xor(v, o);
  return v;
}

// ---------------- fused embedding -> X0 bf16 [N,832] ----------------
__global__ __launch_bounds__(256) void embed_kernel(
    const float* __restrict__ cell_h, const float* __restrict__ pos_emb,
    const float* __restrict__ mf_emb,
    const int* __restrict__ row_pos, const int* __restrict__ col_pos,
    const int* __restrict__ row_mf, const int* __restrict__ col_mf,
    ushort* __restrict__ X0, int N)
{
  const int idx = blockIdx.x * 256 + threadIdx.x;
  const int total = N * 104;  // 832/8 chunks per node
  if (idx >= total) return;
  const int n = idx / 104;
  const int c8 = (idx - n * 104) * 8;
  float o[8];
  if (c8 < 768) {
    const int rp = row_pos[n], cp = col_pos[n];
    const float4* pc = (const float4*)(cell_h + (size_t)n * 768 + c8);
    const float4* pr = (const float4*)(pos_emb + (size_t)rp * 768 + c8);
    const float4* pq = (const float4*)(pos_emb + (size_t)cp * 768 + c8);
    float4 c0 = pc[0], c1 = pc[1], r0 = pr[0], r1 = pr[1], q0 = pq[0], q1 = pq[1];
    o[0] = c0.x + r0.x + q0.x; o[1] = c0.y + r0.y + q0.y;
    o[2] = c0.z + r0.z + q0.z; o[3] = c0.w + r0.w + q0.w;
    o[4] = c1.x + r1.x + q1.x; o[5] = c1.y + r1.y + q1.y;
    o[6] = c1.z + r1.z + q1.z; o[7] = c1.w + r1.w + q1.w;
  } else {
    const int rm = min(row_mf[n], 5), cm = min(col_mf[n], 5);
    const int j0 = c8 - 768;
    const float4* pr = (const float4*)(mf_emb + (size_t)rm * 64 + j0);
    const float4* pq = (const float4*)(mf_emb + (size_t)cm * 64 + j0);
    float4 r0 = pr[0], r1 = pr[1], q0 = pq[0], q1 = pq[1];
    o[0] = r0.x + q0.x; o[1] = r0.y + q0.y; o[2] = r0.z + q0.z; o[3] = r0.w + q0.w;
    o[4] = r1.x + q1.x; o[5] = r1.y + q1.y; o[6] = r1.z + q1.z; o[7] = r1.w + q1.w;
  }
  *(uint4*)(X0 + (size_t)n * 832 + c8) = pk8(o);
}

// ------- weight pack helper: element (k, c) of W[K][srcN] -> packed frag layout ------
__device__ __forceinline__ void pack_one(
    const float* __restrict__ W, ushort* __restrict__ Wp,
    int idx, int K, int srcN, int colBase, int nTK)
{
  const int c = idx / K, k = idx - c * K;
  const int n = colBase + c;
  const int tn = n >> 7, tk = k >> 6;
  const int sub = (((n >> 4) & 7) << 1) | ((k >> 5) & 1);
  const int lane = (n & 15) | (((k >> 3) & 3) << 4);
  const int j = k & 7;
  const size_t off = (((size_t)(tn * nTK + tk) << 4) + sub) * 512 + lane * 8 + j;
  Wp[off] = f2b(W[(size_t)k * srcN + c]);
}

// ---- fused prep: all weight packs + edge-head BN fold in one dispatch ----
#define PREP_C0 (832 * 512)
#define PREP_C1 (PREP_C0 + 512 * 512)
#define PREP_C2 (PREP_C1 + 512 * 256)
#define PREP_C3 (PREP_C2 + 512 * 256)
#define PREP_C4 (PREP_C3 + 512 * 256)
__global__ __launch_bounds__(256) void prep_kernel(
    const float* __restrict__ W1, const float* __restrict__ W2,
    const float* __restrict__ Wg1, const float* __restrict__ We1,
    ushort* __restrict__ W1p, ushort* __restrict__ W2p, ushort* __restrict__ Bh,
    const float* __restrict__ be1, const float* __restrict__ eg,
    const float* __restrict__ eb, const float* __restrict__ em,
    const float* __restrict__ ev, float* __restrict__ sa_ext, float* __restrict__ sbv)
{
  const int idx = blockIdx.x * 256 + threadIdx.x;
  if (idx < PREP_C0) {
    pack_one(W1, W1p, idx, 832, 512, 0, 13);
  } else if (idx < PREP_C1) {
    pack_one(W2, W2p, idx - PREP_C0, 512, 512, 0, 8);
  } else if (idx < PREP_C2) {
    pack_one(Wg1, Bh, idx - PREP_C1, 512, 256, 0, 8);
  } else if (idx < PREP_C3) {
    pack_one(We1, Bh, idx - PREP_C2, 512, 256, 256, 8);
  } else if (idx < PREP_C4) {
    pack_one(We1 + 512 * 256, Bh, idx - PREP_C3, 512, 256, 512, 8);
  } else if (idx < PREP_C4 + 256) {
    const int c = idx - PREP_C4;
    const float sa = eg[c] * rsqrtf(ev[c] + 1e-5f);
    sa_ext[c] = sa;
    sa_ext[c + 256] = sa;
    sbv[c] = eb[c] + (be1[c] - em[c]) * sa;
  }
}

// ---------------- bf16 MFMA GEMM (global_load_lds, 2-phase double buffer) -----------
// 128x128 tile, BK=64, 4 waves (2x2 of 64x64). EPI 0: plain -> C0[M][Ncols].
// EPI 1 (HEADS): cols<256 BN+ReLU -> C0[M][256]; cols>=256 *sa_ext -> C1[M][512].
// ELR: fused el/er (col tile == one head; complete per-block dot with al/ar).
template <int EPI, bool ELR>
__global__ __launch_bounds__(256) void mfma_gemm_kernel(
    const ushort* __restrict__ A, const ushort* __restrict__ Bp,
    ushort* __restrict__ C0, ushort* __restrict__ C1,
    int M, int K, int Ncols, int NT, int mtiles,
    const float* __restrict__ bias, const float* __restrict__ gamma,
    const float* __restrict__ beta, const float* __restrict__ mean,
    const float* __restrict__ var, const float* __restrict__ sa_ext,
    const float* __restrict__ al, const float* __restrict__ ar,
    float* __restrict__ elp, float* __restrict__ erp)
{
  // 2 staging buffers x (As 8192 | Bs 8192) shorts; epilogue [128][132] aliases buf0.
  __shared__ ushort LDS[32768];
  __shared__ float redS[256];
  const int tid = threadIdx.x;
  const int lane = tid & 63;
  const int wave = tid >> 6;
  const int wm = wave >> 1, wn = wave & 1;

  // XCD-co-locating swizzle (bijective incl. tail supergroup).
  const int per = NT << 3;
  const int f = blockIdx.x;
  const int sg = f / per;
  const int rem = f - sg * per;
  const int nb = min(8, mtiles - (sg << 3));
  const int band = rem % nb, colt = rem / nb;
  const int m0 = ((sg << 3) + band) << 7;
  const int n0 = colt << 7;
  const int nTK = K >> 6;

  const int rA = lane & 15;
  const int kA = (lane >> 4) << 3;
  const ushort* Aaddr[4];
#pragma unroll
  for (int q = 0; q < 4; ++q) {
    const int a = (wave << 2) + q;
    int row = m0 + ((a >> 1) << 4) + rA;
    if (row >= M) row = 0;  // clamp: garbage rows never stored
    Aaddr[q] = A + (size_t)row * K + ((a & 1) << 5) + kA;
  }
  const ushort* Baddr = Bp + (((size_t)colt * nTK) << 13)
                        + ((size_t)(wave << 2) << 9) + (lane << 3);

  f32x4 acc[4][4];
#pragma unroll
  for (int i = 0; i < 4; ++i)
#pragma unroll
    for (int j = 0; j < 4; ++j) acc[i][j] = (f32x4){0.f, 0.f, 0.f, 0.f};

  const int nt = K >> 6;

  // prologue: stage tile 0 into buffer 0, full drain once
#pragma unroll
  for (int q = 0; q < 4; ++q)
    GLOAD16(Aaddr[q], LDS + (((wave << 2) + q) << 9));
#pragma unroll
  for (int q = 0; q < 4; ++q)
    GLOAD16(Baddr + (q << 9), LDS + 8192 + (((wave << 2) + q) << 9));
  asm volatile("s_waitcnt vmcnt(0)" ::: "memory");
  __builtin_amdgcn_s_barrier();

  int cur = 0;
  for (int t = 0; t < nt; ++t) {
    const int nxt = cur ^ 1;
    if (t + 1 < nt) {  // issue next tile's loads FIRST (overlap with compute below)
      const int k0n = (t + 1) << 6;
#pragma unroll
      for (int q = 0; q < 4; ++q)
        GLOAD16(Aaddr[q] + k0n, LDS + (nxt << 14) + (((wave << 2) + q) << 9));
#pragma unroll
      for (int q = 0; q < 4; ++q)
        GLOAD16(Baddr + ((size_t)(t + 1) << 13) + (q << 9),
                LDS + (nxt << 14) + 8192 + (((wave << 2) + q) << 9));
    }
    const ushort* Ab = LDS + (cur << 14);
    const ushort* Bb = Ab + 8192;
#pragma unroll
    for (int ks = 0; ks < 2; ++ks) {
      short8 af[4], bf4[4];
#pragma unroll
      for (int x = 0; x < 4; ++x)
        af[x] = *(const short8*)(Ab + ((((wm << 2) + x) * 2 + ks) << 9) + (lane << 3));
#pragma unroll
      for (int x = 0; x < 4; ++x)
        bf4[x] = *(const short8*)(Bb + ((((wn << 2) + x) * 2 + ks) << 9) + (lane << 3));
#pragma unroll
      for (int mf = 0; mf < 4; ++mf)
#pragma unroll
        for (int nf = 0; nf < 4; ++nf)
          acc[mf][nf] = __builtin_amdgcn_mfma_f32_16x16x32_bf16(
              af[mf], bf4[nf], acc[mf][nf], 0, 0, 0);
    }
    // next tile's loads landed; all waves done reading cur before it's reused
    asm volatile("s_waitcnt vmcnt(0)" ::: "memory");
    __builtin_amdgcn_s_barrier();
    cur = nxt;
  }

  // ---- epilogue: acc -> LDS[128][132] bf16 (aliases buf0; safe), coalesced stores ----
  __syncthreads();
#pragma unroll
  for (int nf = 0; nf < 4; ++nf) {
    const int cl = (((wn << 2) + nf) << 4) + (lane & 15);
    const int col = n0 + cl;
    float sa = 1.f, sb = 0.f;
    bool dorelu = false;
    if (EPI == 1) {
      if (col < 256) {
        const float rs = rsqrtf(var[col] + 1e-5f);
        sa = rs * gamma[col];
        sb = beta[col] + (bias[col] - mean[col]) * sa;
        dorelu = true;
      } else {
        sa = sa_ext[col - 256];
      }
    }
#pragma unroll
    for (int mf = 0; mf < 4; ++mf) {
      const int rl = (((wm << 2) + mf) << 4) + ((lane >> 4) << 2);
#pragma unroll
      for (int j = 0; j < 4; ++j) {
        float v = acc[mf][nf][j];
        if (EPI == 1) { v = fmaf(v, sa, sb); if (dorelu) v = fmaxf(v, 0.f); }
        LDS[(rl + j) * 132 + cl] = f2b(v);
      }
    }
  }
  __syncthreads();
#pragma unroll
  for (int i = 0; i < 8; ++i) {
    const int g = tid + (i << 8);          // 2048 granules of 16B
    const int r = g >> 4, c8 = g & 15;
    const int row = m0 + r;
    if (row >= M) continue;
    const uint4 v = *(const uint4*)(LDS + r * 132 + (c8 << 3));
    const int col = n0 + (c8 << 3);
    if (EPI == 0) {
      *(uint4*)(C0 + (size_t)row * Ncols + col) = v;
    } else {
      if (col < 256) *(uint4*)(C0 + (size_t)row * 256 + col) = v;
      else           *(uint4*)(C1 + (size_t)row * 512 + (col - 256)) = v;
    }
  }

  // ---- fused elr: this col tile is head `colt`; complete dot over 128 cols ----
  if (ELR) {
    const int r = tid & 127;
    const int half = tid >> 7;
    const float* alh = al + colt * 128 + half * 64;
    const float* arh = ar + colt * 128 + half * 64;
    const ushort* rowp = LDS + r * 132 + half * 64;
    float sl = 0.f, sr = 0.f;
#pragma unroll
    for (int c = 0; c < 64; ++c) {
      const float v = b2f(rowp[c]);
      sl = fmaf(v, alh[c], sl);
      sr = fmaf(v, arh[c], sr);
    }
    if (half) { redS[r] = sl; redS[r + 128] = sr; }
    __syncthreads();
    if (!half) {
      const int row = m0 + r;
      if (row < M) {
        elp[(size_t)row * 4 + colt] = sl + redS[r];
        erp[(size_t)row * 4 + colt] = sr + redS[r + 128];
      }
    }
  }
}

// ---------------- CSR build (by dst), done once ----------------
__global__ __launch_bounds__(256) void hist_kernel(
    const int* __restrict__ dst, int* __restrict__ counts, int E)
{
  const int e = blockIdx.x * 256 + threadIdx.x;
  if (e < E) atomicAdd(counts + dst[e], 1);
}

__global__ __launch_bounds__(1024) void scan_kernel(
    const int* __restrict__ counts, int* __restrict__ offsets, int N)
{
  __shared__ int sums[1024];
  const int t = threadIdx.x;
  const int chunk = (N + 1023) >> 10;
  const int beg = t * chunk;
  const int end = min(beg + chunk, N);
  int s = 0;
  for (int i = beg; i < end; ++i) s += counts[i];
  sums[t] = s;
  __syncthreads();
  for (int o = 1; o < 1024; o <<= 1) {
    int u = (t >= o) ? sums[t - o] : 0;
    __syncthreads();
    sums[t] += u;
    __syncthreads();
  }
  int run = sums[t] - s;
  for (int i = beg; i < end; ++i) { offsets[i] = run; run += counts[i]; }
  if (t == 1023) offsets[N] = sums[1023];
}

__global__ __launch_bounds__(256) void scatter_kernel(
    const int* __restrict__ src, const int* __restrict__ dst,
    const int* __restrict__ offsets, int* __restrict__ cursor,
    int* __restrict__ csr_src, int E)
{
  const int e = blockIdx.x * 256 + threadIdx.x;
  if (e >= E) return;
  const int d = dst[e];
  const int pos = offsets[d] + atomicAdd(cursor + d, 1);
  csr_src[pos] = src[e];
}

// ---------------- GAT aggregate: one wave per dst node ----------------
template <bool RES>
__global__ __launch_bounds__(256) void gat_aggregate_kernel(
    const int* __restrict__ csr_src, const int* __restrict__ offsets,
    const float* __restrict__ el, const float* __restrict__ er,
    const ushort* __restrict__ feat, const float* __restrict__ bias,
    const ushort* __restrict__ resid, ushort* __restrict__ out, int N)
{
  __shared__ float eeS[4][1024];  // [wave][edge<256][head]
  __shared__ int sS[4][256];      // [wave][edge<256] src id
  const int w = threadIdx.x >> 6;
  const int node = (blockIdx.x * 256 + threadIdx.x) >> 6;
  const int lane = threadIdx.x & 63;
  if (node >= N) return;
  const int beg = offsets[node], end = offsets[node + 1];
  const int deg = end - beg;
  const float4 erd = *(const float4*)(er + (size_t)node * 4);
  float* eew = eeS[w];
  int* sw = sS[w];

  // phase A: lane-parallel weight precompute + denominators
  float d0 = 0.f, d1 = 0.f, d2 = 0.f, d3 = 0.f;
  for (int i = lane; i < deg; i += 64) {
    const int s = csr_src[beg + i];
    const float4 l = *(const float4*)(el + (size_t)s * 4);
    float x0 = l.x + erd.x, x1 = l.y + erd.y, x2 = l.z + erd.z, x3 = l.w + erd.w;
    x0 = x0 > 0.f ? x0 : 0.2f * x0;
    x1 = x1 > 0.f ? x1 : 0.2f * x1;
    x2 = x2 > 0.f ? x2 : 0.2f * x2;
    x3 = x3 > 0.f ? x3 : 0.2f * x3;
    const float e0 = __expf(x0), e1 = __expf(x1), e2 = __expf(x2), e3 = __expf(x3);
    if (i < 256) {
      float4 ev = {e0, e1, e2, e3};
      *(float4*)(eew + (i << 2)) = ev;
      sw[i] = s;
    }
    d0 += e0; d1 += e1; d2 += e2; d3 += e3;
  }
  d0 = warp_sum(d0); d1 = warp_sum(d1); d2 = warp_sum(d2); d3 = warp_sum(d3);
  const float r0 = 1.f / d0, r1 = 1.f / d1, r2 = 1.f / d2, r3 = 1.f / d3;
  const int h = lane >> 4;  // this lane's head (lane owns feats [lane*8,+8))
  const float rh = (lane & 32) ? ((lane & 16) ? r3 : r2) : ((lane & 16) ? r1 : r0);
  const float erh = (lane & 32) ? ((lane & 16) ? erd.w : erd.z)
                                : ((lane & 16) ? erd.y : erd.x);

  // phase B: feature-parallel weighted gather
  float a[8] = {0.f, 0.f, 0.f, 0.f, 0.f, 0.f, 0.f, 0.f};
  for (int i = 0; i < deg; ++i) {
    int s;
    float ew;
    if (i < 256) {
      s = sw[i];                       // broadcast LDS read
      ew = eew[(i << 2) | h];
    } else {                           // rare overflow: recompute own head only
      s = csr_src[beg + i];
      float x = el[(size_t)s * 4 + h] + erh;
      x = x > 0.f ? x : 0.2f * x;
      ew = __expf(x);
    }
    const float aw = ew * rh;
    const uint4 q = *(const uint4*)(feat + (size_t)s * 512 + lane * 8);
    float v[8];
    up8(q, v);
#pragma unroll
    for (int j = 0; j < 8; ++j) a[j] = fmaf(v[j], aw, a[j]);
  }

  const float4 b0 = *(const float4*)(bias + lane * 8);
  const float4 b1 = *(const float4*)(bias + lane * 8 + 4);
  a[0] += b0.x; a[1] += b0.y; a[2] += b0.z; a[3] += b0.w;
  a[4] += b1.x; a[5] += b1.y; a[6] += b1.z; a[7] += b1.w;
  if (RES) {
    float q[8];
    up8(*(const uint4*)(resid + (size_t)node * 512 + lane * 8), q);
#pragma unroll
    for (int j = 0; j < 8; ++j) a[j] += q[j];
  }
  *(uint4*)(out + (size_t)node * 512 + lane * 8) = pk8(a);
}

// gid logits: one wave per node; g bf16 [N,256] @ Wg2[256,4] + bg2.
__global__ __launch_bounds__(256) void gid2_kernel(
    const ushort* __restrict__ g, const float* __restrict__ Wg2,
    const float* __restrict__ bg2, float* __restrict__ out, int N)
{
  const int wv = (blockIdx.x * 256 + threadIdx.x) >> 6;
  const int lane = threadIdx.x & 63;
  if (wv >= N) return;
  float ga[4];
  up4(*(const uint2*)(g + (size_t)wv * 256 + lane * 4), ga);
  float a0 = 0.f, a1 = 0.f, a2 = 0.f, a3 = 0.f;
  const float* wp = Wg2 + (size_t)lane * 16;
#pragma unroll
  for (int j = 0; j < 4; j++) {
    const float4 w = *(const float4*)(wp + j * 4);
    a0 += ga[j] * w.x; a1 += ga[j] * w.y; a2 += ga[j] * w.z; a3 += ga[j] * w.w;
  }
  a0 = warp_sum(a0); a1 = warp_sum(a1); a2 = warp_sum(a2); a3 = warp_sum(a3);
  if (lane == 0) {
    float4 o = {a0 + bg2[0], a1 + bg2[1], a2 + bg2[2], a3 + bg2[3]};
    *(float4*)(out + (size_t)wv * 4) = o;
  }
}

// edge logits: HALF-wave (32 lanes) per pair; 32 x uint4 = exactly one 256-col row.
__global__ __launch_bounds__(256) void pair_combine_kernel(
    const ushort* __restrict__ UV, const int* __restrict__ pairs,
    const float* __restrict__ sb, const float* __restrict__ We2,
    const float* __restrict__ be2, float* __restrict__ out, int P)
{
  const int hw = (blockIdx.x * 256 + threadIdx.x) >> 5;
  const int l = threadIdx.x & 31;
  if (hw >= P) return;
  const int p0 = pairs[2 * hw], p1 = pairs[2 * hw + 1];
  float u[8], v[8];
  up8(*(const uint4*)(UV + (size_t)p0 * 512 + l * 8), u);
  up8(*(const uint4*)(UV + (size_t)p1 * 512 + 256 + l * 8), v);
  const float4 sb0 = *(const float4*)(sb + l * 8);
  const float4 sb1 = *(const float4*)(sb + l * 8 + 4);
  const float4 w0 = *(const float4*)(We2 + l * 8);
  const float4 w1 = *(const float4*)(We2 + l * 8 + 4);
  float s = fmaxf(u[0] + v[0] + sb0.x, 0.f) * w0.x
          + fmaxf(u[1] + v[1] + sb0.y, 0.f) * w0.y
          + fmaxf(u[2] + v[2] + sb0.z, 0.f) * w0.z
          + fmaxf(u[3] + v[3] + sb0.w, 0.f) * w0.w
          + fmaxf(u[4] + v[4] + sb1.x, 0.f) * w1.x
          + fmaxf(u[5] + v[5] + sb1.y, 0.f) * w1.y
          + fmaxf(u[6] + v[6] + sb1.z, 0.f) * w1.z
          + fmaxf(u[7] + v[7] + sb1.w, 0.f) * w1.w;
#pragma unroll
  for (int o = 16; o > 0; o >>= 1) s += __shfl_xor(s, o);
  if (l == 0) out[hw] = s + be2[0];
}

extern "C" void kernel_launch(void* const* d_in, const int* in_sizes, int n_in,
                              void* d_out, int out_size, void* d_ws, size_t ws_size,
                              hipStream_t stream) {
  const float* cell_h  = (const float*)d_in[0];
  const float* pos_emb = (const float*)d_in[1];
  const float* mf_emb  = (const float*)d_in[2];
  const float* W1  = (const float*)d_in[3];
  const float* al1 = (const float*)d_in[4];
  const float* ar1 = (const float*)d_in[5];
  const float* b1  = (const float*)d_in[6];
  const float* W2  = (const float*)d_in[7];
  const float* al2 = (const float*)d_in[8];
  const float* ar2 = (const float*)d_in[9];
  const float* b2  = (const float*)d_in[10];
  const float* Wg1 = (const float*)d_in[11];
  const float* bg1 = (const float*)d_in[12];
  const float* g_gamma = (const float*)d_in[13];
  const float* g_beta  = (const float*)d_in[14];
  const float* g_mean  = (const float*)d_in[15];
  const float* g_var   = (const float*)d_in[16];
  const float* Wg2 = (const float*)d_in[17];
  const float* bg2 = (const float*)d_in[18];
  const float* We1 = (const float*)d_in[19];
  const float* be1 = (const float*)d_in[20];
  const float* e_gamma = (const float*)d_in[21];
  const float* e_beta  = (const float*)d_in[22];
  const float* e_mean  = (const float*)d_in[23];
  const float* e_var   = (const float*)d_in[24];
  const float* We2 = (const float*)d_in[25];
  const float* be2 = (const float*)d_in[26];
  const int* src = (const int*)d_in[27];
  const int* dst = (const int*)d_in[28];
  const int* row_pos = (const int*)d_in[29];
  const int* col_pos = (const int*)d_in[30];
  const int* row_mf  = (const int*)d_in[31];
  const int* col_mf  = (const int*)d_in[32];
  const int* pairs   = (const int*)d_in[33];

  const int N = in_sizes[0] / 768;
  const int E = in_sizes[27];
  const int P = in_sizes[33] / 2;

  ushort* X0    = (ushort*)d_ws;                 // [N,832]
  ushort* featB = X0 + (size_t)N * 832;          // [N,512] (later reused as UV)
  ushort* h1    = featB + (size_t)N * 512;       // [N,512]
  ushort* h2    = h1 + (size_t)N * 512;          // [N,512]
  ushort* W1p   = h2 + (size_t)N * 512;          // packed [512 cols,832 k]
  ushort* W2p   = W1p + 512 * 832;               // packed [512,512]
  ushort* Bh    = W2p + 512 * 512;               // packed heads [768 cols,512 k]
  float* sa_ext = (float*)(Bh + 768 * 512);      // [512]
  float* sbv    = sa_ext + 512;                  // [256]
  float* el     = sbv + 256;                     // [N,4]
  float* er     = el + (size_t)N * 4;            // [N,4]
  int* offsets  = (int*)(er + (size_t)N * 4);    // [N+1]
  int* counts   = offsets + (N + 1);             // [N]
  int* csr_src  = counts + N;                    // [E]
  ushort* g_tmp = X0;                            // [N,256] (X0 dead after GEMM1)
  ushort* UV    = featB;                         // [N,512] (featB dead after agg2)

  const int nodeWaves = (N + 3) / 4;
  const int mtiles = (N + 127) / 128;

  // ---- CSR build (once) ----
  hipMemsetAsync(counts, 0, (size_t)N * sizeof(int), stream);
  hist_kernel<<<(E + 255) / 256, 256, 0, stream>>>(dst, counts, E);
  scan_kernel<<<1, 1024, 0, stream>>>(counts, offsets, N);
  hipMemsetAsync(counts, 0, (size_t)N * sizeof(int), stream);
  scatter_kernel<<<(E + 255) / 256, 256, 0, stream>>>(src, dst, offsets, counts, csr_src, E);

  // ---- fused prep: weight packs + BN fold ----
  prep_kernel<<<(PREP_C4 + 256 + 255) / 256, 256, 0, stream>>>(
      W1, W2, Wg1, We1, W1p, W2p, Bh,
      be1, e_gamma, e_beta, e_mean, e_var, sa_ext, sbv);

  // ---- fused embedding -> X0 bf16 ----
  embed_kernel<<<(N * 104 + 255) / 256, 256, 0, stream>>>(
      cell_h, pos_emb, mf_emb, row_pos, col_pos, row_mf, col_mf, X0, N);

  // ---- GAT layer 1 (GEMM with fused elr) ----
  mfma_gemm_kernel<0, true><<<mtiles * 4, 256, 0, stream>>>(
      X0, W1p, featB, nullptr, N, 832, 512, 4, mtiles,
      nullptr, nullptr, nullptr, nullptr, nullptr, nullptr, al1, ar1, el, er);
  gat_aggregate_kernel<false><<<nodeWaves, 256, 0, stream>>>(
      csr_src, offsets, el, er, featB, b1, nullptr, h1, N);

  // ---- GAT layer 2 (identity residual) ----
  mfma_gemm_kernel<0, true><<<mtiles * 4, 256, 0, stream>>>(
      h1, W2p, featB, nullptr, N, 512, 512, 4, mtiles,
      nullptr, nullptr, nullptr, nullptr, nullptr, nullptr, al2, ar2, el, er);
  gat_aggregate_kernel<true><<<nodeWaves, 256, 0, stream>>>(
      csr_src, offsets, el, er, featB, b2, h1, h2, N);

  // ---- fused heads GEMM: [g_tmp | UV] = h2 @ [Wg1 | We1_top | We1_bot] ----
  mfma_gemm_kernel<1, false><<<mtiles * 6, 256, 0, stream>>>(
      h2, Bh, g_tmp, UV, N, 512, 0, 6, mtiles,
      bg1, g_gamma, g_beta, g_mean, g_var, sa_ext, nullptr, nullptr, nullptr, nullptr);
  gid2_kernel<<<nodeWaves, 256, 0, stream>>>(g_tmp, Wg2, bg2, (float*)d_out, N);
  pair_combine_kernel<<<(P + 7) / 8, 256, 0, stream>>>(
      UV, pairs, sbv, We2, be2, (float*)d_out + (size_t)N * 4, P);
}

// Round 8
// 606.661 us; speedup vs baseline: 1.5422x; 1.0066x over previous
//
#include <hip/hip_runtime.h>
#include <math.h>

// GNN_2_Model: fused-embed -> GAT1 -> GAT2(+res) -> gid head & edge head.
// Round 8:
//  - gat_aggregate phase B unrolled x4 with independent accumulators:
//    4 outstanding uint4 gathers per wave (was 1) -> hides L2/L3 gather latency.
//  - CSR build: counts+cursor adjacent, single memset (one launch fewer).
//  - GEMM unchanged from round 7 (2-phase dbuf, global_load_lds, LDS epilogue,
//    XCD swizzle, fused elr / fused heads).

typedef __attribute__((ext_vector_type(8))) short short8;   // 8 x bf16 (4 VGPR)
typedef __attribute__((ext_vector_type(4))) float f32x4;    // MFMA accum
typedef unsigned short ushort;

#define GLOAD16(g, l)                                                   \
  __builtin_amdgcn_global_load_lds(                                     \
      (const __attribute__((address_space(1))) unsigned int*)(g),       \
      (__attribute__((address_space(3))) unsigned int*)(l), 16, 0, 0)

__device__ __forceinline__ float b2f(ushort h) {
  union { unsigned u; float f; } v; v.u = ((unsigned)h) << 16; return v.f;
}
__device__ __forceinline__ ushort f2b(float f) {
  union { float f; unsigned u; } v; v.f = f;
  unsigned r = v.u + 0x7fffu + ((v.u >> 16) & 1u);  // round-to-nearest-even
  return (ushort)(r >> 16);
}
__device__ __forceinline__ void up4(uint2 q, float* o) {
  o[0] = b2f((ushort)(q.x & 0xffffu)); o[1] = b2f((ushort)(q.x >> 16));
  o[2] = b2f((ushort)(q.y & 0xffffu)); o[3] = b2f((ushort)(q.y >> 16));
}
__device__ __forceinline__ void up8(uint4 q, float* o) {
  o[0] = b2f((ushort)(q.x & 0xffffu)); o[1] = b2f((ushort)(q.x >> 16));
  o[2] = b2f((ushort)(q.y & 0xffffu)); o[3] = b2f((ushort)(q.y >> 16));
  o[4] = b2f((ushort)(q.z & 0xffffu)); o[5] = b2f((ushort)(q.z >> 16));
  o[6] = b2f((ushort)(q.w & 0xffffu)); o[7] = b2f((ushort)(q.w >> 16));
}
__device__ __forceinline__ uint4 pk8(const float* o) {
  uint4 q;
  q.x = (unsigned)f2b(o[0]) | ((unsigned)f2b(o[1]) << 16);
  q.y = (unsigned)f2b(o[2]) | ((unsigned)f2b(o[3]) << 16);
  q.z = (unsigned)f2b(o[4]) | ((unsigned)f2b(o[5]) << 16);
  q.w = (unsigned)f2b(o[6]) | ((unsigned)f2b(o[7]) << 16);
  return q;
}
__device__ __forceinline__ float warp_sum(float v) {
#pragma unroll
  for (int o = 32; o > 0; o >>= 1) v += __shfl_xor(v, o);
  return v;
}

// ---------------- fused embedding -> X0 bf16 [N,832] ----------------
__global__ __launch_bounds__(256) void embed_kernel(
    const float* __restrict__ cell_h, const float* __restrict__ pos_emb,
    const float* __restrict__ mf_emb,
    const int* __restrict__ row_pos, const int* __restrict__ col_pos,
    const int* __restrict__ row_mf, const int* __restrict__ col_mf,
    ushort* __restrict__ X0, int N)
{
  const int idx = blockIdx.x * 256 + threadIdx.x;
  const int total = N * 104;  // 832/8 chunks per node
  if (idx >= total) return;
  const int n = idx / 104;
  const int c8 = (idx - n * 104) * 8;
  float o[8];
  if (c8 < 768) {
    const int rp = row_pos[n], cp = col_pos[n];
    const float4* pc = (const float4*)(cell_h + (size_t)n * 768 + c8);
    const float4* pr = (const float4*)(pos_emb + (size_t)rp * 768 + c8);
    const float4* pq = (const float4*)(pos_emb + (size_t)cp * 768 + c8);
    float4 c0 = pc[0], c1 = pc[1], r0 = pr[0], r1 = pr[1], q0 = pq[0], q1 = pq[1];
    o[0] = c0.x + r0.x + q0.x; o[1] = c0.y + r0.y + q0.y;
    o[2] = c0.z + r0.z + q0.z; o[3] = c0.w + r0.w + q0.w;
    o[4] = c1.x + r1.x + q1.x; o[5] = c1.y + r1.y + q1.y;
    o[6] = c1.z + r1.z + q1.z; o[7] = c1.w + r1.w + q1.w;
  } else {
    const int rm = min(row_mf[n], 5), cm = min(col_mf[n], 5);
    const int j0 = c8 - 768;
    const float4* pr = (const float4*)(mf_emb + (size_t)rm * 64 + j0);
    const float4* pq = (const float4*)(mf_emb + (size_t)cm * 64 + j0);
    float4 r0 = pr[0], r1 = pr[1], q0 = pq[0], q1 = pq[1];
    o[0] = r0.x + q0.x; o[1] = r0.y + q0.y; o[2] = r0.z + q0.z; o[3] = r0.w + q0.w;
    o[4] = r1.x + q1.x; o[5] = r1.y + q1.y; o[6] = r1.z + q1.z; o[7] = r1.w + q1.w;
  }
  *(uint4*)(X0 + (size_t)n * 832 + c8) = pk8(o);
}

// ------- weight pack helper: element (k, c) of W[K][srcN] -> packed frag layout ------
__device__ __forceinline__ void pack_one(
    const float* __restrict__ W, ushort* __restrict__ Wp,
    int idx, int K, int srcN, int colBase, int nTK)
{
  const int c = idx / K, k = idx - c * K;
  const int n = colBase + c;
  const int tn = n >> 7, tk = k >> 6;
  const int sub = (((n >> 4) & 7) << 1) | ((k >> 5) & 1);
  const int lane = (n & 15) | (((k >> 3) & 3) << 4);
  const int j = k & 7;
  const size_t off = (((size_t)(tn * nTK + tk) << 4) + sub) * 512 + lane * 8 + j;
  Wp[off] = f2b(W[(size_t)k * srcN + c]);
}

// ---- fused prep: all weight packs + edge-head BN fold in one dispatch ----
#define PREP_C0 (832 * 512)
#define PREP_C1 (PREP_C0 + 512 * 512)
#define PREP_C2 (PREP_C1 + 512 * 256)
#define PREP_C3 (PREP_C2 + 512 * 256)
#define PREP_C4 (PREP_C3 + 512 * 256)
__global__ __launch_bounds__(256) void prep_kernel(
    const float* __restrict__ W1, const float* __restrict__ W2,
    const float* __restrict__ Wg1, const float* __restrict__ We1,
    ushort* __restrict__ W1p, ushort* __restrict__ W2p, ushort* __restrict__ Bh,
    const float* __restrict__ be1, const float* __restrict__ eg,
    const float* __restrict__ eb, const float* __restrict__ em,
    const float* __restrict__ ev, float* __restrict__ sa_ext, float* __restrict__ sbv)
{
  const int idx = blockIdx.x * 256 + threadIdx.x;
  if (idx < PREP_C0) {
    pack_one(W1, W1p, idx, 832, 512, 0, 13);
  } else if (idx < PREP_C1) {
    pack_one(W2, W2p, idx - PREP_C0, 512, 512, 0, 8);
  } else if (idx < PREP_C2) {
    pack_one(Wg1, Bh, idx - PREP_C1, 512, 256, 0, 8);
  } else if (idx < PREP_C3) {
    pack_one(We1, Bh, idx - PREP_C2, 512, 256, 256, 8);
  } else if (idx < PREP_C4) {
    pack_one(We1 + 512 * 256, Bh, idx - PREP_C3, 512, 256, 512, 8);
  } else if (idx < PREP_C4 + 256) {
    const int c = idx - PREP_C4;
    const float sa = eg[c] * rsqrtf(ev[c] + 1e-5f);
    sa_ext[c] = sa;
    sa_ext[c + 256] = sa;
    sbv[c] = eb[c] + (be1[c] - em[c]) * sa;
  }
}

// ---------------- bf16 MFMA GEMM (global_load_lds, 2-phase double buffer) -----------
template <int EPI, bool ELR>
__global__ __launch_bounds__(256) void mfma_gemm_kernel(
    const ushort* __restrict__ A, const ushort* __restrict__ Bp,
    ushort* __restrict__ C0, ushort* __restrict__ C1,
    int M, int K, int Ncols, int NT, int mtiles,
    const float* __restrict__ bias, const float* __restrict__ gamma,
    const float* __restrict__ beta, const float* __restrict__ mean,
    const float* __restrict__ var, const float* __restrict__ sa_ext,
    const float* __restrict__ al, const float* __restrict__ ar,
    float* __restrict__ elp, float* __restrict__ erp)
{
  __shared__ ushort LDS[32768];
  __shared__ float redS[256];
  const int tid = threadIdx.x;
  const int lane = tid & 63;
  const int wave = tid >> 6;
  const int wm = wave >> 1, wn = wave & 1;

  const int per = NT << 3;
  const int f = blockIdx.x;
  const int sg = f / per;
  const int rem = f - sg * per;
  const int nb = min(8, mtiles - (sg << 3));
  const int band = rem % nb, colt = rem / nb;
  const int m0 = ((sg << 3) + band) << 7;
  const int n0 = colt << 7;
  const int nTK = K >> 6;

  const int rA = lane & 15;
  const int kA = (lane >> 4) << 3;
  const ushort* Aaddr[4];
#pragma unroll
  for (int q = 0; q < 4; ++q) {
    const int a = (wave << 2) + q;
    int row = m0 + ((a >> 1) << 4) + rA;
    if (row >= M) row = 0;  // clamp: garbage rows never stored
    Aaddr[q] = A + (size_t)row * K + ((a & 1) << 5) + kA;
  }
  const ushort* Baddr = Bp + (((size_t)colt * nTK) << 13)
                        + ((size_t)(wave << 2) << 9) + (lane << 3);

  f32x4 acc[4][4];
#pragma unroll
  for (int i = 0; i < 4; ++i)
#pragma unroll
    for (int j = 0; j < 4; ++j) acc[i][j] = (f32x4){0.f, 0.f, 0.f, 0.f};

  const int nt = K >> 6;

#pragma unroll
  for (int q = 0; q < 4; ++q)
    GLOAD16(Aaddr[q], LDS + (((wave << 2) + q) << 9));
#pragma unroll
  for (int q = 0; q < 4; ++q)
    GLOAD16(Baddr + (q << 9), LDS + 8192 + (((wave << 2) + q) << 9));
  asm volatile("s_waitcnt vmcnt(0)" ::: "memory");
  __builtin_amdgcn_s_barrier();

  int cur = 0;
  for (int t = 0; t < nt; ++t) {
    const int nxt = cur ^ 1;
    if (t + 1 < nt) {
      const int k0n = (t + 1) << 6;
#pragma unroll
      for (int q = 0; q < 4; ++q)
        GLOAD16(Aaddr[q] + k0n, LDS + (nxt << 14) + (((wave << 2) + q) << 9));
#pragma unroll
      for (int q = 0; q < 4; ++q)
        GLOAD16(Baddr + ((size_t)(t + 1) << 13) + (q << 9),
                LDS + (nxt << 14) + 8192 + (((wave << 2) + q) << 9));
    }
    const ushort* Ab = LDS + (cur << 14);
    const ushort* Bb = Ab + 8192;
#pragma unroll
    for (int ks = 0; ks < 2; ++ks) {
      short8 af[4], bf4[4];
#pragma unroll
      for (int x = 0; x < 4; ++x)
        af[x] = *(const short8*)(Ab + ((((wm << 2) + x) * 2 + ks) << 9) + (lane << 3));
#pragma unroll
      for (int x = 0; x < 4; ++x)
        bf4[x] = *(const short8*)(Bb + ((((wn << 2) + x) * 2 + ks) << 9) + (lane << 3));
#pragma unroll
      for (int mf = 0; mf < 4; ++mf)
#pragma unroll
        for (int nf = 0; nf < 4; ++nf)
          acc[mf][nf] = __builtin_amdgcn_mfma_f32_16x16x32_bf16(
              af[mf], bf4[nf], acc[mf][nf], 0, 0, 0);
    }
    asm volatile("s_waitcnt vmcnt(0)" ::: "memory");
    __builtin_amdgcn_s_barrier();
    cur = nxt;
  }

  // ---- epilogue: acc -> LDS[128][132] bf16, then coalesced stores ----
  __syncthreads();
#pragma unroll
  for (int nf = 0; nf < 4; ++nf) {
    const int cl = (((wn << 2) + nf) << 4) + (lane & 15);
    const int col = n0 + cl;
    float sa = 1.f, sb = 0.f;
    bool dorelu = false;
    if (EPI == 1) {
      if (col < 256) {
        const float rs = rsqrtf(var[col] + 1e-5f);
        sa = rs * gamma[col];
        sb = beta[col] + (bias[col] - mean[col]) * sa;
        dorelu = true;
      } else {
        sa = sa_ext[col - 256];
      }
    }
#pragma unroll
    for (int mf = 0; mf < 4; ++mf) {
      const int rl = (((wm << 2) + mf) << 4) + ((lane >> 4) << 2);
#pragma unroll
      for (int j = 0; j < 4; ++j) {
        float v = acc[mf][nf][j];
        if (EPI == 1) { v = fmaf(v, sa, sb); if (dorelu) v = fmaxf(v, 0.f); }
        LDS[(rl + j) * 132 + cl] = f2b(v);
      }
    }
  }
  __syncthreads();
#pragma unroll
  for (int i = 0; i < 8; ++i) {
    const int g = tid + (i << 8);
    const int r = g >> 4, c8 = g & 15;
    const int row = m0 + r;
    if (row >= M) continue;
    const uint4 v = *(const uint4*)(LDS + r * 132 + (c8 << 3));
    const int col = n0 + (c8 << 3);
    if (EPI == 0) {
      *(uint4*)(C0 + (size_t)row * Ncols + col) = v;
    } else {
      if (col < 256) *(uint4*)(C0 + (size_t)row * 256 + col) = v;
      else           *(uint4*)(C1 + (size_t)row * 512 + (col - 256)) = v;
    }
  }

  if (ELR) {
    const int r = tid & 127;
    const int half = tid >> 7;
    const float* alh = al + colt * 128 + half * 64;
    const float* arh = ar + colt * 128 + half * 64;
    const ushort* rowp = LDS + r * 132 + half * 64;
    float sl = 0.f, sr = 0.f;
#pragma unroll
    for (int c = 0; c < 64; ++c) {
      const float v = b2f(rowp[c]);
      sl = fmaf(v, alh[c], sl);
      sr = fmaf(v, arh[c], sr);
    }
    if (half) { redS[r] = sl; redS[r + 128] = sr; }
    __syncthreads();
    if (!half) {
      const int row = m0 + r;
      if (row < M) {
        elp[(size_t)row * 4 + colt] = sl + redS[r];
        erp[(size_t)row * 4 + colt] = sr + redS[r + 128];
      }
    }
  }
}

// ---------------- CSR build (by dst), done once ----------------
__global__ __launch_bounds__(256) void hist_kernel(
    const int* __restrict__ dst, int* __restrict__ counts, int E)
{
  const int e = blockIdx.x * 256 + threadIdx.x;
  if (e < E) atomicAdd(counts + dst[e], 1);
}

__global__ __launch_bounds__(1024) void scan_kernel(
    const int* __restrict__ counts, int* __restrict__ offsets, int N)
{
  __shared__ int sums[1024];
  const int t = threadIdx.x;
  const int chunk = (N + 1023) >> 10;
  const int beg = t * chunk;
  const int end = min(beg + chunk, N);
  int s = 0;
  for (int i = beg; i < end; ++i) s += counts[i];
  sums[t] = s;
  __syncthreads();
  for (int o = 1; o < 1024; o <<= 1) {
    int u = (t >= o) ? sums[t - o] : 0;
    __syncthreads();
    sums[t] += u;
    __syncthreads();
  }
  int run = sums[t] - s;
  for (int i = beg; i < end; ++i) { offsets[i] = run; run += counts[i]; }
  if (t == 1023) offsets[N] = sums[1023];
}

__global__ __launch_bounds__(256) void scatter_kernel(
    const int* __restrict__ src, const int* __restrict__ dst,
    const int* __restrict__ offsets, int* __restrict__ cursor,
    int* __restrict__ csr_src, int E)
{
  const int e = blockIdx.x * 256 + threadIdx.x;
  if (e >= E) return;
  const int d = dst[e];
  const int pos = offsets[d] + atomicAdd(cursor + d, 1);
  csr_src[pos] = src[e];
}

// ---------------- GAT aggregate: one wave per dst node ----------------
// Phase A: lane-parallel ee precompute into per-wave LDS + denominators.
// Phase B: x4-unrolled feature-parallel gather (4 loads in flight per wave).
template <bool RES>
__global__ __launch_bounds__(256) void gat_aggregate_kernel(
    const int* __restrict__ csr_src, const int* __restrict__ offsets,
    const float* __restrict__ el, const float* __restrict__ er,
    const ushort* __restrict__ feat, const float* __restrict__ bias,
    const ushort* __restrict__ resid, ushort* __restrict__ out, int N)
{
  __shared__ float eeS[4][1024];  // [wave][edge<256][head]
  __shared__ int sS[4][256];      // [wave][edge<256] src id
  const int w = threadIdx.x >> 6;
  const int node = (blockIdx.x * 256 + threadIdx.x) >> 6;
  const int lane = threadIdx.x & 63;
  if (node >= N) return;
  const int beg = offsets[node], end = offsets[node + 1];
  const int deg = end - beg;
  const float4 erd = *(const float4*)(er + (size_t)node * 4);
  float* eew = eeS[w];
  int* sw = sS[w];

  // phase A
  float d0 = 0.f, d1 = 0.f, d2 = 0.f, d3 = 0.f;
  for (int i = lane; i < deg; i += 64) {
    const int s = csr_src[beg + i];
    const float4 l = *(const float4*)(el + (size_t)s * 4);
    float x0 = l.x + erd.x, x1 = l.y + erd.y, x2 = l.z + erd.z, x3 = l.w + erd.w;
    x0 = x0 > 0.f ? x0 : 0.2f * x0;
    x1 = x1 > 0.f ? x1 : 0.2f * x1;
    x2 = x2 > 0.f ? x2 : 0.2f * x2;
    x3 = x3 > 0.f ? x3 : 0.2f * x3;
    const float e0 = __expf(x0), e1 = __expf(x1), e2 = __expf(x2), e3 = __expf(x3);
    if (i < 256) {
      float4 ev = {e0, e1, e2, e3};
      *(float4*)(eew + (i << 2)) = ev;
      sw[i] = s;
    }
    d0 += e0; d1 += e1; d2 += e2; d3 += e3;
  }
  d0 = warp_sum(d0); d1 = warp_sum(d1); d2 = warp_sum(d2); d3 = warp_sum(d3);
  const float r0 = 1.f / d0, r1 = 1.f / d1, r2 = 1.f / d2, r3 = 1.f / d3;
  const int h = lane >> 4;
  const float rh = (lane & 32) ? ((lane & 16) ? r3 : r2) : ((lane & 16) ? r1 : r0);
  const float erh = (lane & 32) ? ((lane & 16) ? erd.w : erd.z)
                                : ((lane & 16) ? erd.y : erd.x);

  // phase B: x4 unrolled (independent accumulators -> 4 gathers in flight)
  float a0[8] = {0.f}, a1[8] = {0.f}, a2[8] = {0.f}, a3[8] = {0.f};
  const int cap = min(deg, 256);
  const int main4 = cap & ~3;
  int i = 0;
  for (; i < main4; i += 4) {
    const int s0 = sw[i], s1 = sw[i + 1], s2 = sw[i + 2], s3 = sw[i + 3];
    const float w0 = eew[((i + 0) << 2) | h] * rh;
    const float w1 = eew[((i + 1) << 2) | h] * rh;
    const float w2 = eew[((i + 2) << 2) | h] * rh;
    const float w3 = eew[((i + 3) << 2) | h] * rh;
    const uint4 q0 = *(const uint4*)(feat + (size_t)s0 * 512 + lane * 8);
    const uint4 q1 = *(const uint4*)(feat + (size_t)s1 * 512 + lane * 8);
    const uint4 q2 = *(const uint4*)(feat + (size_t)s2 * 512 + lane * 8);
    const uint4 q3 = *(const uint4*)(feat + (size_t)s3 * 512 + lane * 8);
    float v[8];
    up8(q0, v);
#pragma unroll
    for (int j = 0; j < 8; ++j) a0[j] = fmaf(v[j], w0, a0[j]);
    up8(q1, v);
#pragma unroll
    for (int j = 0; j < 8; ++j) a1[j] = fmaf(v[j], w1, a1[j]);
    up8(q2, v);
#pragma unroll
    for (int j = 0; j < 8; ++j) a2[j] = fmaf(v[j], w2, a2[j]);
    up8(q3, v);
#pragma unroll
    for (int j = 0; j < 8; ++j) a3[j] = fmaf(v[j], w3, a3[j]);
  }
  for (; i < cap; ++i) {  // remainder within LDS cache
    const int s = sw[i];
    const float aw = eew[(i << 2) | h] * rh;
    const uint4 q = *(const uint4*)(feat + (size_t)s * 512 + lane * 8);
    float v[8];
    up8(q, v);
#pragma unroll
    for (int j = 0; j < 8; ++j) a0[j] = fmaf(v[j], aw, a0[j]);
  }
  for (; i < deg; ++i) {  // rare overflow beyond 256: recompute own head only
    const int s = csr_src[beg + i];
    float x = el[(size_t)s * 4 + h] + erh;
    x = x > 0.f ? x : 0.2f * x;
    const float aw = __expf(x) * rh;
    const uint4 q = *(const uint4*)(feat + (size_t)s * 512 + lane * 8);
    float v[8];
    up8(q, v);
#pragma unroll
    for (int j = 0; j < 8; ++j) a0[j] = fmaf(v[j], aw, a0[j]);
  }
#pragma unroll
  for (int j = 0; j < 8; ++j) a0[j] += (a1[j] + a2[j]) + a3[j];

  const float4 b0 = *(const float4*)(bias + lane * 8);
  const float4 b1 = *(const float4*)(bias + lane * 8 + 4);
  a0[0] += b0.x; a0[1] += b0.y; a0[2] += b0.z; a0[3] += b0.w;
  a0[4] += b1.x; a0[5] += b1.y; a0[6] += b1.z; a0[7] += b1.w;
  if (RES) {
    float q[8];
    up8(*(const uint4*)(resid + (size_t)node * 512 + lane * 8), q);
#pragma unroll
    for (int j = 0; j < 8; ++j) a0[j] += q[j];
  }
  *(uint4*)(out + (size_t)node * 512 + lane * 8) = pk8(a0);
}

// gid logits: one wave per node; g bf16 [N,256] @ Wg2[256,4] + bg2.
__global__ __launch_bounds__(256) void gid2_kernel(
    const ushort* __restrict__ g, const float* __restrict__ Wg2,
    const float* __restrict__ bg2, float* __restrict__ out, int N)
{
  const int wv = (blockIdx.x * 256 + threadIdx.x) >> 6;
  const int lane = threadIdx.x & 63;
  if (wv >= N) return;
  float ga[4];
  up4(*(const uint2*)(g + (size_t)wv * 256 + lane * 4), ga);
  float a0 = 0.f, a1 = 0.f, a2 = 0.f, a3 = 0.f;
  const float* wp = Wg2 + (size_t)lane * 16;
#pragma unroll
  for (int j = 0; j < 4; j++) {
    const float4 w = *(const float4*)(wp + j * 4);
    a0 += ga[j] * w.x; a1 += ga[j] * w.y; a2 += ga[j] * w.z; a3 += ga[j] * w.w;
  }
  a0 = warp_sum(a0); a1 = warp_sum(a1); a2 = warp_sum(a2); a3 = warp_sum(a3);
  if (lane == 0) {
    float4 o = {a0 + bg2[0], a1 + bg2[1], a2 + bg2[2], a3 + bg2[3]};
    *(float4*)(out + (size_t)wv * 4) = o;
  }
}

// edge logits: HALF-wave (32 lanes) per pair; 32 x uint4 = exactly one 256-col row.
__global__ __launch_bounds__(256) void pair_combine_kernel(
    const ushort* __restrict__ UV, const int* __restrict__ pairs,
    const float* __restrict__ sb, const float* __restrict__ We2,
    const float* __restrict__ be2, float* __restrict__ out, int P)
{
  const int hw = (blockIdx.x * 256 + threadIdx.x) >> 5;
  const int l = threadIdx.x & 31;
  if (hw >= P) return;
  const int p0 = pairs[2 * hw], p1 = pairs[2 * hw + 1];
  float u[8], v[8];
  up8(*(const uint4*)(UV + (size_t)p0 * 512 + l * 8), u);
  up8(*(const uint4*)(UV + (size_t)p1 * 512 + 256 + l * 8), v);
  const float4 sb0 = *(const float4*)(sb + l * 8);
  const float4 sb1 = *(const float4*)(sb + l * 8 + 4);
  const float4 w0 = *(const float4*)(We2 + l * 8);
  const float4 w1 = *(const float4*)(We2 + l * 8 + 4);
  float s = fmaxf(u[0] + v[0] + sb0.x, 0.f) * w0.x
          + fmaxf(u[1] + v[1] + sb0.y, 0.f) * w0.y
          + fmaxf(u[2] + v[2] + sb0.z, 0.f) * w0.z
          + fmaxf(u[3] + v[3] + sb0.w, 0.f) * w0.w
          + fmaxf(u[4] + v[4] + sb1.x, 0.f) * w1.x
          + fmaxf(u[5] + v[5] + sb1.y, 0.f) * w1.y
          + fmaxf(u[6] + v[6] + sb1.z, 0.f) * w1.z
          + fmaxf(u[7] + v[7] + sb1.w, 0.f) * w1.w;
#pragma unroll
  for (int o = 16; o > 0; o >>= 1) s += __shfl_xor(s, o);
  if (l == 0) out[hw] = s + be2[0];
}

extern "C" void kernel_launch(void* const* d_in, const int* in_sizes, int n_in,
                              void* d_out, int out_size, void* d_ws, size_t ws_size,
                              hipStream_t stream) {
  const float* cell_h  = (const float*)d_in[0];
  const float* pos_emb = (const float*)d_in[1];
  const float* mf_emb  = (const float*)d_in[2];
  const float* W1  = (const float*)d_in[3];
  const float* al1 = (const float*)d_in[4];
  const float* ar1 = (const float*)d_in[5];
  const float* b1  = (const float*)d_in[6];
  const float* W2  = (const float*)d_in[7];
  const float* al2 = (const float*)d_in[8];
  const float* ar2 = (const float*)d_in[9];
  const float* b2  = (const float*)d_in[10];
  const float* Wg1 = (const float*)d_in[11];
  const float* bg1 = (const float*)d_in[12];
  const float* g_gamma = (const float*)d_in[13];
  const float* g_beta  = (const float*)d_in[14];
  const float* g_mean  = (const float*)d_in[15];
  const float* g_var   = (const float*)d_in[16];
  const float* Wg2 = (const float*)d_in[17];
  const float* bg2 = (const float*)d_in[18];
  const float* We1 = (const float*)d_in[19];
  const float* be1 = (const float*)d_in[20];
  const float* e_gamma = (const float*)d_in[21];
  const float* e_beta  = (const float*)d_in[22];
  const float* e_mean  = (const float*)d_in[23];
  const float* e_var   = (const float*)d_in[24];
  const float* We2 = (const float*)d_in[25];
  const float* be2 = (const float*)d_in[26];
  const int* src = (const int*)d_in[27];
  const int* dst = (const int*)d_in[28];
  const int* row_pos = (const int*)d_in[29];
  const int* col_pos = (const int*)d_in[30];
  const int* row_mf  = (const int*)d_in[31];
  const int* col_mf  = (const int*)d_in[32];
  const int* pairs   = (const int*)d_in[33];

  const int N = in_sizes[0] / 768;
  const int E = in_sizes[27];
  const int P = in_sizes[33] / 2;

  ushort* X0    = (ushort*)d_ws;                 // [N,832]
  ushort* featB = X0 + (size_t)N * 832;          // [N,512] (later reused as UV)
  ushort* h1    = featB + (size_t)N * 512;       // [N,512]
  ushort* h2    = h1 + (size_t)N * 512;          // [N,512]
  ushort* W1p   = h2 + (size_t)N * 512;          // packed [512 cols,832 k]
  ushort* W2p   = W1p + 512 * 832;               // packed [512,512]
  ushort* Bh    = W2p + 512 * 512;               // packed heads [768 cols,512 k]
  float* sa_ext = (float*)(Bh + 768 * 512);      // [512]
  float* sbv    = sa_ext + 512;                  // [256]
  float* el     = sbv + 256;                     // [N,4]
  float* er     = el + (size_t)N * 4;            // [N,4]
  int* offsets  = (int*)(er + (size_t)N * 4);    // [N+1]
  int* counts   = offsets + (N + 1);             // [N]
  int* cursor   = counts + N;                    // [N] (adjacent: one memset covers both)
  int* csr_src  = cursor + N;                    // [E]
  ushort* g_tmp = X0;                            // [N,256] (X0 dead after GEMM1)
  ushort* UV    = featB;                         // [N,512] (featB dead after agg2)

  const int nodeWaves = (N + 3) / 4;
  const int mtiles = (N + 127) / 128;

  // ---- CSR build (once) ----
  hipMemsetAsync(counts, 0, (size_t)(2 * N) * sizeof(int), stream);  // counts + cursor
  hist_kernel<<<(E + 255) / 256, 256, 0, stream>>>(dst, counts, E);
  scan_kernel<<<1, 1024, 0, stream>>>(counts, offsets, N);
  scatter_kernel<<<(E + 255) / 256, 256, 0, stream>>>(src, dst, offsets, cursor, csr_src, E);

  // ---- fused prep: weight packs + BN fold ----
  prep_kernel<<<(PREP_C4 + 256 + 255) / 256, 256, 0, stream>>>(
      W1, W2, Wg1, We1, W1p, W2p, Bh,
      be1, e_gamma, e_beta, e_mean, e_var, sa_ext, sbv);

  // ---- fused embedding -> X0 bf16 ----
  embed_kernel<<<(N * 104 + 255) / 256, 256, 0, stream>>>(
      cell_h, pos_emb, mf_emb, row_pos, col_pos, row_mf, col_mf, X0, N);

  // ---- GAT layer 1 (GEMM with fused elr) ----
  mfma_gemm_kernel<0, true><<<mtiles * 4, 256, 0, stream>>>(
      X0, W1p, featB, nullptr, N, 832, 512, 4, mtiles,
      nullptr, nullptr, nullptr, nullptr, nullptr, nullptr, al1, ar1, el, er);
  gat_aggregate_kernel<false><<<nodeWaves, 256, 0, stream>>>(
      csr_src, offsets, el, er, featB, b1, nullptr, h1, N);

  // ---- GAT layer 2 (identity residual) ----
  mfma_gemm_kernel<0, true><<<mtiles * 4, 256, 0, stream>>>(
      h1, W2p, featB, nullptr, N, 512, 512, 4, mtiles,
      nullptr, nullptr, nullptr, nullptr, nullptr, nullptr, al2, ar2, el, er);
  gat_aggregate_kernel<true><<<nodeWaves, 256, 0, stream>>>(
      csr_src, offsets, el, er, featB, b2, h1, h2, N);

  // ---- fused heads GEMM: [g_tmp | UV] = h2 @ [Wg1 | We1_top | We1_bot] ----
  mfma_gemm_kernel<1, false><<<mtiles * 6, 256, 0, stream>>>(
      h2, Bh, g_tmp, UV, N, 512, 0, 6, mtiles,
      bg1, g_gamma, g_beta, g_mean, g_var, sa_ext, nullptr, nullptr, nullptr, nullptr);
  gid2_kernel<<<nodeWaves, 256, 0, stream>>>(g_tmp, Wg2, bg2, (float*)d_out, N);
  pair_combine_kernel<<<(P + 7) / 8, 256, 0, stream>>>(
      UV, pairs, sbv, We2, be2, (float*)d_out + (size_t)N * 4, P);
}

// Round 9
// 589.179 us; speedup vs baseline: 1.5879x; 1.0297x over previous
//
#include <hip/hip_runtime.h>
#include <math.h>

// GNN_2_Model: fused-embed -> GAT1 -> GAT2(+res) -> gid head & edge head.
// Round 9:
//  - GEMM: 128x128 tile now run by 8 waves (512 threads); each wave owns a
//    64x32 sub-tile (acc[4][2]). Same total MFMA per block, half per wave ->
//    2x resident waves at fixed blocks/CU (R5-R8 showed residency pinned at
//    ~1.3 blocks/CU regardless of LDS): wave-level TLP hides the staging
//    latency the 2-barrier structure exposes. Epilogue/ELR re-partitioned.
//  - Aggregate / prep / embed / pair_combine / CSR unchanged from round 8.

typedef __attribute__((ext_vector_type(8))) short short8;   // 8 x bf16 (4 VGPR)
typedef __attribute__((ext_vector_type(4))) float f32x4;    // MFMA accum
typedef unsigned short ushort;

#define GLOAD16(g, l)                                                   \
  __builtin_amdgcn_global_load_lds(                                     \
      (const __attribute__((address_space(1))) unsigned int*)(g),       \
      (__attribute__((address_space(3))) unsigned int*)(l), 16, 0, 0)

__device__ __forceinline__ float b2f(ushort h) {
  union { unsigned u; float f; } v; v.u = ((unsigned)h) << 16; return v.f;
}
__device__ __forceinline__ ushort f2b(float f) {
  union { float f; unsigned u; } v; v.f = f;
  unsigned r = v.u + 0x7fffu + ((v.u >> 16) & 1u);  // round-to-nearest-even
  return (ushort)(r >> 16);
}
__device__ __forceinline__ void up4(uint2 q, float* o) {
  o[0] = b2f((ushort)(q.x & 0xffffu)); o[1] = b2f((ushort)(q.x >> 16));
  o[2] = b2f((ushort)(q.y & 0xffffu)); o[3] = b2f((ushort)(q.y >> 16));
}
__device__ __forceinline__ void up8(uint4 q, float* o) {
  o[0] = b2f((ushort)(q.x & 0xffffu)); o[1] = b2f((ushort)(q.x >> 16));
  o[2] = b2f((ushort)(q.y & 0xffffu)); o[3] = b2f((ushort)(q.y >> 16));
  o[4] = b2f((ushort)(q.z & 0xffffu)); o[5] = b2f((ushort)(q.z >> 16));
  o[6] = b2f((ushort)(q.w & 0xffffu)); o[7] = b2f((ushort)(q.w >> 16));
}
__device__ __forceinline__ uint4 pk8(const float* o) {
  uint4 q;
  q.x = (unsigned)f2b(o[0]) | ((unsigned)f2b(o[1]) << 16);
  q.y = (unsigned)f2b(o[2]) | ((unsigned)f2b(o[3]) << 16);
  q.z = (unsigned)f2b(o[4]) | ((unsigned)f2b(o[5]) << 16);
  q.w = (unsigned)f2b(o[6]) | ((unsigned)f2b(o[7]) << 16);
  return q;
}
__device__ __forceinline__ float warp_sum(float v) {
#pragma unroll
  for (int o = 32; o > 0; o >>= 1) v += __shfl_xor(v, o);
  return v;
}

// ---------------- fused embedding -> X0 bf16 [N,832] ----------------
__global__ __launch_bounds__(256) void embed_kernel(
    const float* __restrict__ cell_h, const float* __restrict__ pos_emb,
    const float* __restrict__ mf_emb,
    const int* __restrict__ row_pos, const int* __restrict__ col_pos,
    const int* __restrict__ row_mf, const int* __restrict__ col_mf,
    ushort* __restrict__ X0, int N)
{
  const int idx = blockIdx.x * 256 + threadIdx.x;
  const int total = N * 104;  // 832/8 chunks per node
  if (idx >= total) return;
  const int n = idx / 104;
  const int c8 = (idx - n * 104) * 8;
  float o[8];
  if (c8 < 768) {
    const int rp = row_pos[n], cp = col_pos[n];
    const float4* pc = (const float4*)(cell_h + (size_t)n * 768 + c8);
    const float4* pr = (const float4*)(pos_emb + (size_t)rp * 768 + c8);
    const float4* pq = (const float4*)(pos_emb + (size_t)cp * 768 + c8);
    float4 c0 = pc[0], c1 = pc[1], r0 = pr[0], r1 = pr[1], q0 = pq[0], q1 = pq[1];
    o[0] = c0.x + r0.x + q0.x; o[1] = c0.y + r0.y + q0.y;
    o[2] = c0.z + r0.z + q0.z; o[3] = c0.w + r0.w + q0.w;
    o[4] = c1.x + r1.x + q1.x; o[5] = c1.y + r1.y + q1.y;
    o[6] = c1.z + r1.z + q1.z; o[7] = c1.w + r1.w + q1.w;
  } else {
    const int rm = min(row_mf[n], 5), cm = min(col_mf[n], 5);
    const int j0 = c8 - 768;
    const float4* pr = (const float4*)(mf_emb + (size_t)rm * 64 + j0);
    const float4* pq = (const float4*)(mf_emb + (size_t)cm * 64 + j0);
    float4 r0 = pr[0], r1 = pr[1], q0 = pq[0], q1 = pq[1];
    o[0] = r0.x + q0.x; o[1] = r0.y + q0.y; o[2] = r0.z + q0.z; o[3] = r0.w + q0.w;
    o[4] = r1.x + q1.x; o[5] = r1.y + q1.y; o[6] = r1.z + q1.z; o[7] = r1.w + q1.w;
  }
  *(uint4*)(X0 + (size_t)n * 832 + c8) = pk8(o);
}

// ------- weight pack helper: element (k, c) of W[K][srcN] -> packed frag layout ------
__device__ __forceinline__ void pack_one(
    const float* __restrict__ W, ushort* __restrict__ Wp,
    int idx, int K, int srcN, int colBase, int nTK)
{
  const int c = idx / K, k = idx - c * K;
  const int n = colBase + c;
  const int tn = n >> 7, tk = k >> 6;
  const int sub = (((n >> 4) & 7) << 1) | ((k >> 5) & 1);
  const int lane = (n & 15) | (((k >> 3) & 3) << 4);
  const int j = k & 7;
  const size_t off = (((size_t)(tn * nTK + tk) << 4) + sub) * 512 + lane * 8 + j;
  Wp[off] = f2b(W[(size_t)k * srcN + c]);
}

// ---- fused prep: all weight packs + edge-head BN fold in one dispatch ----
#define PREP_C0 (832 * 512)
#define PREP_C1 (PREP_C0 + 512 * 512)
#define PREP_C2 (PREP_C1 + 512 * 256)
#define PREP_C3 (PREP_C2 + 512 * 256)
#define PREP_C4 (PREP_C3 + 512 * 256)
__global__ __launch_bounds__(256) void prep_kernel(
    const float* __restrict__ W1, const float* __restrict__ W2,
    const float* __restrict__ Wg1, const float* __restrict__ We1,
    ushort* __restrict__ W1p, ushort* __restrict__ W2p, ushort* __restrict__ Bh,
    const float* __restrict__ be1, const float* __restrict__ eg,
    const float* __restrict__ eb, const float* __restrict__ em,
    const float* __restrict__ ev, float* __restrict__ sa_ext, float* __restrict__ sbv)
{
  const int idx = blockIdx.x * 256 + threadIdx.x;
  if (idx < PREP_C0) {
    pack_one(W1, W1p, idx, 832, 512, 0, 13);
  } else if (idx < PREP_C1) {
    pack_one(W2, W2p, idx - PREP_C0, 512, 512, 0, 8);
  } else if (idx < PREP_C2) {
    pack_one(Wg1, Bh, idx - PREP_C1, 512, 256, 0, 8);
  } else if (idx < PREP_C3) {
    pack_one(We1, Bh, idx - PREP_C2, 512, 256, 256, 8);
  } else if (idx < PREP_C4) {
    pack_one(We1 + 512 * 256, Bh, idx - PREP_C3, 512, 256, 512, 8);
  } else if (idx < PREP_C4 + 256) {
    const int c = idx - PREP_C4;
    const float sa = eg[c] * rsqrtf(ev[c] + 1e-5f);
    sa_ext[c] = sa;
    sa_ext[c + 256] = sa;
    sbv[c] = eb[c] + (be1[c] - em[c]) * sa;
  }
}

// ---------------- bf16 MFMA GEMM: 128x128 tile, 8 waves (512 thr) ----------------
// wave (wm,wn) = (wave>>2, wave&3) owns 64x32 output: m-frags (wm*4+x)*16,
// n-frags (wn*2+y)*16. Staging: wave stages subtiles {2w, 2w+1} of A and B.
// 2-phase double buffer, global_load_lds width 16, LDS epilogue, XCD swizzle.
template <int EPI, bool ELR>
__global__ __launch_bounds__(512) void mfma_gemm_kernel(
    const ushort* __restrict__ A, const ushort* __restrict__ Bp,
    ushort* __restrict__ C0, ushort* __restrict__ C1,
    int M, int K, int Ncols, int NT, int mtiles,
    const float* __restrict__ bias, const float* __restrict__ gamma,
    const float* __restrict__ beta, const float* __restrict__ mean,
    const float* __restrict__ var, const float* __restrict__ sa_ext,
    const float* __restrict__ al, const float* __restrict__ ar,
    float* __restrict__ elp, float* __restrict__ erp)
{
  __shared__ ushort LDS[32768];   // 2 x (As 8192 | Bs 8192); epi [128][132] aliases buf0
  __shared__ float redS[768];
  const int tid = threadIdx.x;
  const int lane = tid & 63;
  const int wave = tid >> 6;      // 0..7
  const int wm = wave >> 2, wn = wave & 3;

  const int per = NT << 3;
  const int f = blockIdx.x;
  const int sg = f / per;
  const int rem = f - sg * per;
  const int nb = min(8, mtiles - (sg << 3));
  const int band = rem % nb, colt = rem / nb;
  const int m0 = ((sg << 3) + band) << 7;
  const int n0 = colt << 7;
  const int nTK = K >> 6;

  // staging: wave stages A/B subtiles a = wave*2 + q (a = mb*2 + ks)
  const int rA = lane & 15;
  const int kA = (lane >> 4) << 3;
  const ushort* Aaddr[2];
#pragma unroll
  for (int q = 0; q < 2; ++q) {
    const int a = (wave << 1) + q;
    int row = m0 + ((a >> 1) << 4) + rA;
    if (row >= M) row = 0;  // clamp: garbage rows never stored
    Aaddr[q] = A + (size_t)row * K + ((a & 1) << 5) + kA;
  }
  const ushort* Baddr = Bp + (((size_t)colt * nTK) << 13)
                        + ((size_t)(wave << 1) << 9) + (lane << 3);

  f32x4 acc[4][2];
#pragma unroll
  for (int i = 0; i < 4; ++i)
#pragma unroll
    for (int j = 0; j < 2; ++j) acc[i][j] = (f32x4){0.f, 0.f, 0.f, 0.f};

  const int nt = K >> 6;

  // prologue: stage tile 0 into buffer 0, full drain once
#pragma unroll
  for (int q = 0; q < 2; ++q)
    GLOAD16(Aaddr[q], LDS + (((wave << 1) + q) << 9));
#pragma unroll
  for (int q = 0; q < 2; ++q)
    GLOAD16(Baddr + (q << 9), LDS + 8192 + (((wave << 1) + q) << 9));
  asm volatile("s_waitcnt vmcnt(0)" ::: "memory");
  __builtin_amdgcn_s_barrier();

  int cur = 0;
  for (int t = 0; t < nt; ++t) {
    const int nxt = cur ^ 1;
    if (t + 1 < nt) {
      const int k0n = (t + 1) << 6;
#pragma unroll
      for (int q = 0; q < 2; ++q)
        GLOAD16(Aaddr[q] + k0n, LDS + (nxt << 14) + (((wave << 1) + q) << 9));
#pragma unroll
      for (int q = 0; q < 2; ++q)
        GLOAD16(Baddr + ((size_t)(t + 1) << 13) + (q << 9),
                LDS + (nxt << 14) + 8192 + (((wave << 1) + q) << 9));
    }
    const ushort* Ab = LDS + (cur << 14);
    const ushort* Bb = Ab + 8192;
#pragma unroll
    for (int ks = 0; ks < 2; ++ks) {
      short8 af[4], bf2[2];
#pragma unroll
      for (int x = 0; x < 4; ++x)
        af[x] = *(const short8*)(Ab + ((((wm << 2) + x) * 2 + ks) << 9) + (lane << 3));
#pragma unroll
      for (int y = 0; y < 2; ++y)
        bf2[y] = *(const short8*)(Bb + ((((wn << 1) + y) * 2 + ks) << 9) + (lane << 3));
#pragma unroll
      for (int mf = 0; mf < 4; ++mf)
#pragma unroll
        for (int nf = 0; nf < 2; ++nf)
          acc[mf][nf] = __builtin_amdgcn_mfma_f32_16x16x32_bf16(
              af[mf], bf2[nf], acc[mf][nf], 0, 0, 0);
    }
    asm volatile("s_waitcnt vmcnt(0)" ::: "memory");
    __builtin_amdgcn_s_barrier();
    cur = nxt;
  }

  // ---- epilogue: acc -> LDS[128][132] bf16, then coalesced stores ----
  __syncthreads();
#pragma unroll
  for (int nf = 0; nf < 2; ++nf) {
    const int cl = (((wn << 1) + nf) << 4) + (lane & 15);
    const int col = n0 + cl;
    float sa = 1.f, sb = 0.f;
    bool dorelu = false;
    if (EPI == 1) {
      if (col < 256) {
        const float rs = rsqrtf(var[col] + 1e-5f);
        sa = rs * gamma[col];
        sb = beta[col] + (bias[col] - mean[col]) * sa;
        dorelu = true;
      } else {
        sa = sa_ext[col - 256];
      }
    }
#pragma unroll
    for (int mf = 0; mf < 4; ++mf) {
      const int rl = (((wm << 2) + mf) << 4) + ((lane >> 4) << 2);
#pragma unroll
      for (int j = 0; j < 4; ++j) {
        float v = acc[mf][nf][j];
        if (EPI == 1) { v = fmaf(v, sa, sb); if (dorelu) v = fmaxf(v, 0.f); }
        LDS[(rl + j) * 132 + cl] = f2b(v);
      }
    }
  }
  __syncthreads();
#pragma unroll
  for (int i = 0; i < 4; ++i) {
    const int g = tid + (i << 9);          // 2048 granules of 16B
    const int r = g >> 4, c8 = g & 15;
    const int row = m0 + r;
    if (row >= M) continue;
    const uint4 v = *(const uint4*)(LDS + r * 132 + (c8 << 3));
    const int col = n0 + (c8 << 3);
    if (EPI == 0) {
      *(uint4*)(C0 + (size_t)row * Ncols + col) = v;
    } else {
      if (col < 256) *(uint4*)(C0 + (size_t)row * 256 + col) = v;
      else           *(uint4*)(C1 + (size_t)row * 512 + (col - 256)) = v;
    }
  }

  // ---- fused elr: this col tile is head `colt`; dot over 128 cols, 4 quarters ----
  if (ELR) {
    const int r = tid & 127;
    const int qq = tid >> 7;  // 0..3 -> cols [qq*32, +32)
    const float* alh = al + colt * 128 + qq * 32;
    const float* arh = ar + colt * 128 + qq * 32;
    const ushort* rowp = LDS + r * 132 + qq * 32;
    float sl = 0.f, sr = 0.f;
#pragma unroll
    for (int c = 0; c < 32; ++c) {
      const float v = b2f(rowp[c]);
      sl = fmaf(v, alh[c], sl);
      sr = fmaf(v, arh[c], sr);
    }
    if (qq) { redS[((qq - 1) << 7) + r] = sl; redS[384 + ((qq - 1) << 7) + r] = sr; }
    __syncthreads();
    if (!qq) {
      const int row = m0 + r;
      if (row < M) {
        elp[(size_t)row * 4 + colt] = sl + redS[r] + redS[128 + r] + redS[256 + r];
        erp[(size_t)row * 4 + colt] = sr + redS[384 + r] + redS[512 + r] + redS[640 + r];
      }
    }
  }
}

// ---------------- CSR build (by dst), done once ----------------
__global__ __launch_bounds__(256) void hist_kernel(
    const int* __restrict__ dst, int* __restrict__ counts, int E)
{
  const int e = blockIdx.x * 256 + threadIdx.x;
  if (e < E) atomicAdd(counts + dst[e], 1);
}

__global__ __launch_bounds__(1024) void scan_kernel(
    const int* __restrict__ counts, int* __restrict__ offsets, int N)
{
  __shared__ int sums[1024];
  const int t = threadIdx.x;
  const int chunk = (N + 1023) >> 10;
  const int beg = t * chunk;
  const int end = min(beg + chunk, N);
  int s = 0;
  for (int i = beg; i < end; ++i) s += counts[i];
  sums[t] = s;
  __syncthreads();
  for (int o = 1; o < 1024; o <<= 1) {
    int u = (t >= o) ? sums[t - o] : 0;
    __syncthreads();
    sums[t] += u;
    __syncthreads();
  }
  int run = sums[t] - s;
  for (int i = beg; i < end; ++i) { offsets[i] = run; run += counts[i]; }
  if (t == 1023) offsets[N] = sums[1023];
}

__global__ __launch_bounds__(256) void scatter_kernel(
    const int* __restrict__ src, const int* __restrict__ dst,
    const int* __restrict__ offsets, int* __restrict__ cursor,
    int* __restrict__ csr_src, int E)
{
  const int e = blockIdx.x * 256 + threadIdx.x;
  if (e >= E) return;
  const int d = dst[e];
  const int pos = offsets[d] + atomicAdd(cursor + d, 1);
  csr_src[pos] = src[e];
}

// ---------------- GAT aggregate: one wave per dst node ----------------
template <bool RES>
__global__ __launch_bounds__(256) void gat_aggregate_kernel(
    const int* __restrict__ csr_src, const int* __restrict__ offsets,
    const float* __restrict__ el, const float* __restrict__ er,
    const ushort* __restrict__ feat, const float* __restrict__ bias,
    const ushort* __restrict__ resid, ushort* __restrict__ out, int N)
{
  __shared__ float eeS[4][1024];  // [wave][edge<256][head]
  __shared__ int sS[4][256];      // [wave][edge<256] src id
  const int w = threadIdx.x >> 6;
  const int node = (blockIdx.x * 256 + threadIdx.x) >> 6;
  const int lane = threadIdx.x & 63;
  if (node >= N) return;
  const int beg = offsets[node], end = offsets[node + 1];
  const int deg = end - beg;
  const float4 erd = *(const float4*)(er + (size_t)node * 4);
  float* eew = eeS[w];
  int* sw = sS[w];

  // phase A
  float d0 = 0.f, d1 = 0.f, d2 = 0.f, d3 = 0.f;
  for (int i = lane; i < deg; i += 64) {
    const int s = csr_src[beg + i];
    const float4 l = *(const float4*)(el + (size_t)s * 4);
    float x0 = l.x + erd.x, x1 = l.y + erd.y, x2 = l.z + erd.z, x3 = l.w + erd.w;
    x0 = x0 > 0.f ? x0 : 0.2f * x0;
    x1 = x1 > 0.f ? x1 : 0.2f * x1;
    x2 = x2 > 0.f ? x2 : 0.2f * x2;
    x3 = x3 > 0.f ? x3 : 0.2f * x3;
    const float e0 = __expf(x0), e1 = __expf(x1), e2 = __expf(x2), e3 = __expf(x3);
    if (i < 256) {
      float4 ev = {e0, e1, e2, e3};
      *(float4*)(eew + (i << 2)) = ev;
      sw[i] = s;
    }
    d0 += e0; d1 += e1; d2 += e2; d3 += e3;
  }
  d0 = warp_sum(d0); d1 = warp_sum(d1); d2 = warp_sum(d2); d3 = warp_sum(d3);
  const float r0 = 1.f / d0, r1 = 1.f / d1, r2 = 1.f / d2, r3 = 1.f / d3;
  const int h = lane >> 4;
  const float rh = (lane & 32) ? ((lane & 16) ? r3 : r2) : ((lane & 16) ? r1 : r0);
  const float erh = (lane & 32) ? ((lane & 16) ? erd.w : erd.z)
                                : ((lane & 16) ? erd.y : erd.x);

  // phase B: x4 unrolled (independent accumulators -> 4 gathers in flight)
  float a0[8] = {0.f}, a1[8] = {0.f}, a2[8] = {0.f}, a3[8] = {0.f};
  const int cap = min(deg, 256);
  const int main4 = cap & ~3;
  int i = 0;
  for (; i < main4; i += 4) {
    const int s0 = sw[i], s1 = sw[i + 1], s2 = sw[i + 2], s3 = sw[i + 3];
    const float w0 = eew[((i + 0) << 2) | h] * rh;
    const float w1 = eew[((i + 1) << 2) | h] * rh;
    const float w2 = eew[((i + 2) << 2) | h] * rh;
    const float w3 = eew[((i + 3) << 2) | h] * rh;
    const uint4 q0 = *(const uint4*)(feat + (size_t)s0 * 512 + lane * 8);
    const uint4 q1 = *(const uint4*)(feat + (size_t)s1 * 512 + lane * 8);
    const uint4 q2 = *(const uint4*)(feat + (size_t)s2 * 512 + lane * 8);
    const uint4 q3 = *(const uint4*)(feat + (size_t)s3 * 512 + lane * 8);
    float v[8];
    up8(q0, v);
#pragma unroll
    for (int j = 0; j < 8; ++j) a0[j] = fmaf(v[j], w0, a0[j]);
    up8(q1, v);
#pragma unroll
    for (int j = 0; j < 8; ++j) a1[j] = fmaf(v[j], w1, a1[j]);
    up8(q2, v);
#pragma unroll
    for (int j = 0; j < 8; ++j) a2[j] = fmaf(v[j], w2, a2[j]);
    up8(q3, v);
#pragma unroll
    for (int j = 0; j < 8; ++j) a3[j] = fmaf(v[j], w3, a3[j]);
  }
  for (; i < cap; ++i) {
    const int s = sw[i];
    const float aw = eew[(i << 2) | h] * rh;
    const uint4 q = *(const uint4*)(feat + (size_t)s * 512 + lane * 8);
    float v[8];
    up8(q, v);
#pragma unroll
    for (int j = 0; j < 8; ++j) a0[j] = fmaf(v[j], aw, a0[j]);
  }
  for (; i < deg; ++i) {
    const int s = csr_src[beg + i];
    float x = el[(size_t)s * 4 + h] + erh;
    x = x > 0.f ? x : 0.2f * x;
    const float aw = __expf(x) * rh;
    const uint4 q = *(const uint4*)(feat + (size_t)s * 512 + lane * 8);
    float v[8];
    up8(q, v);
#pragma unroll
    for (int j = 0; j < 8; ++j) a0[j] = fmaf(v[j], aw, a0[j]);
  }
#pragma unroll
  for (int j = 0; j < 8; ++j) a0[j] += (a1[j] + a2[j]) + a3[j];

  const float4 b0 = *(const float4*)(bias + lane * 8);
  const float4 b1 = *(const float4*)(bias + lane * 8 + 4);
  a0[0] += b0.x; a0[1] += b0.y; a0[2] += b0.z; a0[3] += b0.w;
  a0[4] += b1.x; a0[5] += b1.y; a0[6] += b1.z; a0[7] += b1.w;
  if (RES) {
    float q[8];
    up8(*(const uint4*)(resid + (size_t)node * 512 + lane * 8), q);
#pragma unroll
    for (int j = 0; j < 8; ++j) a0[j] += q[j];
  }
  *(uint4*)(out + (size_t)node * 512 + lane * 8) = pk8(a0);
}

// gid logits: one wave per node; g bf16 [N,256] @ Wg2[256,4] + bg2.
__global__ __launch_bounds__(256) void gid2_kernel(
    const ushort* __restrict__ g, const float* __restrict__ Wg2,
    const float* __restrict__ bg2, float* __restrict__ out, int N)
{
  const int wv = (blockIdx.x * 256 + threadIdx.x) >> 6;
  const int lane = threadIdx.x & 63;
  if (wv >= N) return;
  float ga[4];
  up4(*(const uint2*)(g + (size_t)wv * 256 + lane * 4), ga);
  float a0 = 0.f, a1 = 0.f, a2 = 0.f, a3 = 0.f;
  const float* wp = Wg2 + (size_t)lane * 16;
#pragma unroll
  for (int j = 0; j < 4; j++) {
    const float4 w = *(const float4*)(wp + j * 4);
    a0 += ga[j] * w.x; a1 += ga[j] * w.y; a2 += ga[j] * w.z; a3 += ga[j] * w.w;
  }
  a0 = warp_sum(a0); a1 = warp_sum(a1); a2 = warp_sum(a2); a3 = warp_sum(a3);
  if (lane == 0) {
    float4 o = {a0 + bg2[0], a1 + bg2[1], a2 + bg2[2], a3 + bg2[3]};
    *(float4*)(out + (size_t)wv * 4) = o;
  }
}

// edge logits: HALF-wave (32 lanes) per pair; 32 x uint4 = exactly one 256-col row.
__global__ __launch_bounds__(256) void pair_combine_kernel(
    const ushort* __restrict__ UV, const int* __restrict__ pairs,
    const float* __restrict__ sb, const float* __restrict__ We2,
    const float* __restrict__ be2, float* __restrict__ out, int P)
{
  const int hw = (blockIdx.x * 256 + threadIdx.x) >> 5;
  const int l = threadIdx.x & 31;
  if (hw >= P) return;
  const int p0 = pairs[2 * hw], p1 = pairs[2 * hw + 1];
  float u[8], v[8];
  up8(*(const uint4*)(UV + (size_t)p0 * 512 + l * 8), u);
  up8(*(const uint4*)(UV + (size_t)p1 * 512 + 256 + l * 8), v);
  const float4 sb0 = *(const float4*)(sb + l * 8);
  const float4 sb1 = *(const float4*)(sb + l * 8 + 4);
  const float4 w0 = *(const float4*)(We2 + l * 8);
  const float4 w1 = *(const float4*)(We2 + l * 8 + 4);
  float s = fmaxf(u[0] + v[0] + sb0.x, 0.f) * w0.x
          + fmaxf(u[1] + v[1] + sb0.y, 0.f) * w0.y
          + fmaxf(u[2] + v[2] + sb0.z, 0.f) * w0.z
          + fmaxf(u[3] + v[3] + sb0.w, 0.f) * w0.w
          + fmaxf(u[4] + v[4] + sb1.x, 0.f) * w1.x
          + fmaxf(u[5] + v[5] + sb1.y, 0.f) * w1.y
          + fmaxf(u[6] + v[6] + sb1.z, 0.f) * w1.z
          + fmaxf(u[7] + v[7] + sb1.w, 0.f) * w1.w;
#pragma unroll
  for (int o = 16; o > 0; o >>= 1) s += __shfl_xor(s, o);
  if (l == 0) out[hw] = s + be2[0];
}

extern "C" void kernel_launch(void* const* d_in, const int* in_sizes, int n_in,
                              void* d_out, int out_size, void* d_ws, size_t ws_size,
                              hipStream_t stream) {
  const float* cell_h  = (const float*)d_in[0];
  const float* pos_emb = (const float*)d_in[1];
  const float* mf_emb  = (const float*)d_in[2];
  const float* W1  = (const float*)d_in[3];
  const float* al1 = (const float*)d_in[4];
  const float* ar1 = (const float*)d_in[5];
  const float* b1  = (const float*)d_in[6];
  const float* W2  = (const float*)d_in[7];
  const float* al2 = (const float*)d_in[8];
  const float* ar2 = (const float*)d_in[9];
  const float* b2  = (const float*)d_in[10];
  const float* Wg1 = (const float*)d_in[11];
  const float* bg1 = (const float*)d_in[12];
  const float* g_gamma = (const float*)d_in[13];
  const float* g_beta  = (const float*)d_in[14];
  const float* g_mean  = (const float*)d_in[15];
  const float* g_var   = (const float*)d_in[16];
  const float* Wg2 = (const float*)d_in[17];
  const float* bg2 = (const float*)d_in[18];
  const float* We1 = (const float*)d_in[19];
  const float* be1 = (const float*)d_in[20];
  const float* e_gamma = (const float*)d_in[21];
  const float* e_beta  = (const float*)d_in[22];
  const float* e_mean  = (const float*)d_in[23];
  const float* e_var   = (const float*)d_in[24];
  const float* We2 = (const float*)d_in[25];
  const float* be2 = (const float*)d_in[26];
  const int* src = (const int*)d_in[27];
  const int* dst = (const int*)d_in[28];
  const int* row_pos = (const int*)d_in[29];
  const int* col_pos = (const int*)d_in[30];
  const int* row_mf  = (const int*)d_in[31];
  const int* col_mf  = (const int*)d_in[32];
  const int* pairs   = (const int*)d_in[33];

  const int N = in_sizes[0] / 768;
  const int E = in_sizes[27];
  const int P = in_sizes[33] / 2;

  ushort* X0    = (ushort*)d_ws;                 // [N,832]
  ushort* featB = X0 + (size_t)N * 832;          // [N,512] (later reused as UV)
  ushort* h1    = featB + (size_t)N * 512;       // [N,512]
  ushort* h2    = h1 + (size_t)N * 512;          // [N,512]
  ushort* W1p   = h2 + (size_t)N * 512;          // packed [512 cols,832 k]
  ushort* W2p   = W1p + 512 * 832;               // packed [512,512]
  ushort* Bh    = W2p + 512 * 512;               // packed heads [768 cols,512 k]
  float* sa_ext = (float*)(Bh + 768 * 512);      // [512]
  float* sbv    = sa_ext + 512;                  // [256]
  float* el     = sbv + 256;                     // [N,4]
  float* er     = el + (size_t)N * 4;            // [N,4]
  int* offsets  = (int*)(er + (size_t)N * 4);    // [N+1]
  int* counts   = offsets + (N + 1);             // [N]
  int* cursor   = counts + N;                    // [N] (adjacent: one memset covers both)
  int* csr_src  = cursor + N;                    // [E]
  ushort* g_tmp = X0;                            // [N,256] (X0 dead after GEMM1)
  ushort* UV    = featB;                         // [N,512] (featB dead after agg2)

  const int nodeWaves = (N + 3) / 4;
  const int mtiles = (N + 127) / 128;

  // ---- CSR build (once) ----
  hipMemsetAsync(counts, 0, (size_t)(2 * N) * sizeof(int), stream);  // counts + cursor
  hist_kernel<<<(E + 255) / 256, 256, 0, stream>>>(dst, counts, E);
  scan_kernel<<<1, 1024, 0, stream>>>(counts, offsets, N);
  scatter_kernel<<<(E + 255) / 256, 256, 0, stream>>>(src, dst, offsets, cursor, csr_src, E);

  // ---- fused prep: weight packs + BN fold ----
  prep_kernel<<<(PREP_C4 + 256 + 255) / 256, 256, 0, stream>>>(
      W1, W2, Wg1, We1, W1p, W2p, Bh,
      be1, e_gamma, e_beta, e_mean, e_var, sa_ext, sbv);

  // ---- fused embedding -> X0 bf16 ----
  embed_kernel<<<(N * 104 + 255) / 256, 256, 0, stream>>>(
      cell_h, pos_emb, mf_emb, row_pos, col_pos, row_mf, col_mf, X0, N);

  // ---- GAT layer 1 (GEMM with fused elr) ----
  mfma_gemm_kernel<0, true><<<mtiles * 4, 512, 0, stream>>>(
      X0, W1p, featB, nullptr, N, 832, 512, 4, mtiles,
      nullptr, nullptr, nullptr, nullptr, nullptr, nullptr, al1, ar1, el, er);
  gat_aggregate_kernel<false><<<nodeWaves, 256, 0, stream>>>(
      csr_src, offsets, el, er, featB, b1, nullptr, h1, N);

  // ---- GAT layer 2 (identity residual) ----
  mfma_gemm_kernel<0, true><<<mtiles * 4, 512, 0, stream>>>(
      h1, W2p, featB, nullptr, N, 512, 512, 4, mtiles,
      nullptr, nullptr, nullptr, nullptr, nullptr, nullptr, al2, ar2, el, er);
  gat_aggregate_kernel<true><<<nodeWaves, 256, 0, stream>>>(
      csr_src, offsets, el, er, featB, b2, h1, h2, N);

  // ---- fused heads GEMM: [g_tmp | UV] = h2 @ [Wg1 | We1_top | We1_bot] ----
  mfma_gemm_kernel<1, false><<<mtiles * 6, 512, 0, stream>>>(
      h2, Bh, g_tmp, UV, N, 512, 0, 6, mtiles,
      bg1, g_gamma, g_beta, g_mean, g_var, sa_ext, nullptr, nullptr, nullptr, nullptr);
  gid2_kernel<<<nodeWaves, 256, 0, stream>>>(g_tmp, Wg2, bg2, (float*)d_out, N);
  pair_combine_kernel<<<(P + 7) / 8, 256, 0, stream>>>(
      UV, pairs, sbv, We2, be2, (float*)d_out + (size_t)N * 4, P);
}

// Round 10
// 586.316 us; speedup vs baseline: 1.5957x; 1.0049x over previous
//
#include <hip/hip_runtime.h>
#include <math.h>

// GNN_2_Model: fused-embed -> GAT1 -> GAT2(+res) -> gid head & edge head.
// Round 10:
//  - GEMM: 256x128 tile, 8 waves (each 64x64, acc[4][4]), single-buffered
//    R5-style loop -> 2x MFMA per barrier-pair, half the barriers, half the
//    B staging. Epilogue done in two 128-row passes ([128][132] aliases the
//    48KB staging buffer). ELR fused per pass.
//  - Aggregate / prep / embed / pair_combine / CSR unchanged from round 9.

typedef __attribute__((ext_vector_type(8))) short short8;   // 8 x bf16 (4 VGPR)
typedef __attribute__((ext_vector_type(4))) float f32x4;    // MFMA accum
typedef unsigned short ushort;

#define GLOAD16(g, l)                                                   \
  __builtin_amdgcn_global_load_lds(                                     \
      (const __attribute__((address_space(1))) unsigned int*)(g),       \
      (__attribute__((address_space(3))) unsigned int*)(l), 16, 0, 0)

__device__ __forceinline__ float b2f(ushort h) {
  union { unsigned u; float f; } v; v.u = ((unsigned)h) << 16; return v.f;
}
__device__ __forceinline__ ushort f2b(float f) {
  union { float f; unsigned u; } v; v.f = f;
  unsigned r = v.u + 0x7fffu + ((v.u >> 16) & 1u);  // round-to-nearest-even
  return (ushort)(r >> 16);
}
__device__ __forceinline__ void up4(uint2 q, float* o) {
  o[0] = b2f((ushort)(q.x & 0xffffu)); o[1] = b2f((ushort)(q.x >> 16));
  o[2] = b2f((ushort)(q.y & 0xffffu)); o[3] = b2f((ushort)(q.y >> 16));
}
__device__ __forceinline__ void up8(uint4 q, float* o) {
  o[0] = b2f((ushort)(q.x & 0xffffu)); o[1] = b2f((ushort)(q.x >> 16));
  o[2] = b2f((ushort)(q.y & 0xffffu)); o[3] = b2f((ushort)(q.y >> 16));
  o[4] = b2f((ushort)(q.z & 0xffffu)); o[5] = b2f((ushort)(q.z >> 16));
  o[6] = b2f((ushort)(q.w & 0xffffu)); o[7] = b2f((ushort)(q.w >> 16));
}
__device__ __forceinline__ uint4 pk8(const float* o) {
  uint4 q;
  q.x = (unsigned)f2b(o[0]) | ((unsigned)f2b(o[1]) << 16);
  q.y = (unsigned)f2b(o[2]) | ((unsigned)f2b(o[3]) << 16);
  q.z = (unsigned)f2b(o[4]) | ((unsigned)f2b(o[5]) << 16);
  q.w = (unsigned)f2b(o[6]) | ((unsigned)f2b(o[7]) << 16);
  return q;
}
__device__ __forceinline__ float warp_sum(float v) {
#pragma unroll
  for (int o = 32; o > 0; o >>= 1) v += __shfl_xor(v, o);
  return v;
}

// ---------------- fused embedding -> X0 bf16 [N,832] ----------------
__global__ __launch_bounds__(256) void embed_kernel(
    const float* __restrict__ cell_h, const float* __restrict__ pos_emb,
    const float* __restrict__ mf_emb,
    const int* __restrict__ row_pos, const int* __restrict__ col_pos,
    const int* __restrict__ row_mf, const int* __restrict__ col_mf,
    ushort* __restrict__ X0, int N)
{
  const int idx = blockIdx.x * 256 + threadIdx.x;
  const int total = N * 104;  // 832/8 chunks per node
  if (idx >= total) return;
  const int n = idx / 104;
  const int c8 = (idx - n * 104) * 8;
  float o[8];
  if (c8 < 768) {
    const int rp = row_pos[n], cp = col_pos[n];
    const float4* pc = (const float4*)(cell_h + (size_t)n * 768 + c8);
    const float4* pr = (const float4*)(pos_emb + (size_t)rp * 768 + c8);
    const float4* pq = (const float4*)(pos_emb + (size_t)cp * 768 + c8);
    float4 c0 = pc[0], c1 = pc[1], r0 = pr[0], r1 = pr[1], q0 = pq[0], q1 = pq[1];
    o[0] = c0.x + r0.x + q0.x; o[1] = c0.y + r0.y + q0.y;
    o[2] = c0.z + r0.z + q0.z; o[3] = c0.w + r0.w + q0.w;
    o[4] = c1.x + r1.x + q1.x; o[5] = c1.y + r1.y + q1.y;
    o[6] = c1.z + r1.z + q1.z; o[7] = c1.w + r1.w + q1.w;
  } else {
    const int rm = min(row_mf[n], 5), cm = min(col_mf[n], 5);
    const int j0 = c8 - 768;
    const float4* pr = (const float4*)(mf_emb + (size_t)rm * 64 + j0);
    const float4* pq = (const float4*)(mf_emb + (size_t)cm * 64 + j0);
    float4 r0 = pr[0], r1 = pr[1], q0 = pq[0], q1 = pq[1];
    o[0] = r0.x + q0.x; o[1] = r0.y + q0.y; o[2] = r0.z + q0.z; o[3] = r0.w + q0.w;
    o[4] = r1.x + q1.x; o[5] = r1.y + q1.y; o[6] = r1.z + q1.z; o[7] = r1.w + q1.w;
  }
  *(uint4*)(X0 + (size_t)n * 832 + c8) = pk8(o);
}

// ------- weight pack helper: element (k, c) of W[K][srcN] -> packed frag layout ------
__device__ __forceinline__ void pack_one(
    const float* __restrict__ W, ushort* __restrict__ Wp,
    int idx, int K, int srcN, int colBase, int nTK)
{
  const int c = idx / K, k = idx - c * K;
  const int n = colBase + c;
  const int tn = n >> 7, tk = k >> 6;
  const int sub = (((n >> 4) & 7) << 1) | ((k >> 5) & 1);
  const int lane = (n & 15) | (((k >> 3) & 3) << 4);
  const int j = k & 7;
  const size_t off = (((size_t)(tn * nTK + tk) << 4) + sub) * 512 + lane * 8 + j;
  Wp[off] = f2b(W[(size_t)k * srcN + c]);
}

// ---- fused prep: all weight packs + edge-head BN fold in one dispatch ----
#define PREP_C0 (832 * 512)
#define PREP_C1 (PREP_C0 + 512 * 512)
#define PREP_C2 (PREP_C1 + 512 * 256)
#define PREP_C3 (PREP_C2 + 512 * 256)
#define PREP_C4 (PREP_C3 + 512 * 256)
__global__ __launch_bounds__(256) void prep_kernel(
    const float* __restrict__ W1, const float* __restrict__ W2,
    const float* __restrict__ Wg1, const float* __restrict__ We1,
    ushort* __restrict__ W1p, ushort* __restrict__ W2p, ushort* __restrict__ Bh,
    const float* __restrict__ be1, const float* __restrict__ eg,
    const float* __restrict__ eb, const float* __restrict__ em,
    const float* __restrict__ ev, float* __restrict__ sa_ext, float* __restrict__ sbv)
{
  const int idx = blockIdx.x * 256 + threadIdx.x;
  if (idx < PREP_C0) {
    pack_one(W1, W1p, idx, 832, 512, 0, 13);
  } else if (idx < PREP_C1) {
    pack_one(W2, W2p, idx - PREP_C0, 512, 512, 0, 8);
  } else if (idx < PREP_C2) {
    pack_one(Wg1, Bh, idx - PREP_C1, 512, 256, 0, 8);
  } else if (idx < PREP_C3) {
    pack_one(We1, Bh, idx - PREP_C2, 512, 256, 256, 8);
  } else if (idx < PREP_C4) {
    pack_one(We1 + 512 * 256, Bh, idx - PREP_C3, 512, 256, 512, 8);
  } else if (idx < PREP_C4 + 256) {
    const int c = idx - PREP_C4;
    const float sa = eg[c] * rsqrtf(ev[c] + 1e-5f);
    sa_ext[c] = sa;
    sa_ext[c + 256] = sa;
    sbv[c] = eb[c] + (be1[c] - em[c]) * sa;
  }
}

// ---------------- bf16 MFMA GEMM: 256x128 tile, 8 waves (512 thr) ----------------
// wave (wm,wn) = (wave>>1, wave&1) owns 64x64: m-frags mb = wm*4+x (0..15),
// n-frags nb = wn*4+y (0..7). Staging: wave stages A subtiles {4w..4w+3},
// B subtiles {2w, 2w+1}. Single-buffer loop (R5-proven): gload -> sync ->
// 32 MFMA/wave -> sync. Epilogue in two 128-row passes via [128][132] LDS.
template <int EPI, bool ELR>
__global__ __launch_bounds__(512) void mfma_gemm_kernel(
    const ushort* __restrict__ A, const ushort* __restrict__ Bp,
    ushort* __restrict__ C0, ushort* __restrict__ C1,
    int M, int K, int Ncols, int NT, int mtiles,
    const float* __restrict__ bias, const float* __restrict__ gamma,
    const float* __restrict__ beta, const float* __restrict__ mean,
    const float* __restrict__ var, const float* __restrict__ sa_ext,
    const float* __restrict__ al, const float* __restrict__ ar,
    float* __restrict__ elp, float* __restrict__ erp)
{
  __shared__ ushort LDS[24576];   // As [0,16384) | Bs [16384,24576); epi aliases
  __shared__ float redS[768];
  const int tid = threadIdx.x;
  const int lane = tid & 63;
  const int wave = tid >> 6;      // 0..7
  const int wm = wave >> 1, wn = wave & 1;

  // XCD-co-locating swizzle (bijective incl. tail supergroup), 256-row bands.
  const int per = NT << 3;
  const int f = blockIdx.x;
  const int sg = f / per;
  const int rem = f - sg * per;
  const int nb = min(8, mtiles - (sg << 3));
  const int band = rem % nb, colt = rem / nb;
  const int m0 = ((sg << 3) + band) << 8;   // * 256
  const int n0 = colt << 7;
  const int nTK = K >> 6;

  // A staging: wave stages subtiles a = wave*4+q (a = mb*2+ks, mb=a>>1, ks=a&1)
  const int rA = lane & 15;
  const int kA = (lane >> 4) << 3;
  const ushort* Aaddr[4];
#pragma unroll
  for (int q = 0; q < 4; ++q) {
    const int a = (wave << 2) + q;          // 0..31
    int row = m0 + ((a >> 1) << 4) + rA;
    if (row >= M) row = 0;  // clamp: garbage rows never stored
    Aaddr[q] = A + (size_t)row * K + ((a & 1) << 5) + kA;
  }
  const ushort* Baddr = Bp + (((size_t)colt * nTK) << 13)
                        + ((size_t)(wave << 1) << 9) + (lane << 3);

  f32x4 acc[4][4];
#pragma unroll
  for (int i = 0; i < 4; ++i)
#pragma unroll
    for (int j = 0; j < 4; ++j) acc[i][j] = (f32x4){0.f, 0.f, 0.f, 0.f};

  const int nt = K >> 6;
  for (int t = 0; t < nt; ++t) {
    const int k0 = t << 6;
#pragma unroll
    for (int q = 0; q < 4; ++q)
      GLOAD16(Aaddr[q] + k0, LDS + (((wave << 2) + q) << 9));
#pragma unroll
    for (int q = 0; q < 2; ++q)
      GLOAD16(Baddr + ((size_t)t << 13) + (q << 9),
              LDS + 16384 + (((wave << 1) + q) << 9));
    __syncthreads();  // drains vmcnt -> LDS valid
#pragma unroll
    for (int ks = 0; ks < 2; ++ks) {
      short8 af[4], bf4[4];
#pragma unroll
      for (int x = 0; x < 4; ++x)
        af[x] = *(const short8*)(LDS + ((((wm << 2) + x) * 2 + ks) << 9) + (lane << 3));
#pragma unroll
      for (int y = 0; y < 4; ++y)
        bf4[y] = *(const short8*)(LDS + 16384 + ((((wn << 2) + y) * 2 + ks) << 9) + (lane << 3));
#pragma unroll
      for (int mf = 0; mf < 4; ++mf)
#pragma unroll
        for (int nf = 0; nf < 4; ++nf)
          acc[mf][nf] = __builtin_amdgcn_mfma_f32_16x16x32_bf16(
              af[mf], bf4[nf], acc[mf][nf], 0, 0, 0);
    }
    __syncthreads();  // all reads done before next overwrite
  }

  // ---- epilogue: two 128-row passes through LDS[128][132] (aliases staging) ----
#pragma unroll
  for (int p = 0; p < 2; ++p) {
    __syncthreads();
    if ((wm >> 1) == p) {   // waves with wm in {2p, 2p+1} own these 128 rows
#pragma unroll
      for (int nf = 0; nf < 4; ++nf) {
        const int cl = (((wn << 2) + nf) << 4) + (lane & 15);
        const int col = n0 + cl;
        float sa = 1.f, sb = 0.f;
        bool dorelu = false;
        if (EPI == 1) {
          if (col < 256) {
            const float rs = rsqrtf(var[col] + 1e-5f);
            sa = rs * gamma[col];
            sb = beta[col] + (bias[col] - mean[col]) * sa;
            dorelu = true;
          } else {
            sa = sa_ext[col - 256];
          }
        }
#pragma unroll
        for (int mf = 0; mf < 4; ++mf) {
          const int rl = ((((wm & 1) << 2) + mf) << 4) + ((lane >> 4) << 2);
#pragma unroll
          for (int j = 0; j < 4; ++j) {
            float v = acc[mf][nf][j];
            if (EPI == 1) { v = fmaf(v, sa, sb); if (dorelu) v = fmaxf(v, 0.f); }
            LDS[(rl + j) * 132 + cl] = f2b(v);
          }
        }
      }
    }
    __syncthreads();
    const int rbase = m0 + (p << 7);
#pragma unroll
    for (int i = 0; i < 4; ++i) {
      const int g = tid + (i << 9);        // 2048 granules of 16B
      const int r = g >> 4, c8 = g & 15;
      const int row = rbase + r;
      if (row < M) {
        const uint4 v = *(const uint4*)(LDS + r * 132 + (c8 << 3));
        const int col = n0 + (c8 << 3);
        if (EPI == 0) {
          *(uint4*)(C0 + (size_t)row * Ncols + col) = v;
        } else if (col < 256) {
          *(uint4*)(C0 + (size_t)row * 256 + col) = v;
        } else {
          *(uint4*)(C1 + (size_t)row * 512 + (col - 256)) = v;
        }
      }
    }
    // fused elr for these 128 rows (col tile == head colt)
    if (ELR) {
      const int r = tid & 127;
      const int qq = tid >> 7;  // 0..3 -> cols [qq*32, +32)
      const float* alh = al + colt * 128 + qq * 32;
      const float* arh = ar + colt * 128 + qq * 32;
      const ushort* rowp = LDS + r * 132 + qq * 32;
      float sl = 0.f, sr = 0.f;
#pragma unroll
      for (int c = 0; c < 32; ++c) {
        const float v = b2f(rowp[c]);
        sl = fmaf(v, alh[c], sl);
        sr = fmaf(v, arh[c], sr);
      }
      if (qq) { redS[((qq - 1) << 7) + r] = sl; redS[384 + ((qq - 1) << 7) + r] = sr; }
      __syncthreads();
      if (!qq) {
        const int row = rbase + r;
        if (row < M) {
          elp[(size_t)row * 4 + colt] = sl + redS[r] + redS[128 + r] + redS[256 + r];
          erp[(size_t)row * 4 + colt] = sr + redS[384 + r] + redS[512 + r] + redS[640 + r];
        }
      }
    }
  }
}

// ---------------- CSR build (by dst), done once ----------------
__global__ __launch_bounds__(256) void hist_kernel(
    const int* __restrict__ dst, int* __restrict__ counts, int E)
{
  const int e = blockIdx.x * 256 + threadIdx.x;
  if (e < E) atomicAdd(counts + dst[e], 1);
}

__global__ __launch_bounds__(1024) void scan_kernel(
    const int* __restrict__ counts, int* __restrict__ offsets, int N)
{
  __shared__ int sums[1024];
  const int t = threadIdx.x;
  const int chunk = (N + 1023) >> 10;
  const int beg = t * chunk;
  const int end = min(beg + chunk, N);
  int s = 0;
  for (int i = beg; i < end; ++i) s += counts[i];
  sums[t] = s;
  __syncthreads();
  for (int o = 1; o < 1024; o <<= 1) {
    int u = (t >= o) ? sums[t - o] : 0;
    __syncthreads();
    sums[t] += u;
    __syncthreads();
  }
  int run = sums[t] - s;
  for (int i = beg; i < end; ++i) { offsets[i] = run; run += counts[i]; }
  if (t == 1023) offsets[N] = sums[1023];
}

__global__ __launch_bounds__(256) void scatter_kernel(
    const int* __restrict__ src, const int* __restrict__ dst,
    const int* __restrict__ offsets, int* __restrict__ cursor,
    int* __restrict__ csr_src, int E)
{
  const int e = blockIdx.x * 256 + threadIdx.x;
  if (e >= E) return;
  const int d = dst[e];
  const int pos = offsets[d] + atomicAdd(cursor + d, 1);
  csr_src[pos] = src[e];
}

// ---------------- GAT aggregate: one wave per dst node ----------------
template <bool RES>
__global__ __launch_bounds__(256) void gat_aggregate_kernel(
    const int* __restrict__ csr_src, const int* __restrict__ offsets,
    const float* __restrict__ el, const float* __restrict__ er,
    const ushort* __restrict__ feat, const float* __restrict__ bias,
    const ushort* __restrict__ resid, ushort* __restrict__ out, int N)
{
  __shared__ float eeS[4][1024];  // [wave][edge<256][head]
  __shared__ int sS[4][256];      // [wave][edge<256] src id
  const int w = threadIdx.x >> 6;
  const int node = (blockIdx.x * 256 + threadIdx.x) >> 6;
  const int lane = threadIdx.x & 63;
  if (node >= N) return;
  const int beg = offsets[node], end = offsets[node + 1];
  const int deg = end - beg;
  const float4 erd = *(const float4*)(er + (size_t)node * 4);
  float* eew = eeS[w];
  int* sw = sS[w];

  // phase A
  float d0 = 0.f, d1 = 0.f, d2 = 0.f, d3 = 0.f;
  for (int i = lane; i < deg; i += 64) {
    const int s = csr_src[beg + i];
    const float4 l = *(const float4*)(el + (size_t)s * 4);
    float x0 = l.x + erd.x, x1 = l.y + erd.y, x2 = l.z + erd.z, x3 = l.w + erd.w;
    x0 = x0 > 0.f ? x0 : 0.2f * x0;
    x1 = x1 > 0.f ? x1 : 0.2f * x1;
    x2 = x2 > 0.f ? x2 : 0.2f * x2;
    x3 = x3 > 0.f ? x3 : 0.2f * x3;
    const float e0 = __expf(x0), e1 = __expf(x1), e2 = __expf(x2), e3 = __expf(x3);
    if (i < 256) {
      float4 ev = {e0, e1, e2, e3};
      *(float4*)(eew + (i << 2)) = ev;
      sw[i] = s;
    }
    d0 += e0; d1 += e1; d2 += e2; d3 += e3;
  }
  d0 = warp_sum(d0); d1 = warp_sum(d1); d2 = warp_sum(d2); d3 = warp_sum(d3);
  const float r0 = 1.f / d0, r1 = 1.f / d1, r2 = 1.f / d2, r3 = 1.f / d3;
  const int h = lane >> 4;
  const float rh = (lane & 32) ? ((lane & 16) ? r3 : r2) : ((lane & 16) ? r1 : r0);
  const float erh = (lane & 32) ? ((lane & 16) ? erd.w : erd.z)
                                : ((lane & 16) ? erd.y : erd.x);

  // phase B: x4 unrolled (independent accumulators -> 4 gathers in flight)
  float a0[8] = {0.f}, a1[8] = {0.f}, a2[8] = {0.f}, a3[8] = {0.f};
  const int cap = min(deg, 256);
  const int main4 = cap & ~3;
  int i = 0;
  for (; i < main4; i += 4) {
    const int s0 = sw[i], s1 = sw[i + 1], s2 = sw[i + 2], s3 = sw[i + 3];
    const float w0 = eew[((i + 0) << 2) | h] * rh;
    const float w1 = eew[((i + 1) << 2) | h] * rh;
    const float w2 = eew[((i + 2) << 2) | h] * rh;
    const float w3 = eew[((i + 3) << 2) | h] * rh;
    const uint4 q0 = *(const uint4*)(feat + (size_t)s0 * 512 + lane * 8);
    const uint4 q1 = *(const uint4*)(feat + (size_t)s1 * 512 + lane * 8);
    const uint4 q2 = *(const uint4*)(feat + (size_t)s2 * 512 + lane * 8);
    const uint4 q3 = *(const uint4*)(feat + (size_t)s3 * 512 + lane * 8);
    float v[8];
    up8(q0, v);
#pragma unroll
    for (int j = 0; j < 8; ++j) a0[j] = fmaf(v[j], w0, a0[j]);
    up8(q1, v);
#pragma unroll
    for (int j = 0; j < 8; ++j) a1[j] = fmaf(v[j], w1, a1[j]);
    up8(q2, v);
#pragma unroll
    for (int j = 0; j < 8; ++j) a2[j] = fmaf(v[j], w2, a2[j]);
    up8(q3, v);
#pragma unroll
    for (int j = 0; j < 8; ++j) a3[j] = fmaf(v[j], w3, a3[j]);
  }
  for (; i < cap; ++i) {
    const int s = sw[i];
    const float aw = eew[(i << 2) | h] * rh;
    const uint4 q = *(const uint4*)(feat + (size_t)s * 512 + lane * 8);
    float v[8];
    up8(q, v);
#pragma unroll
    for (int j = 0; j < 8; ++j) a0[j] = fmaf(v[j], aw, a0[j]);
  }
  for (; i < deg; ++i) {
    const int s = csr_src[beg + i];
    float x = el[(size_t)s * 4 + h] + erh;
    x = x > 0.f ? x : 0.2f * x;
    const float aw = __expf(x) * rh;
    const uint4 q = *(const uint4*)(feat + (size_t)s * 512 + lane * 8);
    float v[8];
    up8(q, v);
#pragma unroll
    for (int j = 0; j < 8; ++j) a0[j] = fmaf(v[j], aw, a0[j]);
  }
#pragma unroll
  for (int j = 0; j < 8; ++j) a0[j] += (a1[j] + a2[j]) + a3[j];

  const float4 b0 = *(const float4*)(bias + lane * 8);
  const float4 b1 = *(const float4*)(bias + lane * 8 + 4);
  a0[0] += b0.x; a0[1] += b0.y; a0[2] += b0.z; a0[3] += b0.w;
  a0[4] += b1.x; a0[5] += b1.y; a0[6] += b1.z; a0[7] += b1.w;
  if (RES) {
    float q[8];
    up8(*(const uint4*)(resid + (size_t)node * 512 + lane * 8), q);
#pragma unroll
    for (int j = 0; j < 8; ++j) a0[j] += q[j];
  }
  *(uint4*)(out + (size_t)node * 512 + lane * 8) = pk8(a0);
}

// gid logits: one wave per node; g bf16 [N,256] @ Wg2[256,4] + bg2.
__global__ __launch_bounds__(256) void gid2_kernel(
    const ushort* __restrict__ g, const float* __restrict__ Wg2,
    const float* __restrict__ bg2, float* __restrict__ out, int N)
{
  const int wv = (blockIdx.x * 256 + threadIdx.x) >> 6;
  const int lane = threadIdx.x & 63;
  if (wv >= N) return;
  float ga[4];
  up4(*(const uint2*)(g + (size_t)wv * 256 + lane * 4), ga);
  float a0 = 0.f, a1 = 0.f, a2 = 0.f, a3 = 0.f;
  const float* wp = Wg2 + (size_t)lane * 16;
#pragma unroll
  for (int j = 0; j < 4; j++) {
    const float4 w = *(const float4*)(wp + j * 4);
    a0 += ga[j] * w.x; a1 += ga[j] * w.y; a2 += ga[j] * w.z; a3 += ga[j] * w.w;
  }
  a0 = warp_sum(a0); a1 = warp_sum(a1); a2 = warp_sum(a2); a3 = warp_sum(a3);
  if (lane == 0) {
    float4 o = {a0 + bg2[0], a1 + bg2[1], a2 + bg2[2], a3 + bg2[3]};
    *(float4*)(out + (size_t)wv * 4) = o;
  }
}

// edge logits: HALF-wave (32 lanes) per pair; 32 x uint4 = exactly one 256-col row.
__global__ __launch_bounds__(256) void pair_combine_kernel(
    const ushort* __restrict__ UV, const int* __restrict__ pairs,
    const float* __restrict__ sb, const float* __restrict__ We2,
    const float* __restrict__ be2, float* __restrict__ out, int P)
{
  const int hw = (blockIdx.x * 256 + threadIdx.x) >> 5;
  const int l = threadIdx.x & 31;
  if (hw >= P) return;
  const int p0 = pairs[2 * hw], p1 = pairs[2 * hw + 1];
  float u[8], v[8];
  up8(*(const uint4*)(UV + (size_t)p0 * 512 + l * 8), u);
  up8(*(const uint4*)(UV + (size_t)p1 * 512 + 256 + l * 8), v);
  const float4 sb0 = *(const float4*)(sb + l * 8);
  const float4 sb1 = *(const float4*)(sb + l * 8 + 4);
  const float4 w0 = *(const float4*)(We2 + l * 8);
  const float4 w1 = *(const float4*)(We2 + l * 8 + 4);
  float s = fmaxf(u[0] + v[0] + sb0.x, 0.f) * w0.x
          + fmaxf(u[1] + v[1] + sb0.y, 0.f) * w0.y
          + fmaxf(u[2] + v[2] + sb0.z, 0.f) * w0.z
          + fmaxf(u[3] + v[3] + sb0.w, 0.f) * w0.w
          + fmaxf(u[4] + v[4] + sb1.x, 0.f) * w1.x
          + fmaxf(u[5] + v[5] + sb1.y, 0.f) * w1.y
          + fmaxf(u[6] + v[6] + sb1.z, 0.f) * w1.z
          + fmaxf(u[7] + v[7] + sb1.w, 0.f) * w1.w;
#pragma unroll
  for (int o = 16; o > 0; o >>= 1) s += __shfl_xor(s, o);
  if (l == 0) out[hw] = s + be2[0];
}

extern "C" void kernel_launch(void* const* d_in, const int* in_sizes, int n_in,
                              void* d_out, int out_size, void* d_ws, size_t ws_size,
                              hipStream_t stream) {
  const float* cell_h  = (const float*)d_in[0];
  const float* pos_emb = (const float*)d_in[1];
  const float* mf_emb  = (const float*)d_in[2];
  const float* W1  = (const float*)d_in[3];
  const float* al1 = (const float*)d_in[4];
  const float* ar1 = (const float*)d_in[5];
  const float* b1  = (const float*)d_in[6];
  const float* W2  = (const float*)d_in[7];
  const float* al2 = (const float*)d_in[8];
  const float* ar2 = (const float*)d_in[9];
  const float* b2  = (const float*)d_in[10];
  const float* Wg1 = (const float*)d_in[11];
  const float* bg1 = (const float*)d_in[12];
  const float* g_gamma = (const float*)d_in[13];
  const float* g_beta  = (const float*)d_in[14];
  const float* g_mean  = (const float*)d_in[15];
  const float* g_var   = (const float*)d_in[16];
  const float* Wg2 = (const float*)d_in[17];
  const float* bg2 = (const float*)d_in[18];
  const float* We1 = (const float*)d_in[19];
  const float* be1 = (const float*)d_in[20];
  const float* e_gamma = (const float*)d_in[21];
  const float* e_beta  = (const float*)d_in[22];
  const float* e_mean  = (const float*)d_in[23];
  const float* e_var   = (const float*)d_in[24];
  const float* We2 = (const float*)d_in[25];
  const float* be2 = (const float*)d_in[26];
  const int* src = (const int*)d_in[27];
  const int* dst = (const int*)d_in[28];
  const int* row_pos = (const int*)d_in[29];
  const int* col_pos = (const int*)d_in[30];
  const int* row_mf  = (const int*)d_in[31];
  const int* col_mf  = (const int*)d_in[32];
  const int* pairs   = (const int*)d_in[33];

  const int N = in_sizes[0] / 768;
  const int E = in_sizes[27];
  const int P = in_sizes[33] / 2;

  ushort* X0    = (ushort*)d_ws;                 // [N,832]
  ushort* featB = X0 + (size_t)N * 832;          // [N,512] (later reused as UV)
  ushort* h1    = featB + (size_t)N * 512;       // [N,512]
  ushort* h2    = h1 + (size_t)N * 512;          // [N,512]
  ushort* W1p   = h2 + (size_t)N * 512;          // packed [512 cols,832 k]
  ushort* W2p   = W1p + 512 * 832;               // packed [512,512]
  ushort* Bh    = W2p + 512 * 512;               // packed heads [768 cols,512 k]
  float* sa_ext = (float*)(Bh + 768 * 512);      // [512]
  float* sbv    = sa_ext + 512;                  // [256]
  float* el     = sbv + 256;                     // [N,4]
  float* er     = el + (size_t)N * 4;            // [N,4]
  int* offsets  = (int*)(er + (size_t)N * 4);    // [N+1]
  int* counts   = offsets + (N + 1);             // [N]
  int* cursor   = counts + N;                    // [N] (adjacent: one memset covers both)
  int* csr_src  = cursor + N;                    // [E]
  ushort* g_tmp = X0;                            // [N,256] (X0 dead after GEMM1)
  ushort* UV    = featB;                         // [N,512] (featB dead after agg2)

  const int nodeWaves = (N + 3) / 4;
  const int mtiles = (N + 255) / 256;            // 256-row bands

  // ---- CSR build (once) ----
  hipMemsetAsync(counts, 0, (size_t)(2 * N) * sizeof(int), stream);  // counts + cursor
  hist_kernel<<<(E + 255) / 256, 256, 0, stream>>>(dst, counts, E);
  scan_kernel<<<1, 1024, 0, stream>>>(counts, offsets, N);
  scatter_kernel<<<(E + 255) / 256, 256, 0, stream>>>(src, dst, offsets, cursor, csr_src, E);

  // ---- fused prep: weight packs + BN fold ----
  prep_kernel<<<(PREP_C4 + 256 + 255) / 256, 256, 0, stream>>>(
      W1, W2, Wg1, We1, W1p, W2p, Bh,
      be1, e_gamma, e_beta, e_mean, e_var, sa_ext, sbv);

  // ---- fused embedding -> X0 bf16 ----
  embed_kernel<<<(N * 104 + 255) / 256, 256, 0, stream>>>(
      cell_h, pos_emb, mf_emb, row_pos, col_pos, row_mf, col_mf, X0, N);

  // ---- GAT layer 1 (GEMM with fused elr) ----
  mfma_gemm_kernel<0, true><<<mtiles * 4, 512, 0, stream>>>(
      X0, W1p, featB, nullptr, N, 832, 512, 4, mtiles,
      nullptr, nullptr, nullptr, nullptr, nullptr, nullptr, al1, ar1, el, er);
  gat_aggregate_kernel<false><<<nodeWaves, 256, 0, stream>>>(
      csr_src, offsets, el, er, featB, b1, nullptr, h1, N);

  // ---- GAT layer 2 (identity residual) ----
  mfma_gemm_kernel<0, true><<<mtiles * 4, 512, 0, stream>>>(
      h1, W2p, featB, nullptr, N, 512, 512, 4, mtiles,
      nullptr, nullptr, nullptr, nullptr, nullptr, nullptr, al2, ar2, el, er);
  gat_aggregate_kernel<true><<<nodeWaves, 256, 0, stream>>>(
      csr_src, offsets, el, er, featB, b2, h1, h2, N);

  // ---- fused heads GEMM: [g_tmp | UV] = h2 @ [Wg1 | We1_top | We1_bot] ----
  mfma_gemm_kernel<1, false><<<mtiles * 6, 512, 0, stream>>>(
      h2, Bh, g_tmp, UV, N, 512, 0, 6, mtiles,
      bg1, g_gamma, g_beta, g_mean, g_var, sa_ext, nullptr, nullptr, nullptr, nullptr);
  gid2_kernel<<<nodeWaves, 256, 0, stream>>>(g_tmp, Wg2, bg2, (float*)d_out, N);
  pair_combine_kernel<<<(P + 7) / 8, 256, 0, stream>>>(
      UV, pairs, sbv, We2, be2, (float*)d_out + (size_t)N * 4, P);
}